// Round 12
// baseline (3393.394 us; speedup 1.0000x reference)
//
#include <hip/hip_runtime.h>

typedef __attribute__((ext_vector_type(8))) short short8;
typedef __attribute__((ext_vector_type(4))) float f32x4;
typedef __attribute__((ext_vector_type(8))) unsigned short u16x8;
typedef unsigned short u16;

#define V_SIZE 32000
#define D_MODEL 1024
#define HFF 4096
#define NHEAD 16
#define HDIM 64
#define NLAYER 4
#define BT 4096   // B*T tokens
#define TSEQ 2048
#define QKV_STRIDE 3072
#define GU_STRIDE 8192

__device__ __forceinline__ u16 f2bf(float f) {
  union { float f; unsigned u; } v; v.f = f;
  unsigned r = v.u + 0x7fffu + ((v.u >> 16) & 1u);
  return (u16)(r >> 16);
}
__device__ __forceinline__ float bf2f(u16 h) {
  union { unsigned u; float f; } v; v.u = ((unsigned)h) << 16;
  return v.f;
}

__device__ __forceinline__ void gload_lds16(const void* g, void* l) {
  __builtin_amdgcn_global_load_lds((__attribute__((address_space(1))) void*)g,
                                   (__attribute__((address_space(3))) void*)l, 16, 0, 0);
}

// ---------------- elementwise / small kernels ----------------

__global__ void rope_table_kernel(float* __restrict__ cosb, float* __restrict__ sinb) {
  int i = blockIdx.x * 256 + threadIdx.x;       // 2048*32 = 65536 items
  int t = i >> 5, fi = i & 31;
  float freq = exp2f(-(2.0f * (float)fi / 64.0f) * log2f(10000.0f));
  float ang = (float)t * freq;
  cosb[i] = cosf(ang);
  sinb[i] = sinf(ang);
}

// lm_head fp32 -> bf16, scaled by final_norm[k] (k = flat index & 1023)
__global__ void convert_bf16_kernel(const float* __restrict__ src, u16* __restrict__ dst,
                                    const float* __restrict__ fn, long n8) {
  long i = (long)blockIdx.x * 256 + threadIdx.x;
  long stride = (long)gridDim.x * 256;
  for (; i < n8; i += stride) {
    const float4* s = (const float4*)(src + i * 8);
    float4 a = s[0], b = s[1];
    int k0 = (int)((i * 8) & (D_MODEL - 1));
    u16x8 r;
    r[0] = f2bf(a.x * fn[k0 + 0]); r[1] = f2bf(a.y * fn[k0 + 1]);
    r[2] = f2bf(a.z * fn[k0 + 2]); r[3] = f2bf(a.w * fn[k0 + 3]);
    r[4] = f2bf(b.x * fn[k0 + 4]); r[5] = f2bf(b.y * fn[k0 + 5]);
    r[6] = f2bf(b.z * fn[k0 + 6]); r[7] = f2bf(b.w * fn[k0 + 7]);
    *(u16x8*)(dst + i * 8) = r;
  }
}

// src [R][C] fp32 -> dst bf16, scaled by nw[src row] if nw != null (norm fold).
// rowMode: 0 -> dst row = c; 1 -> ((c>>6)<<7)|(c&63) (gate); 2 -> +64 (up)
__global__ __launch_bounds__(256) void transpose_bf16_kernel(const float* __restrict__ src0,
                                                             u16* __restrict__ dst0, int R, int C,
                                                             long srcStride, long dstStride,
                                                             int rowMode,
                                                             const float* __restrict__ nw0,
                                                             int nwStride) {
  __shared__ float tile[32][33];
  const float* src = src0 + (size_t)blockIdx.z * srcStride;
  u16* dst = dst0 + (size_t)blockIdx.z * dstStride;
  const float* nw = nw0 ? nw0 + (size_t)blockIdx.z * nwStride : nullptr;
  int tx = threadIdx.x & 31, ty = threadIdx.x >> 5;  // 32 x 8
  int bx = blockIdx.x, by = blockIdx.y;
#pragma unroll
  for (int i = 0; i < 32; i += 8) {
    int r = by * 32 + ty + i, c = bx * 32 + tx;
    tile[ty + i][tx] = src[(size_t)r * C + c];
  }
  __syncthreads();
#pragma unroll
  for (int i = 0; i < 32; i += 8) {
    int c = bx * 32 + ty + i;   // source col
    int r = by * 32 + tx;       // source row (k index) -> dst col
    float val = tile[tx][ty + i];
    if (nw) val *= nw[r];
    int drow = c;
    if (rowMode == 1) drow = ((c >> 6) << 7) | (c & 63);
    else if (rowMode == 2) drow = ((c >> 6) << 7) | 64 | (c & 63);
    dst[(size_t)drow * R + r] = f2bf(val);
  }
}

// embed gather: writes X fp32, Xb bf16, and rinv[t] (rms of the row). 1 block = 1 token.
__global__ __launch_bounds__(256) void embed_gather_kernel(const int* __restrict__ idx,
                                                           const float* __restrict__ embed,
                                                           float* __restrict__ x,
                                                           u16* __restrict__ xb,
                                                           float* __restrict__ rinv) {
  int t = blockIdx.x;
  int id = idx[t];
  float4 v = ((const float4*)embed)[(size_t)id * 256 + threadIdx.x];
  ((float4*)x)[(size_t)t * 256 + threadIdx.x] = v;
  u16* hp = xb + (size_t)t * D_MODEL + threadIdx.x * 4;
  hp[0] = f2bf(v.x); hp[1] = f2bf(v.y); hp[2] = f2bf(v.z); hp[3] = f2bf(v.w);
  float ss = v.x * v.x + v.y * v.y + v.z * v.z + v.w * v.w;
#pragma unroll
  for (int m = 32; m > 0; m >>= 1) ss += __shfl_xor(ss, m, 64);
  __shared__ float wsum[4];
  if ((threadIdx.x & 63) == 0) wsum[threadIdx.x >> 6] = ss;
  __syncthreads();
  if (threadIdx.x == 0) {
    float tot = wsum[0] + wsum[1] + wsum[2] + wsum[3];
    rinv[t] = rsqrtf(tot * (1.0f / (float)D_MODEL) + 1e-6f);
  }
}

// reduce 16 ssq partials per row -> rinv
__global__ void rinv_kernel(const float* __restrict__ ssqPart, float* __restrict__ rinv) {
  int r = blockIdx.x * 256 + threadIdx.x;   // BT rows
  float s = 0.f;
#pragma unroll
  for (int i = 0; i < 16; i++) s += ssqPart[(size_t)r * 16 + i];
  rinv[r] = rsqrtf(s * (1.0f / (float)D_MODEL) + 1e-6f);
}

// V (in QKV buffer) -> Vt [bh][64 d][TSEQ t] bf16, tile-transposed via LDS.
__global__ __launch_bounds__(256) void vtrans_kernel(const u16* __restrict__ qkv,
                                                     u16* __restrict__ vt) {
  __shared__ u16 lds[64 * 64];
  const int tid = threadIdx.x;
  const int bh = blockIdx.y, tt = blockIdx.x;
  const int b = bh >> 4, h = bh & 15;
  const int tok0 = b * TSEQ + tt * 64;
  const int hoff = 2 * D_MODEL + h * HDIM;
#pragma unroll
  for (int it = 0; it < 2; it++) {
    int idx = it * 256 + tid;
    int row = idx >> 3, c = (idx & 7) * 8;
    short8 v = *(const short8*)(qkv + (size_t)(tok0 + row) * QKV_STRIDE + hoff + c);
    *(short8*)&lds[row * 64 + (c ^ ((row & 7) << 3))] = v;
  }
  __syncthreads();
#pragma unroll
  for (int it = 0; it < 2; it++) {
    int idx = it * 256 + tid;
    int d = idx >> 3, t0 = (idx & 7) * 8;
    u16x8 pk;
#pragma unroll
    for (int j = 0; j < 8; j++) {
      int t = t0 + j;
      pk[j] = lds[t * 64 + (((d & ~7) ^ ((t & 7) << 3)) | (d & 7))];
    }
    *(u16x8*)(vt + ((size_t)bh * 64 + d) * TSEQ + tt * 64 + t0) = pk;
  }
}

// ---------------- GEMM 128x128 (m97 structure, both-sides swizzle, 5 blocks/CU) ----
// C[M,N] = A[M,K](bf16) * B[N,K](bf16)^T. 256 threads = 4 waves (2x2).
// bn-chunked; bm-fast XCD-local order (R11): 1 L2 fill per B-panel per XCD.
// EPI: 0 = lm-head: vv *= rinv; fp32 nontemporal store + LSE partials
//      2 = residual add; also writes Xb bf16 + 16 ssq partials/row (norm fold)
//      4 = QKV: vv *= rinv, fused RoPE on cols < 2048, bf16 store
//      5 = GU fused silu-mul: g,u *= rinv before silu; LDS exchange; N/2 store
template <int EPI>
__global__ __launch_bounds__(256, 5) void gemm128_kernel(const u16* __restrict__ A,
                                                         const u16* __restrict__ B, void* Cp,
                                                         const float* __restrict__ resid,
                                                         float* __restrict__ partM,
                                                         float* __restrict__ partS,
                                                         const float* __restrict__ cosb,
                                                         const float* __restrict__ sinb,
                                                         u16* __restrict__ xbout,
                                                         float* __restrict__ ssqPart,
                                                         const float* __restrict__ rinv,
                                                         int M, int N, int K, int chunkBn) {
  __shared__ __align__(16) u16 smem_ab[2][128 * 64];   // 32 KiB total
  u16* As = smem_ab[0];
  u16* Bs = smem_ab[1];
  const int tid = threadIdx.x;
  const int lane = tid & 63, wid = tid >> 6;
  const int wr = wid >> 1, wc = wid & 1;
  const int q = lane >> 4, l15 = lane & 15;
  const int nbm = M >> 7;
  const int nbmx = nbm >> 3;               // bm rows per XCD (4)
  const int cs = nbm * chunkBn;            // blocks per chunk
  const int chunk = (int)blockIdx.x / cs;
  const int r0 = (int)blockIdx.x - chunk * cs;
  const int s2 = r0 >> 3;
  const int bm = (r0 & 7) * nbmx + (s2 % nbmx);
  const int bn = chunk * chunkBn + (s2 / nbmx);
  const size_t abase = (size_t)bm * 128 * K;
  const size_t bbase = (size_t)bn * 128 * K;
  f32x4 acc[4][4] = {};
  for (int k0 = 0; k0 < K; k0 += 64) {
#pragma unroll
    for (int i = 0; i < 4; i++) {
      int idx8 = i * 256 + tid;
      int row = idx8 >> 3, ch = idx8 & 7;
      int sc = (ch ^ (row & 7)) << 3;
      gload_lds16(A + abase + (size_t)row * K + k0 + sc, As + idx8 * 8);
      gload_lds16(B + bbase + (size_t)row * K + k0 + sc, Bs + idx8 * 8);
    }
    __syncthreads();
#pragma unroll
    for (int ks = 0; ks < 2; ks++) {
      short8 af[4], bfr[4];
      int chunkc = ks * 4 + q;
#pragma unroll
      for (int mi = 0; mi < 4; mi++) {
        int row = wr * 64 + mi * 16 + l15;
        af[mi] = *(const short8*)&As[row * 64 + ((chunkc ^ (row & 7)) << 3)];
      }
#pragma unroll
      for (int ni = 0; ni < 4; ni++) {
        int row = wc * 64 + ni * 16 + l15;
        bfr[ni] = *(const short8*)&Bs[row * 64 + ((chunkc ^ (row & 7)) << 3)];
      }
#pragma unroll
      for (int mi = 0; mi < 4; mi++)
#pragma unroll
        for (int ni = 0; ni < 4; ni++)
          acc[mi][ni] = __builtin_amdgcn_mfma_f32_16x16x32_bf16(af[mi], bfr[ni], acc[mi][ni], 0, 0, 0);
    }
    __syncthreads();
  }

  // ---- EPI 5: fused silu-mul via cross-wave LDS exchange (rinv applied pre-silu) ----
  if (EPI == 5) {
    float* upf = (float*)&smem_ab[0][0];   // 128x64 floats = 32 KiB
    if (wc == 1) {
#pragma unroll
      for (int mi = 0; mi < 4; mi++)
#pragma unroll
        for (int ni = 0; ni < 4; ni++)
#pragma unroll
          for (int j = 0; j < 4; j++) {
            int r = wr * 64 + mi * 16 + q * 4 + j;
            int cswz = (ni ^ ((r >> 2) & 3)) * 16 + l15;
            upf[r * 64 + cswz] = acc[mi][ni][j];
          }
    }
    __syncthreads();
    if (wc == 0) {
#pragma unroll
      for (int mi = 0; mi < 4; mi++)
#pragma unroll
        for (int j = 0; j < 4; j++) {
          int rloc = wr * 64 + mi * 16 + q * 4 + j;
          int rr = bm * 128 + rloc;
          float ri = rinv[rr];
#pragma unroll
          for (int ni = 0; ni < 4; ni++) {
            int cswz = (ni ^ ((rloc >> 2) & 3)) * 16 + l15;
            float g = acc[mi][ni][j] * ri;
            float u = upf[rloc * 64 + cswz] * ri;
            float rsl = g / (1.0f + expf(-g)) * u;
            ((u16*)Cp)[(size_t)rr * (N >> 1) + bn * 64 + ni * 16 + l15] = f2bf(rsl);
          }
        }
    }
    return;
  }

  // ---- EPI 2: residual add + Xb bf16 + ssq partials ----
  if (EPI == 2) {
#pragma unroll
    for (int mi = 0; mi < 4; mi++)
#pragma unroll
      for (int j = 0; j < 4; j++) {
        int rr = bm * 128 + wr * 64 + mi * 16 + q * 4 + j;
        float ssq = 0.f;
#pragma unroll
        for (int ni = 0; ni < 4; ni++) {
          int cn = bn * 128 + wc * 64 + ni * 16 + l15;
          size_t off = (size_t)rr * N + cn;
          float nx = resid[off] + acc[mi][ni][j];
          ((float*)Cp)[off] = nx;
          xbout[off] = f2bf(nx);
          ssq += nx * nx;
        }
        ssq += __shfl_xor(ssq, 1, 64);
        ssq += __shfl_xor(ssq, 2, 64);
        ssq += __shfl_xor(ssq, 4, 64);
        ssq += __shfl_xor(ssq, 8, 64);
        if (l15 == 0) ssqPart[(size_t)rr * 16 + (bn << 1) + wc] = ssq;
      }
    return;
  }

  // ---- EPI 0 / 4 ----
#pragma unroll
  for (int mi = 0; mi < 4; mi++)
#pragma unroll
    for (int j = 0; j < 4; j++) {
      int rr = bm * 128 + wr * 64 + mi * 16 + q * 4 + j;
      float ri = rinv[rr];
      float vv[4];
#pragma unroll
      for (int ni = 0; ni < 4; ni++) vv[ni] = acc[mi][ni][j] * ri;
      if (EPI == 0) {
        float mx = fmaxf(fmaxf(vv[0], vv[1]), fmaxf(vv[2], vv[3]));
        mx = fmaxf(mx, __shfl_xor(mx, 1, 64));
        mx = fmaxf(mx, __shfl_xor(mx, 2, 64));
        mx = fmaxf(mx, __shfl_xor(mx, 4, 64));
        mx = fmaxf(mx, __shfl_xor(mx, 8, 64));
        float sm = 0.f;
#pragma unroll
        for (int ni = 0; ni < 4; ni++) sm += expf(vv[ni] - mx);
        sm += __shfl_xor(sm, 1, 64);
        sm += __shfl_xor(sm, 2, 64);
        sm += __shfl_xor(sm, 4, 64);
        sm += __shfl_xor(sm, 8, 64);
        if (l15 == 0) {
          int nt = (N >> 6);
          partM[(size_t)rr * nt + (bn << 1) + wc] = mx;
          partS[(size_t)rr * nt + (bn << 1) + wc] = sm;
        }
      }
      if (EPI == 4) {
        if (((bn << 1) + wc) < 32) {   // Q or K cols: wave-uniform
          int t = rr & (TSEQ - 1);
#pragma unroll
          for (int ni = 0; ni < 2; ni++) {
            int fi = ni * 16 + l15;
            float c = cosb[t * 32 + fi], s = sinb[t * 32 + fi];
            float x1 = vv[ni], x2 = vv[ni + 2];
            vv[ni] = x1 * c - x2 * s;
            vv[ni + 2] = x2 * c + x1 * s;
          }
        }
      }
#pragma unroll
      for (int ni = 0; ni < 4; ni++) {
        int cn = bn * 128 + wc * 64 + ni * 16 + l15;
        size_t off = (size_t)rr * N + cn;
        if (EPI == 0) __builtin_nontemporal_store(vv[ni], (float*)Cp + off);
        else ((u16*)Cp)[off] = f2bf(vv[ni]);
      }
    }
}

// ---------------- flash attention ----------------
__global__ __launch_bounds__(256) void attn_kernel(const u16* __restrict__ qkv,
                                                   const u16* __restrict__ vt,
                                                   u16* __restrict__ o) {
  __shared__ __align__(16) u16 Ks[64 * 64];
  __shared__ __align__(16) u16 Vt[64 * 64];
  __shared__ u16 Ps[4][32 * 64];
  const u16* q = qkv;
  const u16* k = qkv + D_MODEL;
  const int tid = threadIdx.x, lane = tid & 63, wid = tid >> 6;
  const int qg = lane >> 4, l15 = lane & 15;
  const int qt = blockIdx.x;
  const int bh = blockIdx.y;
  const int b = bh >> 4, h = bh & 15;
  const int tok0 = b * TSEQ;
  const int hoff = h * HDIM;
  const int qrow0 = qt * 128 + wid * 32;
  const u16* vtb = vt + (size_t)bh * 64 * TSEQ;

  short8 aq[2][2];
#pragma unroll
  for (int mi = 0; mi < 2; mi++)
#pragma unroll
    for (int ks = 0; ks < 2; ks++) {
      int r = qrow0 + mi * 16 + l15;
      int d = ks * 32 + qg * 8;
      aq[mi][ks] = *(const short8*)(q + (size_t)(tok0 + r) * QKV_STRIDE + hoff + d);
    }
  f32x4 oacc[2][4] = {};
  float mrow[2][4], lrow[2][4];
#pragma unroll
  for (int mi = 0; mi < 2; mi++)
#pragma unroll
    for (int j = 0; j < 4; j++) { mrow[mi][j] = -1e30f; lrow[mi][j] = 0.f; }

  const int nkt = (qt + 1) * 2;
  for (int kt = 0; kt < nkt; kt++) {
    const int kv0 = kt * 64;
#pragma unroll
    for (int it = 0; it < 2; it++) {
      int idx = it * 256 + tid;
      int row = idx >> 3, ch = idx & 7;
      int sc = (ch ^ (row & 7)) << 3;
      gload_lds16(k + (size_t)(tok0 + kv0 + row) * QKV_STRIDE + hoff + sc, Ks + idx * 8);
      gload_lds16(vtb + (size_t)row * TSEQ + kv0 + sc, Vt + idx * 8);
    }
    __syncthreads();
    f32x4 sc[2][4] = {};
#pragma unroll
    for (int ks = 0; ks < 2; ks++) {
      short8 bk[4];
      int kcol = ks * 32 + qg * 8;
#pragma unroll
      for (int ni = 0; ni < 4; ni++) {
        int r = ni * 16 + l15;
        bk[ni] = *(const short8*)&Ks[r * 64 + (kcol ^ ((r & 7) << 3))];
      }
#pragma unroll
      for (int mi = 0; mi < 2; mi++)
#pragma unroll
        for (int ni = 0; ni < 4; ni++)
          sc[mi][ni] = __builtin_amdgcn_mfma_f32_16x16x32_bf16(aq[mi][ks], bk[ni], sc[mi][ni], 0, 0, 0);
    }
    float pm[2][4];
#pragma unroll
    for (int mi = 0; mi < 2; mi++)
#pragma unroll
      for (int j = 0; j < 4; j++) pm[mi][j] = -1e30f;
#pragma unroll
    for (int mi = 0; mi < 2; mi++)
#pragma unroll
      for (int ni = 0; ni < 4; ni++)
#pragma unroll
        for (int j = 0; j < 4; j++) {
          int rq = qrow0 + mi * 16 + qg * 4 + j;
          int ck = kv0 + ni * 16 + l15;
          float s = sc[mi][ni][j] * 0.125f;
          if (ck > rq) s = -1e30f;
          sc[mi][ni][j] = s;
          pm[mi][j] = fmaxf(pm[mi][j], s);
        }
#pragma unroll
    for (int mi = 0; mi < 2; mi++)
#pragma unroll
      for (int j = 0; j < 4; j++) {
        float t = pm[mi][j];
        t = fmaxf(t, __shfl_xor(t, 1, 64));
        t = fmaxf(t, __shfl_xor(t, 2, 64));
        t = fmaxf(t, __shfl_xor(t, 4, 64));
        t = fmaxf(t, __shfl_xor(t, 8, 64));
        pm[mi][j] = t;
      }
#pragma unroll
    for (int mi = 0; mi < 2; mi++)
#pragma unroll
      for (int j = 0; j < 4; j++) {
        float mn = fmaxf(mrow[mi][j], pm[mi][j]);
        float fac = expf(mrow[mi][j] - mn);
        lrow[mi][j] *= fac;
#pragma unroll
        for (int df = 0; df < 4; df++) oacc[mi][df][j] *= fac;
        mrow[mi][j] = mn;
      }
    float psum[2][4] = {};
#pragma unroll
    for (int mi = 0; mi < 2; mi++)
#pragma unroll
      for (int ni = 0; ni < 4; ni++)
#pragma unroll
        for (int j = 0; j < 4; j++) {
          float p = expf(sc[mi][ni][j] - mrow[mi][j]);
          psum[mi][j] += p;
          int r32 = mi * 16 + qg * 4 + j;
          int cc = ni * 16 + l15;
          Ps[wid][r32 * 64 + (cc ^ ((r32 & 7) << 3))] = f2bf(p);
        }
#pragma unroll
    for (int mi = 0; mi < 2; mi++)
#pragma unroll
      for (int j = 0; j < 4; j++) {
        float t = psum[mi][j];
        t += __shfl_xor(t, 1, 64);
        t += __shfl_xor(t, 2, 64);
        t += __shfl_xor(t, 4, 64);
        t += __shfl_xor(t, 8, 64);
        lrow[mi][j] += t;
      }
#pragma unroll
    for (int kf = 0; kf < 2; kf++) {
      short8 pa[2], bv[4];
      int kcol = kf * 32 + qg * 8;
#pragma unroll
      for (int mi = 0; mi < 2; mi++) {
        int r = mi * 16 + l15;
        pa[mi] = *(const short8*)&Ps[wid][r * 64 + (kcol ^ ((r & 7) << 3))];
      }
#pragma unroll
      for (int df = 0; df < 4; df++) {
        int r = df * 16 + l15;
        bv[df] = *(const short8*)&Vt[r * 64 + (kcol ^ ((r & 7) << 3))];
      }
#pragma unroll
      for (int mi = 0; mi < 2; mi++)
#pragma unroll
        for (int df = 0; df < 4; df++)
          oacc[mi][df] = __builtin_amdgcn_mfma_f32_16x16x32_bf16(pa[mi], bv[df], oacc[mi][df], 0, 0, 0);
    }
    __syncthreads();
  }
#pragma unroll
  for (int mi = 0; mi < 2; mi++)
#pragma unroll
    for (int df = 0; df < 4; df++)
#pragma unroll
      for (int j = 0; j < 4; j++) {
        int r = qrow0 + mi * 16 + qg * 4 + j;
        int d = df * 16 + l15;
        float val = oacc[mi][df][j] / lrow[mi][j];
        o[(size_t)(tok0 + r) * D_MODEL + hoff + d] = f2bf(val);
      }
}

// ---------------- loss ----------------

__global__ void nll_finalize_kernel(const float* __restrict__ partM, const float* __restrict__ partS,
                                    const float* __restrict__ logits, const int* __restrict__ targets,
                                    float* __restrict__ nll) {
  int tok = blockIdx.x;
  int lane = threadIdx.x;    // 64
  const int NTL = V_SIZE >> 6;  // 500
  float m = -1e30f, s = 0.f;
  for (int i = lane; i < NTL; i += 64) {
    float m2 = partM[(size_t)tok * NTL + i];
    float s2 = partS[(size_t)tok * NTL + i];
    float nm = fmaxf(m, m2);
    s = s * expf(m - nm) + s2 * expf(m2 - nm);
    m = nm;
  }
#pragma unroll
  for (int mask = 1; mask < 64; mask <<= 1) {
    float m2 = __shfl_xor(m, mask, 64);
    float s2 = __shfl_xor(s, mask, 64);
    float nm = fmaxf(m, m2);
    s = s * expf(m - nm) + s2 * expf(m2 - nm);
    m = nm;
  }
  if (lane == 0)
    nll[tok] = m + logf(s) - logits[(size_t)tok * V_SIZE + targets[tok]];
}

__global__ void loss_reduce_kernel(const float* __restrict__ nll, float* __restrict__ out) {
  float s = 0.f;
  for (int i = threadIdx.x; i < BT; i += 256) s += nll[i];
#pragma unroll
  for (int mask = 1; mask < 64; mask <<= 1) s += __shfl_xor(s, mask, 64);
  __shared__ float sm[4];
  if ((threadIdx.x & 63) == 0) sm[threadIdx.x >> 6] = s;
  __syncthreads();
  if (threadIdx.x == 0) out[0] = (sm[0] + sm[1] + sm[2] + sm[3]) / (float)BT;
}

// ---------------- host launcher ----------------

extern "C" void kernel_launch(void* const* d_in, const int* in_sizes, int n_in,
                              void* d_out, int out_size, void* d_ws, size_t ws_size,
                              hipStream_t stream) {
  const int* idx = (const int*)d_in[0];
  const int* targets = (const int*)d_in[1];
  const float* embed = (const float*)d_in[2];
  const float* wq = (const float*)d_in[3];
  const float* wk = (const float*)d_in[4];
  const float* wv = (const float*)d_in[5];
  const float* wo = (const float*)d_in[6];
  const float* w_gate = (const float*)d_in[7];
  const float* w_up = (const float*)d_in[8];
  const float* w_down = (const float*)d_in[9];
  const float* attn_norm = (const float*)d_in[10];
  const float* mlp_norm = (const float*)d_in[11];
  const float* final_norm = (const float*)d_in[12];
  const float* lm_head = (const float*)d_in[13];
  float* out = (float*)d_out;

  char* ws = (char*)d_ws;
  size_t off = 0;
  auto alloc = [&](size_t bytes) {
    void* p = ws + off;
    off += (bytes + 255) & ~(size_t)255;
    return p;
  };
  const size_t DD = (size_t)D_MODEL * D_MODEL;
  float* rope_cos = (float*)alloc((size_t)TSEQ * 32 * 4);
  float* rope_sin = (float*)alloc((size_t)TSEQ * 32 * 4);
  float* X = (float*)alloc((size_t)BT * D_MODEL * 4);
  u16* Xb = (u16*)alloc((size_t)BT * D_MODEL * 2);
  float* Rinv = (float*)alloc((size_t)BT * 4);
  float* SsqP = (float*)alloc((size_t)BT * 16 * 4);
  u16* QKVb = (u16*)alloc((size_t)BT * QKV_STRIDE * 2);
  u16* Vtb = (u16*)alloc((size_t)32 * 64 * TSEQ * 2);
  u16* Ob = (u16*)alloc((size_t)BT * D_MODEL * 2);
  u16* Gb = (u16*)alloc((size_t)BT * HFF * 2);
  u16* WQKVT = (u16*)alloc((size_t)NLAYER * QKV_STRIDE * D_MODEL * 2);
  u16* WOT = (u16*)alloc((size_t)NLAYER * DD * 2);
  u16* WGU = (u16*)alloc((size_t)NLAYER * GU_STRIDE * D_MODEL * 2);
  u16* WDT = (u16*)alloc((size_t)NLAYER * D_MODEL * HFF * 2);
  u16* LMH = (u16*)alloc((size_t)V_SIZE * D_MODEL * 2);
  float* NLLb = (float*)alloc((size_t)BT * 4);
  float* PartM = (float*)alloc((size_t)BT * (V_SIZE >> 6) * 4);
  float* PartS = (float*)alloc((size_t)BT * (V_SIZE >> 6) * 4);

  rope_table_kernel<<<256, 256, 0, stream>>>(rope_cos, rope_sin);
  convert_bf16_kernel<<<4096, 256, 0, stream>>>(lm_head, LMH, final_norm, (long)V_SIZE * D_MODEL / 8);
  embed_gather_kernel<<<BT, 256, 0, stream>>>(idx, embed, X, Xb, Rinv);

  const long QKVW = (long)QKV_STRIDE * D_MODEL;
  const long GUW = (long)GU_STRIDE * D_MODEL;
  const long DW = (long)D_MODEL * HFF;
  // attn_norm folded into QKV weights; mlp_norm into gate/up weights
  transpose_bf16_kernel<<<dim3(32, 32, NLAYER), 256, 0, stream>>>(wq, WQKVT, D_MODEL, D_MODEL, DD, QKVW, 0, attn_norm, D_MODEL);
  transpose_bf16_kernel<<<dim3(32, 32, NLAYER), 256, 0, stream>>>(wk, WQKVT + DD, D_MODEL, D_MODEL, DD, QKVW, 0, attn_norm, D_MODEL);
  transpose_bf16_kernel<<<dim3(32, 32, NLAYER), 256, 0, stream>>>(wv, WQKVT + 2 * DD, D_MODEL, D_MODEL, DD, QKVW, 0, attn_norm, D_MODEL);
  transpose_bf16_kernel<<<dim3(32, 32, NLAYER), 256, 0, stream>>>(wo, WOT, D_MODEL, D_MODEL, DD, DD, 0, nullptr, 0);
  transpose_bf16_kernel<<<dim3(128, 32, NLAYER), 256, 0, stream>>>(w_gate, WGU, D_MODEL, HFF, DW, GUW, 1, mlp_norm, D_MODEL);
  transpose_bf16_kernel<<<dim3(128, 32, NLAYER), 256, 0, stream>>>(w_up, WGU, D_MODEL, HFF, DW, GUW, 2, mlp_norm, D_MODEL);
  transpose_bf16_kernel<<<dim3(32, 128, NLAYER), 256, 0, stream>>>(w_down, WDT, HFF, D_MODEL, DW, DW, 0, nullptr, 0);

  for (int l = 0; l < NLAYER; l++) {
    gemm128_kernel<4><<<(QKV_STRIDE / 128) * (BT / 128), 256, 0, stream>>>(
        Xb, WQKVT + (size_t)l * QKVW, QKVb, nullptr, nullptr, nullptr, rope_cos, rope_sin,
        nullptr, nullptr, Rinv, BT, QKV_STRIDE, D_MODEL, QKV_STRIDE / 128);
    vtrans_kernel<<<dim3(32, 32), 256, 0, stream>>>(QKVb, Vtb);
    attn_kernel<<<dim3(16, 32), 256, 0, stream>>>(QKVb, Vtb, Ob);
    gemm128_kernel<2><<<(D_MODEL / 128) * (BT / 128), 256, 0, stream>>>(
        Ob, WOT + (size_t)l * DD, X, X, nullptr, nullptr, nullptr, nullptr,
        Xb, SsqP, nullptr, BT, D_MODEL, D_MODEL, D_MODEL / 128);
    rinv_kernel<<<BT / 256, 256, 0, stream>>>(SsqP, Rinv);

    gemm128_kernel<5><<<(GU_STRIDE / 128) * (BT / 128), 256, 0, stream>>>(
        Xb, WGU + (size_t)l * GUW, Gb, nullptr, nullptr, nullptr, nullptr, nullptr,
        nullptr, nullptr, Rinv, BT, GU_STRIDE, D_MODEL, 32);
    gemm128_kernel<2><<<(D_MODEL / 128) * (BT / 128), 256, 0, stream>>>(
        Gb, WDT + (size_t)l * DW, X, X, nullptr, nullptr, nullptr, nullptr,
        Xb, SsqP, nullptr, BT, D_MODEL, HFF, D_MODEL / 128);
    rinv_kernel<<<BT / 256, 256, 0, stream>>>(SsqP, Rinv);
  }

  gemm128_kernel<0><<<(V_SIZE / 128) * (BT / 128), 256, 0, stream>>>(
      Xb, LMH, out, nullptr, PartM, PartS, nullptr, nullptr,
      nullptr, nullptr, Rinv, BT, V_SIZE, D_MODEL, 50);
  nll_finalize_kernel<<<BT, 64, 0, stream>>>(PartM, PartS, out, targets, NLLb);
  loss_reduce_kernel<<<1, 256, 0, stream>>>(NLLb, out + (size_t)BT * V_SIZE);
}

// Round 13
// 2178.298 us; speedup vs baseline: 1.5578x; 1.5578x over previous
//
#include <hip/hip_runtime.h>

typedef __attribute__((ext_vector_type(8))) short short8;
typedef __attribute__((ext_vector_type(4))) float f32x4;
typedef __attribute__((ext_vector_type(8))) unsigned short u16x8;
typedef unsigned short u16;

#define V_SIZE 32000
#define D_MODEL 1024
#define HFF 4096
#define NHEAD 16
#define HDIM 64
#define NLAYER 4
#define BT 4096   // B*T tokens
#define TSEQ 2048
#define QKV_STRIDE 3072
#define GU_STRIDE 8192

__device__ __forceinline__ u16 f2bf(float f) {
  union { float f; unsigned u; } v; v.f = f;
  unsigned r = v.u + 0x7fffu + ((v.u >> 16) & 1u);
  return (u16)(r >> 16);
}
__device__ __forceinline__ float bf2f(u16 h) {
  union { unsigned u; float f; } v; v.u = ((unsigned)h) << 16;
  return v.f;
}

__device__ __forceinline__ void gload_lds16(const void* g, void* l) {
  __builtin_amdgcn_global_load_lds((__attribute__((address_space(1))) void*)g,
                                   (__attribute__((address_space(3))) void*)l, 16, 0, 0);
}

// ---------------- elementwise / small kernels ----------------

__global__ void rope_table_kernel(float* __restrict__ cosb, float* __restrict__ sinb) {
  int i = blockIdx.x * 256 + threadIdx.x;       // 2048*32 = 65536 items
  int t = i >> 5, fi = i & 31;
  float freq = exp2f(-(2.0f * (float)fi / 64.0f) * log2f(10000.0f));
  float ang = (float)t * freq;
  cosb[i] = cosf(ang);
  sinb[i] = sinf(ang);
}

// lm_head fp32 -> bf16, scaled by final_norm[k] (k = flat index & 1023)
__global__ void convert_bf16_kernel(const float* __restrict__ src, u16* __restrict__ dst,
                                    const float* __restrict__ fn, long n8) {
  long i = (long)blockIdx.x * 256 + threadIdx.x;
  long stride = (long)gridDim.x * 256;
  for (; i < n8; i += stride) {
    const float4* s = (const float4*)(src + i * 8);
    float4 a = s[0], b = s[1];
    int k0 = (int)((i * 8) & (D_MODEL - 1));
    u16x8 r;
    r[0] = f2bf(a.x * fn[k0 + 0]); r[1] = f2bf(a.y * fn[k0 + 1]);
    r[2] = f2bf(a.z * fn[k0 + 2]); r[3] = f2bf(a.w * fn[k0 + 3]);
    r[4] = f2bf(b.x * fn[k0 + 4]); r[5] = f2bf(b.y * fn[k0 + 5]);
    r[6] = f2bf(b.z * fn[k0 + 6]); r[7] = f2bf(b.w * fn[k0 + 7]);
    *(u16x8*)(dst + i * 8) = r;
  }
}

// src [R][C] fp32 -> dst bf16, scaled by nw[src row] if nw != null (norm fold).
// rowMode: 0 -> dst row = c; 1 -> ((c>>6)<<7)|(c&63) (gate); 2 -> +64 (up)
__global__ __launch_bounds__(256) void transpose_bf16_kernel(const float* __restrict__ src0,
                                                             u16* __restrict__ dst0, int R, int C,
                                                             long srcStride, long dstStride,
                                                             int rowMode,
                                                             const float* __restrict__ nw0,
                                                             int nwStride) {
  __shared__ float tile[32][33];
  const float* src = src0 + (size_t)blockIdx.z * srcStride;
  u16* dst = dst0 + (size_t)blockIdx.z * dstStride;
  const float* nw = nw0 ? nw0 + (size_t)blockIdx.z * nwStride : nullptr;
  int tx = threadIdx.x & 31, ty = threadIdx.x >> 5;  // 32 x 8
  int bx = blockIdx.x, by = blockIdx.y;
#pragma unroll
  for (int i = 0; i < 32; i += 8) {
    int r = by * 32 + ty + i, c = bx * 32 + tx;
    tile[ty + i][tx] = src[(size_t)r * C + c];
  }
  __syncthreads();
#pragma unroll
  for (int i = 0; i < 32; i += 8) {
    int c = bx * 32 + ty + i;   // source col
    int r = by * 32 + tx;       // source row (k index) -> dst col
    float val = tile[tx][ty + i];
    if (nw) val *= nw[r];
    int drow = c;
    if (rowMode == 1) drow = ((c >> 6) << 7) | (c & 63);
    else if (rowMode == 2) drow = ((c >> 6) << 7) | 64 | (c & 63);
    dst[(size_t)drow * R + r] = f2bf(val);
  }
}

// embed gather: writes X fp32, Xb bf16, and rinv[t] (rms of the row). 1 block = 1 token.
__global__ __launch_bounds__(256) void embed_gather_kernel(const int* __restrict__ idx,
                                                           const float* __restrict__ embed,
                                                           float* __restrict__ x,
                                                           u16* __restrict__ xb,
                                                           float* __restrict__ rinv) {
  int t = blockIdx.x;
  int id = idx[t];
  float4 v = ((const float4*)embed)[(size_t)id * 256 + threadIdx.x];
  ((float4*)x)[(size_t)t * 256 + threadIdx.x] = v;
  u16* hp = xb + (size_t)t * D_MODEL + threadIdx.x * 4;
  hp[0] = f2bf(v.x); hp[1] = f2bf(v.y); hp[2] = f2bf(v.z); hp[3] = f2bf(v.w);
  float ss = v.x * v.x + v.y * v.y + v.z * v.z + v.w * v.w;
#pragma unroll
  for (int m = 32; m > 0; m >>= 1) ss += __shfl_xor(ss, m, 64);
  __shared__ float wsum[4];
  if ((threadIdx.x & 63) == 0) wsum[threadIdx.x >> 6] = ss;
  __syncthreads();
  if (threadIdx.x == 0) {
    float tot = wsum[0] + wsum[1] + wsum[2] + wsum[3];
    rinv[t] = rsqrtf(tot * (1.0f / (float)D_MODEL) + 1e-6f);
  }
}

// reduce 16 ssq partials per row -> rinv
__global__ void rinv_kernel(const float* __restrict__ ssqPart, float* __restrict__ rinv) {
  int r = blockIdx.x * 256 + threadIdx.x;   // BT rows
  float s = 0.f;
#pragma unroll
  for (int i = 0; i < 16; i++) s += ssqPart[(size_t)r * 16 + i];
  rinv[r] = rsqrtf(s * (1.0f / (float)D_MODEL) + 1e-6f);
}

// V (in QKV buffer) -> Vt [bh][64 d][TSEQ t] bf16, tile-transposed via LDS.
__global__ __launch_bounds__(256) void vtrans_kernel(const u16* __restrict__ qkv,
                                                     u16* __restrict__ vt) {
  __shared__ u16 lds[64 * 64];
  const int tid = threadIdx.x;
  const int bh = blockIdx.y, tt = blockIdx.x;
  const int b = bh >> 4, h = bh & 15;
  const int tok0 = b * TSEQ + tt * 64;
  const int hoff = 2 * D_MODEL + h * HDIM;
#pragma unroll
  for (int it = 0; it < 2; it++) {
    int idx = it * 256 + tid;
    int row = idx >> 3, c = (idx & 7) * 8;
    short8 v = *(const short8*)(qkv + (size_t)(tok0 + row) * QKV_STRIDE + hoff + c);
    *(short8*)&lds[row * 64 + (c ^ ((row & 7) << 3))] = v;
  }
  __syncthreads();
#pragma unroll
  for (int it = 0; it < 2; it++) {
    int idx = it * 256 + tid;
    int d = idx >> 3, t0 = (idx & 7) * 8;
    u16x8 pk;
#pragma unroll
    for (int j = 0; j < 8; j++) {
      int t = t0 + j;
      pk[j] = lds[t * 64 + (((d & ~7) ^ ((t & 7) << 3)) | (d & 7))];
    }
    *(u16x8*)(vt + ((size_t)bh * 64 + d) * TSEQ + tt * 64 + t0) = pk;
  }
}

// ---------------- GEMM 128x128 (m97 structure, both-sides swizzle, 4 blocks/CU) ----
// C[M,N] = A[M,K](bf16) * B[N,K](bf16)^T. 256 threads = 4 waves (2x2).
// 4 waves/SIMD: 60 VGPR + 64 AGPR acc = 124 <= 128/wave budget -> NO SPILL.
// (5 waves/SIMD caps at ~102 regs and spills the accumulators -> 2x slower, R12.)
// bn-chunked; bm-fast XCD-local order (R11): 1 L2 fill per B-panel per XCD.
// EPI: 0 = lm-head: vv *= rinv; fp32 nontemporal store + LSE partials
//      2 = residual add; also writes Xb bf16 + 16 ssq partials/row (norm fold)
//      4 = QKV: vv *= rinv, fused RoPE on cols < 2048, bf16 store
//      5 = GU fused silu-mul: g,u *= rinv before silu; LDS exchange; N/2 store
template <int EPI>
__global__ __launch_bounds__(256, 4) void gemm128_kernel(const u16* __restrict__ A,
                                                         const u16* __restrict__ B, void* Cp,
                                                         const float* __restrict__ resid,
                                                         float* __restrict__ partM,
                                                         float* __restrict__ partS,
                                                         const float* __restrict__ cosb,
                                                         const float* __restrict__ sinb,
                                                         u16* __restrict__ xbout,
                                                         float* __restrict__ ssqPart,
                                                         const float* __restrict__ rinv,
                                                         int M, int N, int K, int chunkBn) {
  __shared__ __align__(16) u16 smem_ab[2][128 * 64];   // 32 KiB total
  u16* As = smem_ab[0];
  u16* Bs = smem_ab[1];
  const int tid = threadIdx.x;
  const int lane = tid & 63, wid = tid >> 6;
  const int wr = wid >> 1, wc = wid & 1;
  const int q = lane >> 4, l15 = lane & 15;
  const int nbm = M >> 7;
  const int nbmx = nbm >> 3;               // bm rows per XCD (4)
  const int cs = nbm * chunkBn;            // blocks per chunk
  const int chunk = (int)blockIdx.x / cs;
  const int r0 = (int)blockIdx.x - chunk * cs;
  const int s2 = r0 >> 3;
  const int bm = (r0 & 7) * nbmx + (s2 % nbmx);
  const int bn = chunk * chunkBn + (s2 / nbmx);
  const size_t abase = (size_t)bm * 128 * K;
  const size_t bbase = (size_t)bn * 128 * K;
  f32x4 acc[4][4] = {};
  for (int k0 = 0; k0 < K; k0 += 64) {
#pragma unroll
    for (int i = 0; i < 4; i++) {
      int idx8 = i * 256 + tid;
      int row = idx8 >> 3, ch = idx8 & 7;
      int sc = (ch ^ (row & 7)) << 3;
      gload_lds16(A + abase + (size_t)row * K + k0 + sc, As + idx8 * 8);
      gload_lds16(B + bbase + (size_t)row * K + k0 + sc, Bs + idx8 * 8);
    }
    __syncthreads();
#pragma unroll
    for (int ks = 0; ks < 2; ks++) {
      short8 af[4], bfr[4];
      int chunkc = ks * 4 + q;
#pragma unroll
      for (int mi = 0; mi < 4; mi++) {
        int row = wr * 64 + mi * 16 + l15;
        af[mi] = *(const short8*)&As[row * 64 + ((chunkc ^ (row & 7)) << 3)];
      }
#pragma unroll
      for (int ni = 0; ni < 4; ni++) {
        int row = wc * 64 + ni * 16 + l15;
        bfr[ni] = *(const short8*)&Bs[row * 64 + ((chunkc ^ (row & 7)) << 3)];
      }
#pragma unroll
      for (int mi = 0; mi < 4; mi++)
#pragma unroll
        for (int ni = 0; ni < 4; ni++)
          acc[mi][ni] = __builtin_amdgcn_mfma_f32_16x16x32_bf16(af[mi], bfr[ni], acc[mi][ni], 0, 0, 0);
    }
    __syncthreads();
  }

  // ---- EPI 5: fused silu-mul via cross-wave LDS exchange (rinv applied pre-silu) ----
  if (EPI == 5) {
    float* upf = (float*)&smem_ab[0][0];   // 128x64 floats = 32 KiB
    if (wc == 1) {
#pragma unroll
      for (int mi = 0; mi < 4; mi++)
#pragma unroll
        for (int ni = 0; ni < 4; ni++)
#pragma unroll
          for (int j = 0; j < 4; j++) {
            int r = wr * 64 + mi * 16 + q * 4 + j;
            int cswz = (ni ^ ((r >> 2) & 3)) * 16 + l15;
            upf[r * 64 + cswz] = acc[mi][ni][j];
          }
    }
    __syncthreads();
    if (wc == 0) {
#pragma unroll
      for (int mi = 0; mi < 4; mi++)
#pragma unroll
        for (int j = 0; j < 4; j++) {
          int rloc = wr * 64 + mi * 16 + q * 4 + j;
          int rr = bm * 128 + rloc;
          float ri = rinv[rr];
#pragma unroll
          for (int ni = 0; ni < 4; ni++) {
            int cswz = (ni ^ ((rloc >> 2) & 3)) * 16 + l15;
            float g = acc[mi][ni][j] * ri;
            float u = upf[rloc * 64 + cswz] * ri;
            float rsl = g / (1.0f + expf(-g)) * u;
            ((u16*)Cp)[(size_t)rr * (N >> 1) + bn * 64 + ni * 16 + l15] = f2bf(rsl);
          }
        }
    }
    return;
  }

  // ---- EPI 2: residual add + Xb bf16 + ssq partials ----
  if (EPI == 2) {
#pragma unroll
    for (int mi = 0; mi < 4; mi++)
#pragma unroll
      for (int j = 0; j < 4; j++) {
        int rr = bm * 128 + wr * 64 + mi * 16 + q * 4 + j;
        float ssq = 0.f;
#pragma unroll
        for (int ni = 0; ni < 4; ni++) {
          int cn = bn * 128 + wc * 64 + ni * 16 + l15;
          size_t off = (size_t)rr * N + cn;
          float nx = resid[off] + acc[mi][ni][j];
          ((float*)Cp)[off] = nx;
          xbout[off] = f2bf(nx);
          ssq += nx * nx;
        }
        ssq += __shfl_xor(ssq, 1, 64);
        ssq += __shfl_xor(ssq, 2, 64);
        ssq += __shfl_xor(ssq, 4, 64);
        ssq += __shfl_xor(ssq, 8, 64);
        if (l15 == 0) ssqPart[(size_t)rr * 16 + (bn << 1) + wc] = ssq;
      }
    return;
  }

  // ---- EPI 0 / 4 ----
#pragma unroll
  for (int mi = 0; mi < 4; mi++)
#pragma unroll
    for (int j = 0; j < 4; j++) {
      int rr = bm * 128 + wr * 64 + mi * 16 + q * 4 + j;
      float ri = rinv[rr];
      float vv[4];
#pragma unroll
      for (int ni = 0; ni < 4; ni++) vv[ni] = acc[mi][ni][j] * ri;
      if (EPI == 0) {
        float mx = fmaxf(fmaxf(vv[0], vv[1]), fmaxf(vv[2], vv[3]));
        mx = fmaxf(mx, __shfl_xor(mx, 1, 64));
        mx = fmaxf(mx, __shfl_xor(mx, 2, 64));
        mx = fmaxf(mx, __shfl_xor(mx, 4, 64));
        mx = fmaxf(mx, __shfl_xor(mx, 8, 64));
        float sm = 0.f;
#pragma unroll
        for (int ni = 0; ni < 4; ni++) sm += expf(vv[ni] - mx);
        sm += __shfl_xor(sm, 1, 64);
        sm += __shfl_xor(sm, 2, 64);
        sm += __shfl_xor(sm, 4, 64);
        sm += __shfl_xor(sm, 8, 64);
        if (l15 == 0) {
          int nt = (N >> 6);
          partM[(size_t)rr * nt + (bn << 1) + wc] = mx;
          partS[(size_t)rr * nt + (bn << 1) + wc] = sm;
        }
      }
      if (EPI == 4) {
        if (((bn << 1) + wc) < 32) {   // Q or K cols: wave-uniform
          int t = rr & (TSEQ - 1);
#pragma unroll
          for (int ni = 0; ni < 2; ni++) {
            int fi = ni * 16 + l15;
            float c = cosb[t * 32 + fi], s = sinb[t * 32 + fi];
            float x1 = vv[ni], x2 = vv[ni + 2];
            vv[ni] = x1 * c - x2 * s;
            vv[ni + 2] = x2 * c + x1 * s;
          }
        }
      }
#pragma unroll
      for (int ni = 0; ni < 4; ni++) {
        int cn = bn * 128 + wc * 64 + ni * 16 + l15;
        size_t off = (size_t)rr * N + cn;
        if (EPI == 0) __builtin_nontemporal_store(vv[ni], (float*)Cp + off);
        else ((u16*)Cp)[off] = f2bf(vv[ni]);
      }
    }
}

// ---------------- flash attention ----------------
__global__ __launch_bounds__(256) void attn_kernel(const u16* __restrict__ qkv,
                                                   const u16* __restrict__ vt,
                                                   u16* __restrict__ o) {
  __shared__ __align__(16) u16 Ks[64 * 64];
  __shared__ __align__(16) u16 Vt[64 * 64];
  __shared__ u16 Ps[4][32 * 64];
  const u16* q = qkv;
  const u16* k = qkv + D_MODEL;
  const int tid = threadIdx.x, lane = tid & 63, wid = tid >> 6;
  const int qg = lane >> 4, l15 = lane & 15;
  const int qt = blockIdx.x;
  const int bh = blockIdx.y;
  const int b = bh >> 4, h = bh & 15;
  const int tok0 = b * TSEQ;
  const int hoff = h * HDIM;
  const int qrow0 = qt * 128 + wid * 32;
  const u16* vtb = vt + (size_t)bh * 64 * TSEQ;

  short8 aq[2][2];
#pragma unroll
  for (int mi = 0; mi < 2; mi++)
#pragma unroll
    for (int ks = 0; ks < 2; ks++) {
      int r = qrow0 + mi * 16 + l15;
      int d = ks * 32 + qg * 8;
      aq[mi][ks] = *(const short8*)(q + (size_t)(tok0 + r) * QKV_STRIDE + hoff + d);
    }
  f32x4 oacc[2][4] = {};
  float mrow[2][4], lrow[2][4];
#pragma unroll
  for (int mi = 0; mi < 2; mi++)
#pragma unroll
    for (int j = 0; j < 4; j++) { mrow[mi][j] = -1e30f; lrow[mi][j] = 0.f; }

  const int nkt = (qt + 1) * 2;
  for (int kt = 0; kt < nkt; kt++) {
    const int kv0 = kt * 64;
#pragma unroll
    for (int it = 0; it < 2; it++) {
      int idx = it * 256 + tid;
      int row = idx >> 3, ch = idx & 7;
      int sc = (ch ^ (row & 7)) << 3;
      gload_lds16(k + (size_t)(tok0 + kv0 + row) * QKV_STRIDE + hoff + sc, Ks + idx * 8);
      gload_lds16(vtb + (size_t)row * TSEQ + kv0 + sc, Vt + idx * 8);
    }
    __syncthreads();
    f32x4 sc[2][4] = {};
#pragma unroll
    for (int ks = 0; ks < 2; ks++) {
      short8 bk[4];
      int kcol = ks * 32 + qg * 8;
#pragma unroll
      for (int ni = 0; ni < 4; ni++) {
        int r = ni * 16 + l15;
        bk[ni] = *(const short8*)&Ks[r * 64 + (kcol ^ ((r & 7) << 3))];
      }
#pragma unroll
      for (int mi = 0; mi < 2; mi++)
#pragma unroll
        for (int ni = 0; ni < 4; ni++)
          sc[mi][ni] = __builtin_amdgcn_mfma_f32_16x16x32_bf16(aq[mi][ks], bk[ni], sc[mi][ni], 0, 0, 0);
    }
    float pm[2][4];
#pragma unroll
    for (int mi = 0; mi < 2; mi++)
#pragma unroll
      for (int j = 0; j < 4; j++) pm[mi][j] = -1e30f;
#pragma unroll
    for (int mi = 0; mi < 2; mi++)
#pragma unroll
      for (int ni = 0; ni < 4; ni++)
#pragma unroll
        for (int j = 0; j < 4; j++) {
          int rq = qrow0 + mi * 16 + qg * 4 + j;
          int ck = kv0 + ni * 16 + l15;
          float s = sc[mi][ni][j] * 0.125f;
          if (ck > rq) s = -1e30f;
          sc[mi][ni][j] = s;
          pm[mi][j] = fmaxf(pm[mi][j], s);
        }
#pragma unroll
    for (int mi = 0; mi < 2; mi++)
#pragma unroll
      for (int j = 0; j < 4; j++) {
        float t = pm[mi][j];
        t = fmaxf(t, __shfl_xor(t, 1, 64));
        t = fmaxf(t, __shfl_xor(t, 2, 64));
        t = fmaxf(t, __shfl_xor(t, 4, 64));
        t = fmaxf(t, __shfl_xor(t, 8, 64));
        pm[mi][j] = t;
      }
#pragma unroll
    for (int mi = 0; mi < 2; mi++)
#pragma unroll
      for (int j = 0; j < 4; j++) {
        float mn = fmaxf(mrow[mi][j], pm[mi][j]);
        float fac = expf(mrow[mi][j] - mn);
        lrow[mi][j] *= fac;
#pragma unroll
        for (int df = 0; df < 4; df++) oacc[mi][df][j] *= fac;
        mrow[mi][j] = mn;
      }
    float psum[2][4] = {};
#pragma unroll
    for (int mi = 0; mi < 2; mi++)
#pragma unroll
      for (int ni = 0; ni < 4; ni++)
#pragma unroll
        for (int j = 0; j < 4; j++) {
          float p = expf(sc[mi][ni][j] - mrow[mi][j]);
          psum[mi][j] += p;
          int r32 = mi * 16 + qg * 4 + j;
          int cc = ni * 16 + l15;
          Ps[wid][r32 * 64 + (cc ^ ((r32 & 7) << 3))] = f2bf(p);
        }
#pragma unroll
    for (int mi = 0; mi < 2; mi++)
#pragma unroll
      for (int j = 0; j < 4; j++) {
        float t = psum[mi][j];
        t += __shfl_xor(t, 1, 64);
        t += __shfl_xor(t, 2, 64);
        t += __shfl_xor(t, 4, 64);
        t += __shfl_xor(t, 8, 64);
        lrow[mi][j] += t;
      }
#pragma unroll
    for (int kf = 0; kf < 2; kf++) {
      short8 pa[2], bv[4];
      int kcol = kf * 32 + qg * 8;
#pragma unroll
      for (int mi = 0; mi < 2; mi++) {
        int r = mi * 16 + l15;
        pa[mi] = *(const short8*)&Ps[wid][r * 64 + (kcol ^ ((r & 7) << 3))];
      }
#pragma unroll
      for (int df = 0; df < 4; df++) {
        int r = df * 16 + l15;
        bv[df] = *(const short8*)&Vt[r * 64 + (kcol ^ ((r & 7) << 3))];
      }
#pragma unroll
      for (int mi = 0; mi < 2; mi++)
#pragma unroll
        for (int df = 0; df < 4; df++)
          oacc[mi][df] = __builtin_amdgcn_mfma_f32_16x16x32_bf16(pa[mi], bv[df], oacc[mi][df], 0, 0, 0);
    }
    __syncthreads();
  }
#pragma unroll
  for (int mi = 0; mi < 2; mi++)
#pragma unroll
    for (int df = 0; df < 4; df++)
#pragma unroll
      for (int j = 0; j < 4; j++) {
        int r = qrow0 + mi * 16 + qg * 4 + j;
        int d = df * 16 + l15;
        float val = oacc[mi][df][j] / lrow[mi][j];
        o[(size_t)(tok0 + r) * D_MODEL + hoff + d] = f2bf(val);
      }
}

// ---------------- loss ----------------

__global__ void nll_finalize_kernel(const float* __restrict__ partM, const float* __restrict__ partS,
                                    const float* __restrict__ logits, const int* __restrict__ targets,
                                    float* __restrict__ nll) {
  int tok = blockIdx.x;
  int lane = threadIdx.x;    // 64
  const int NTL = V_SIZE >> 6;  // 500
  float m = -1e30f, s = 0.f;
  for (int i = lane; i < NTL; i += 64) {
    float m2 = partM[(size_t)tok * NTL + i];
    float s2 = partS[(size_t)tok * NTL + i];
    float nm = fmaxf(m, m2);
    s = s * expf(m - nm) + s2 * expf(m2 - nm);
    m = nm;
  }
#pragma unroll
  for (int mask = 1; mask < 64; mask <<= 1) {
    float m2 = __shfl_xor(m, mask, 64);
    float s2 = __shfl_xor(s, mask, 64);
    float nm = fmaxf(m, m2);
    s = s * expf(m - nm) + s2 * expf(m2 - nm);
    m = nm;
  }
  if (lane == 0)
    nll[tok] = m + logf(s) - logits[(size_t)tok * V_SIZE + targets[tok]];
}

__global__ void loss_reduce_kernel(const float* __restrict__ nll, float* __restrict__ out) {
  float s = 0.f;
  for (int i = threadIdx.x; i < BT; i += 256) s += nll[i];
#pragma unroll
  for (int mask = 1; mask < 64; mask <<= 1) s += __shfl_xor(s, mask, 64);
  __shared__ float sm[4];
  if ((threadIdx.x & 63) == 0) sm[threadIdx.x >> 6] = s;
  __syncthreads();
  if (threadIdx.x == 0) out[0] = (sm[0] + sm[1] + sm[2] + sm[3]) / (float)BT;
}

// ---------------- host launcher ----------------

extern "C" void kernel_launch(void* const* d_in, const int* in_sizes, int n_in,
                              void* d_out, int out_size, void* d_ws, size_t ws_size,
                              hipStream_t stream) {
  const int* idx = (const int*)d_in[0];
  const int* targets = (const int*)d_in[1];
  const float* embed = (const float*)d_in[2];
  const float* wq = (const float*)d_in[3];
  const float* wk = (const float*)d_in[4];
  const float* wv = (const float*)d_in[5];
  const float* wo = (const float*)d_in[6];
  const float* w_gate = (const float*)d_in[7];
  const float* w_up = (const float*)d_in[8];
  const float* w_down = (const float*)d_in[9];
  const float* attn_norm = (const float*)d_in[10];
  const float* mlp_norm = (const float*)d_in[11];
  const float* final_norm = (const float*)d_in[12];
  const float* lm_head = (const float*)d_in[13];
  float* out = (float*)d_out;

  char* ws = (char*)d_ws;
  size_t off = 0;
  auto alloc = [&](size_t bytes) {
    void* p = ws + off;
    off += (bytes + 255) & ~(size_t)255;
    return p;
  };
  const size_t DD = (size_t)D_MODEL * D_MODEL;
  float* rope_cos = (float*)alloc((size_t)TSEQ * 32 * 4);
  float* rope_sin = (float*)alloc((size_t)TSEQ * 32 * 4);
  float* X = (float*)alloc((size_t)BT * D_MODEL * 4);
  u16* Xb = (u16*)alloc((size_t)BT * D_MODEL * 2);
  float* Rinv = (float*)alloc((size_t)BT * 4);
  float* SsqP = (float*)alloc((size_t)BT * 16 * 4);
  u16* QKVb = (u16*)alloc((size_t)BT * QKV_STRIDE * 2);
  u16* Vtb = (u16*)alloc((size_t)32 * 64 * TSEQ * 2);
  u16* Ob = (u16*)alloc((size_t)BT * D_MODEL * 2);
  u16* Gb = (u16*)alloc((size_t)BT * HFF * 2);
  u16* WQKVT = (u16*)alloc((size_t)NLAYER * QKV_STRIDE * D_MODEL * 2);
  u16* WOT = (u16*)alloc((size_t)NLAYER * DD * 2);
  u16* WGU = (u16*)alloc((size_t)NLAYER * GU_STRIDE * D_MODEL * 2);
  u16* WDT = (u16*)alloc((size_t)NLAYER * D_MODEL * HFF * 2);
  u16* LMH = (u16*)alloc((size_t)V_SIZE * D_MODEL * 2);
  float* NLLb = (float*)alloc((size_t)BT * 4);
  float* PartM = (float*)alloc((size_t)BT * (V_SIZE >> 6) * 4);
  float* PartS = (float*)alloc((size_t)BT * (V_SIZE >> 6) * 4);

  rope_table_kernel<<<256, 256, 0, stream>>>(rope_cos, rope_sin);
  convert_bf16_kernel<<<4096, 256, 0, stream>>>(lm_head, LMH, final_norm, (long)V_SIZE * D_MODEL / 8);
  embed_gather_kernel<<<BT, 256, 0, stream>>>(idx, embed, X, Xb, Rinv);

  const long QKVW = (long)QKV_STRIDE * D_MODEL;
  const long GUW = (long)GU_STRIDE * D_MODEL;
  const long DW = (long)D_MODEL * HFF;
  // attn_norm folded into QKV weights; mlp_norm into gate/up weights
  transpose_bf16_kernel<<<dim3(32, 32, NLAYER), 256, 0, stream>>>(wq, WQKVT, D_MODEL, D_MODEL, DD, QKVW, 0, attn_norm, D_MODEL);
  transpose_bf16_kernel<<<dim3(32, 32, NLAYER), 256, 0, stream>>>(wk, WQKVT + DD, D_MODEL, D_MODEL, DD, QKVW, 0, attn_norm, D_MODEL);
  transpose_bf16_kernel<<<dim3(32, 32, NLAYER), 256, 0, stream>>>(wv, WQKVT + 2 * DD, D_MODEL, D_MODEL, DD, QKVW, 0, attn_norm, D_MODEL);
  transpose_bf16_kernel<<<dim3(32, 32, NLAYER), 256, 0, stream>>>(wo, WOT, D_MODEL, D_MODEL, DD, DD, 0, nullptr, 0);
  transpose_bf16_kernel<<<dim3(128, 32, NLAYER), 256, 0, stream>>>(w_gate, WGU, D_MODEL, HFF, DW, GUW, 1, mlp_norm, D_MODEL);
  transpose_bf16_kernel<<<dim3(128, 32, NLAYER), 256, 0, stream>>>(w_up, WGU, D_MODEL, HFF, DW, GUW, 2, mlp_norm, D_MODEL);
  transpose_bf16_kernel<<<dim3(32, 128, NLAYER), 256, 0, stream>>>(w_down, WDT, HFF, D_MODEL, DW, DW, 0, nullptr, 0);

  for (int l = 0; l < NLAYER; l++) {
    gemm128_kernel<4><<<(QKV_STRIDE / 128) * (BT / 128), 256, 0, stream>>>(
        Xb, WQKVT + (size_t)l * QKVW, QKVb, nullptr, nullptr, nullptr, rope_cos, rope_sin,
        nullptr, nullptr, Rinv, BT, QKV_STRIDE, D_MODEL, QKV_STRIDE / 128);
    vtrans_kernel<<<dim3(32, 32), 256, 0, stream>>>(QKVb, Vtb);
    attn_kernel<<<dim3(16, 32), 256, 0, stream>>>(QKVb, Vtb, Ob);
    gemm128_kernel<2><<<(D_MODEL / 128) * (BT / 128), 256, 0, stream>>>(
        Ob, WOT + (size_t)l * DD, X, X, nullptr, nullptr, nullptr, nullptr,
        Xb, SsqP, nullptr, BT, D_MODEL, D_MODEL, D_MODEL / 128);
    rinv_kernel<<<BT / 256, 256, 0, stream>>>(SsqP, Rinv);

    gemm128_kernel<5><<<(GU_STRIDE / 128) * (BT / 128), 256, 0, stream>>>(
        Xb, WGU + (size_t)l * GUW, Gb, nullptr, nullptr, nullptr, nullptr, nullptr,
        nullptr, nullptr, Rinv, BT, GU_STRIDE, D_MODEL, 32);
    gemm128_kernel<2><<<(D_MODEL / 128) * (BT / 128), 256, 0, stream>>>(
        Gb, WDT + (size_t)l * DW, X, X, nullptr, nullptr, nullptr, nullptr,
        Xb, SsqP, nullptr, BT, D_MODEL, HFF, D_MODEL / 128);
    rinv_kernel<<<BT / 256, 256, 0, stream>>>(SsqP, Rinv);
  }

  gemm128_kernel<0><<<(V_SIZE / 128) * (BT / 128), 256, 0, stream>>>(
      Xb, LMH, out, nullptr, PartM, PartS, nullptr, nullptr,
      nullptr, nullptr, Rinv, BT, V_SIZE, D_MODEL, 50);
  nll_finalize_kernel<<<BT, 64, 0, stream>>>(PartM, PartS, out, targets, NLLb);
  loss_reduce_kernel<<<1, 256, 0, stream>>>(NLLb, out + (size_t)BT * V_SIZE);
}

// Round 14
// 2004.992 us; speedup vs baseline: 1.6925x; 1.0864x over previous
//
#include <hip/hip_runtime.h>

typedef __attribute__((ext_vector_type(8))) short short8;
typedef __attribute__((ext_vector_type(4))) float f32x4;
typedef __attribute__((ext_vector_type(8))) unsigned short u16x8;
typedef unsigned short u16;

#define V_SIZE 32000
#define D_MODEL 1024
#define HFF 4096
#define NHEAD 16
#define HDIM 64
#define NLAYER 4
#define BT 4096   // B*T tokens
#define TSEQ 2048
#define QKV_STRIDE 3072
#define GU_STRIDE 8192

__device__ __forceinline__ u16 f2bf(float f) {
  union { float f; unsigned u; } v; v.f = f;
  unsigned r = v.u + 0x7fffu + ((v.u >> 16) & 1u);
  return (u16)(r >> 16);
}
__device__ __forceinline__ float bf2f(u16 h) {
  union { unsigned u; float f; } v; v.u = ((unsigned)h) << 16;
  return v.f;
}

__device__ __forceinline__ void gload_lds16(const void* g, void* l) {
  __builtin_amdgcn_global_load_lds((__attribute__((address_space(1))) void*)g,
                                   (__attribute__((address_space(3))) void*)l, 16, 0, 0);
}

// ---------------- elementwise / small kernels ----------------

__global__ void rope_table_kernel(float* __restrict__ cosb, float* __restrict__ sinb) {
  int i = blockIdx.x * 256 + threadIdx.x;       // 2048*32 = 65536 items
  int t = i >> 5, fi = i & 31;
  float freq = exp2f(-(2.0f * (float)fi / 64.0f) * log2f(10000.0f));
  float ang = (float)t * freq;
  cosb[i] = cosf(ang);
  sinb[i] = sinf(ang);
}

// lm_head fp32 -> bf16, scaled by final_norm[k] (k = flat index & 1023)
__global__ void convert_bf16_kernel(const float* __restrict__ src, u16* __restrict__ dst,
                                    const float* __restrict__ fn, long n8) {
  long i = (long)blockIdx.x * 256 + threadIdx.x;
  long stride = (long)gridDim.x * 256;
  for (; i < n8; i += stride) {
    const float4* s = (const float4*)(src + i * 8);
    float4 a = s[0], b = s[1];
    int k0 = (int)((i * 8) & (D_MODEL - 1));
    u16x8 r;
    r[0] = f2bf(a.x * fn[k0 + 0]); r[1] = f2bf(a.y * fn[k0 + 1]);
    r[2] = f2bf(a.z * fn[k0 + 2]); r[3] = f2bf(a.w * fn[k0 + 3]);
    r[4] = f2bf(b.x * fn[k0 + 4]); r[5] = f2bf(b.y * fn[k0 + 5]);
    r[6] = f2bf(b.z * fn[k0 + 6]); r[7] = f2bf(b.w * fn[k0 + 7]);
    *(u16x8*)(dst + i * 8) = r;
  }
}

// src [R][C] fp32 -> dst bf16, scaled by nw[src row] if nw != null (norm fold).
// rowMode: 0 -> dst row = c; 1 -> ((c>>6)<<7)|(c&63) (gate); 2 -> +64 (up)
__global__ __launch_bounds__(256) void transpose_bf16_kernel(const float* __restrict__ src0,
                                                             u16* __restrict__ dst0, int R, int C,
                                                             long srcStride, long dstStride,
                                                             int rowMode,
                                                             const float* __restrict__ nw0,
                                                             int nwStride) {
  __shared__ float tile[32][33];
  const float* src = src0 + (size_t)blockIdx.z * srcStride;
  u16* dst = dst0 + (size_t)blockIdx.z * dstStride;
  const float* nw = nw0 ? nw0 + (size_t)blockIdx.z * nwStride : nullptr;
  int tx = threadIdx.x & 31, ty = threadIdx.x >> 5;  // 32 x 8
  int bx = blockIdx.x, by = blockIdx.y;
#pragma unroll
  for (int i = 0; i < 32; i += 8) {
    int r = by * 32 + ty + i, c = bx * 32 + tx;
    tile[ty + i][tx] = src[(size_t)r * C + c];
  }
  __syncthreads();
#pragma unroll
  for (int i = 0; i < 32; i += 8) {
    int c = bx * 32 + ty + i;   // source col
    int r = by * 32 + tx;       // source row (k index) -> dst col
    float val = tile[tx][ty + i];
    if (nw) val *= nw[r];
    int drow = c;
    if (rowMode == 1) drow = ((c >> 6) << 7) | (c & 63);
    else if (rowMode == 2) drow = ((c >> 6) << 7) | 64 | (c & 63);
    dst[(size_t)drow * R + r] = f2bf(val);
  }
}

// embed gather: writes X fp32, Xb bf16, and rinv[t] (rms of the row). 1 block = 1 token.
__global__ __launch_bounds__(256) void embed_gather_kernel(const int* __restrict__ idx,
                                                           const float* __restrict__ embed,
                                                           float* __restrict__ x,
                                                           u16* __restrict__ xb,
                                                           float* __restrict__ rinv) {
  int t = blockIdx.x;
  int id = idx[t];
  float4 v = ((const float4*)embed)[(size_t)id * 256 + threadIdx.x];
  ((float4*)x)[(size_t)t * 256 + threadIdx.x] = v;
  u16* hp = xb + (size_t)t * D_MODEL + threadIdx.x * 4;
  hp[0] = f2bf(v.x); hp[1] = f2bf(v.y); hp[2] = f2bf(v.z); hp[3] = f2bf(v.w);
  float ss = v.x * v.x + v.y * v.y + v.z * v.z + v.w * v.w;
#pragma unroll
  for (int m = 32; m > 0; m >>= 1) ss += __shfl_xor(ss, m, 64);
  __shared__ float wsum[4];
  if ((threadIdx.x & 63) == 0) wsum[threadIdx.x >> 6] = ss;
  __syncthreads();
  if (threadIdx.x == 0) {
    float tot = wsum[0] + wsum[1] + wsum[2] + wsum[3];
    rinv[t] = rsqrtf(tot * (1.0f / (float)D_MODEL) + 1e-6f);
  }
}

// reduce 16 ssq partials per row -> rinv
__global__ void rinv_kernel(const float* __restrict__ ssqPart, float* __restrict__ rinv) {
  int r = blockIdx.x * 256 + threadIdx.x;   // BT rows
  float s = 0.f;
#pragma unroll
  for (int i = 0; i < 16; i++) s += ssqPart[(size_t)r * 16 + i];
  rinv[r] = rsqrtf(s * (1.0f / (float)D_MODEL) + 1e-6f);
}

// XbF = Xb * rinv[row] (bf16, vectorized). 2048 blocks x 256 thr x 8 elems.
__global__ void scale_xb_kernel(const u16* __restrict__ xb, const float* __restrict__ rinv,
                                u16* __restrict__ xbf) {
  long i = (long)blockIdx.x * 256 + threadIdx.x;   // item = 8 elems
  int row = (int)(i >> 7);                         // 128 items per 1024-elem row
  float ri = rinv[row];
  short8 v = *(const short8*)(xb + i * 8);
  u16x8 r;
#pragma unroll
  for (int j = 0; j < 8; j++) r[j] = f2bf(bf2f((u16)v[j]) * ri);
  *(u16x8*)(xbf + i * 8) = r;
}

// V (in QKV buffer) -> Vt [bh][64 d][TSEQ t] bf16, tile-transposed via LDS.
__global__ __launch_bounds__(256) void vtrans_kernel(const u16* __restrict__ qkv,
                                                     u16* __restrict__ vt) {
  __shared__ u16 lds[64 * 64];
  const int tid = threadIdx.x;
  const int bh = blockIdx.y, tt = blockIdx.x;
  const int b = bh >> 4, h = bh & 15;
  const int tok0 = b * TSEQ + tt * 64;
  const int hoff = 2 * D_MODEL + h * HDIM;
#pragma unroll
  for (int it = 0; it < 2; it++) {
    int idx = it * 256 + tid;
    int row = idx >> 3, c = (idx & 7) * 8;
    short8 v = *(const short8*)(qkv + (size_t)(tok0 + row) * QKV_STRIDE + hoff + c);
    *(short8*)&lds[row * 64 + (c ^ ((row & 7) << 3))] = v;
  }
  __syncthreads();
#pragma unroll
  for (int it = 0; it < 2; it++) {
    int idx = it * 256 + tid;
    int d = idx >> 3, t0 = (idx & 7) * 8;
    u16x8 pk;
#pragma unroll
    for (int j = 0; j < 8; j++) {
      int t = t0 + j;
      pk[j] = lds[t * 64 + (((d & ~7) ^ ((t & 7) << 3)) | (d & 7))];
    }
    *(u16x8*)(vt + ((size_t)bh * 64 + d) * TSEQ + tt * 64 + t0) = pk;
  }
}

// ---------------- GEMM 128x128 (m97 structure, both-sides swizzle, 4 blocks/CU) ----
// C[M,N] = A[M,K](bf16) * B[N,K](bf16)^T. 256 threads = 4 waves (2x2).
// 4 waves/SIMD: 60 VGPR + 64 AGPR acc = 124 <= 128/wave budget -> NO SPILL.
// (5 waves/SIMD caps at ~102 regs and spills the accumulators -> 2x slower, R12.)
// bn-chunked; bm-fast XCD-local order (R11): 1 L2 fill per B-panel per XCD.
// EPI: 0 = lm-head (A pre-normed): fp32 nontemporal store + LSE partials
//      2 = residual add; also writes Xb bf16 + 16 ssq partials/row (norm fold)
//      4 = QKV: vv *= rinv, fused RoPE on cols < 2048, bf16 store
//      5 = GU fused silu-mul: g,u *= rinv before silu; LDS exchange; N/2 store
template <int EPI>
__global__ __launch_bounds__(256, 4) void gemm128_kernel(const u16* __restrict__ A,
                                                         const u16* __restrict__ B, void* Cp,
                                                         const float* __restrict__ resid,
                                                         float* __restrict__ partM,
                                                         float* __restrict__ partS,
                                                         const float* __restrict__ cosb,
                                                         const float* __restrict__ sinb,
                                                         u16* __restrict__ xbout,
                                                         float* __restrict__ ssqPart,
                                                         const float* __restrict__ rinv,
                                                         int M, int N, int K, int chunkBn) {
  __shared__ __align__(16) u16 smem_ab[2][128 * 64];   // 32 KiB total
  u16* As = smem_ab[0];
  u16* Bs = smem_ab[1];
  const int tid = threadIdx.x;
  const int lane = tid & 63, wid = tid >> 6;
  const int wr = wid >> 1, wc = wid & 1;
  const int q = lane >> 4, l15 = lane & 15;
  const int nbm = M >> 7;
  const int nbmx = nbm >> 3;               // bm rows per XCD (4)
  const int cs = nbm * chunkBn;            // blocks per chunk
  const int chunk = (int)blockIdx.x / cs;
  const int r0 = (int)blockIdx.x - chunk * cs;
  const int s2 = r0 >> 3;
  const int bm = (r0 & 7) * nbmx + (s2 % nbmx);
  const int bn = chunk * chunkBn + (s2 / nbmx);
  const size_t abase = (size_t)bm * 128 * K;
  const size_t bbase = (size_t)bn * 128 * K;
  f32x4 acc[4][4] = {};
  for (int k0 = 0; k0 < K; k0 += 64) {
#pragma unroll
    for (int i = 0; i < 4; i++) {
      int idx8 = i * 256 + tid;
      int row = idx8 >> 3, ch = idx8 & 7;
      int sc = (ch ^ (row & 7)) << 3;
      gload_lds16(A + abase + (size_t)row * K + k0 + sc, As + idx8 * 8);
      gload_lds16(B + bbase + (size_t)row * K + k0 + sc, Bs + idx8 * 8);
    }
    __syncthreads();
#pragma unroll
    for (int ks = 0; ks < 2; ks++) {
      short8 af[4], bfr[4];
      int chunkc = ks * 4 + q;
#pragma unroll
      for (int mi = 0; mi < 4; mi++) {
        int row = wr * 64 + mi * 16 + l15;
        af[mi] = *(const short8*)&As[row * 64 + ((chunkc ^ (row & 7)) << 3)];
      }
#pragma unroll
      for (int ni = 0; ni < 4; ni++) {
        int row = wc * 64 + ni * 16 + l15;
        bfr[ni] = *(const short8*)&Bs[row * 64 + ((chunkc ^ (row & 7)) << 3)];
      }
#pragma unroll
      for (int mi = 0; mi < 4; mi++)
#pragma unroll
        for (int ni = 0; ni < 4; ni++)
          acc[mi][ni] = __builtin_amdgcn_mfma_f32_16x16x32_bf16(af[mi], bfr[ni], acc[mi][ni], 0, 0, 0);
    }
    __syncthreads();
  }

  // ---- EPI 5: fused silu-mul via cross-wave LDS exchange (rinv applied pre-silu) ----
  if (EPI == 5) {
    float* upf = (float*)&smem_ab[0][0];   // 128x64 floats = 32 KiB
    if (wc == 1) {
#pragma unroll
      for (int mi = 0; mi < 4; mi++)
#pragma unroll
        for (int ni = 0; ni < 4; ni++)
#pragma unroll
          for (int j = 0; j < 4; j++) {
            int r = wr * 64 + mi * 16 + q * 4 + j;
            int cswz = (ni ^ ((r >> 2) & 3)) * 16 + l15;
            upf[r * 64 + cswz] = acc[mi][ni][j];
          }
    }
    __syncthreads();
    if (wc == 0) {
#pragma unroll
      for (int mi = 0; mi < 4; mi++)
#pragma unroll
        for (int j = 0; j < 4; j++) {
          int rloc = wr * 64 + mi * 16 + q * 4 + j;
          int rr = bm * 128 + rloc;
          float ri = rinv[rr];
#pragma unroll
          for (int ni = 0; ni < 4; ni++) {
            int cswz = (ni ^ ((rloc >> 2) & 3)) * 16 + l15;
            float g = acc[mi][ni][j] * ri;
            float u = upf[rloc * 64 + cswz] * ri;
            float rsl = g / (1.0f + expf(-g)) * u;
            ((u16*)Cp)[(size_t)rr * (N >> 1) + bn * 64 + ni * 16 + l15] = f2bf(rsl);
          }
        }
    }
    return;
  }

  // ---- EPI 2: residual add + Xb bf16 + ssq partials ----
  if (EPI == 2) {
#pragma unroll
    for (int mi = 0; mi < 4; mi++)
#pragma unroll
      for (int j = 0; j < 4; j++) {
        int rr = bm * 128 + wr * 64 + mi * 16 + q * 4 + j;
        float ssq = 0.f;
#pragma unroll
        for (int ni = 0; ni < 4; ni++) {
          int cn = bn * 128 + wc * 64 + ni * 16 + l15;
          size_t off = (size_t)rr * N + cn;
          float nx = resid[off] + acc[mi][ni][j];
          ((float*)Cp)[off] = nx;
          xbout[off] = f2bf(nx);
          ssq += nx * nx;
        }
        ssq += __shfl_xor(ssq, 1, 64);
        ssq += __shfl_xor(ssq, 2, 64);
        ssq += __shfl_xor(ssq, 4, 64);
        ssq += __shfl_xor(ssq, 8, 64);
        if (l15 == 0) ssqPart[(size_t)rr * 16 + (bn << 1) + wc] = ssq;
      }
    return;
  }

  // ---- EPI 0 / 4 ----
#pragma unroll
  for (int mi = 0; mi < 4; mi++)
#pragma unroll
    for (int j = 0; j < 4; j++) {
      int rr = bm * 128 + wr * 64 + mi * 16 + q * 4 + j;
      float vv[4];
      if (EPI == 4) {
        float ri = rinv[rr];
#pragma unroll
        for (int ni = 0; ni < 4; ni++) vv[ni] = acc[mi][ni][j] * ri;
      } else {
#pragma unroll
        for (int ni = 0; ni < 4; ni++) vv[ni] = acc[mi][ni][j];
      }
      if (EPI == 0) {
        float mx = fmaxf(fmaxf(vv[0], vv[1]), fmaxf(vv[2], vv[3]));
        mx = fmaxf(mx, __shfl_xor(mx, 1, 64));
        mx = fmaxf(mx, __shfl_xor(mx, 2, 64));
        mx = fmaxf(mx, __shfl_xor(mx, 4, 64));
        mx = fmaxf(mx, __shfl_xor(mx, 8, 64));
        float sm = 0.f;
#pragma unroll
        for (int ni = 0; ni < 4; ni++) sm += expf(vv[ni] - mx);
        sm += __shfl_xor(sm, 1, 64);
        sm += __shfl_xor(sm, 2, 64);
        sm += __shfl_xor(sm, 4, 64);
        sm += __shfl_xor(sm, 8, 64);
        if (l15 == 0) {
          int nt = (N >> 6);
          partM[(size_t)rr * nt + (bn << 1) + wc] = mx;
          partS[(size_t)rr * nt + (bn << 1) + wc] = sm;
        }
      }
      if (EPI == 4) {
        if (((bn << 1) + wc) < 32) {   // Q or K cols: wave-uniform
          int t = rr & (TSEQ - 1);
#pragma unroll
          for (int ni = 0; ni < 2; ni++) {
            int fi = ni * 16 + l15;
            float c = cosb[t * 32 + fi], s = sinb[t * 32 + fi];
            float x1 = vv[ni], x2 = vv[ni + 2];
            vv[ni] = x1 * c - x2 * s;
            vv[ni + 2] = x2 * c + x1 * s;
          }
        }
      }
#pragma unroll
      for (int ni = 0; ni < 4; ni++) {
        int cn = bn * 128 + wc * 64 + ni * 16 + l15;
        size_t off = (size_t)rr * N + cn;
        if (EPI == 0) __builtin_nontemporal_store(vv[ni], (float*)Cp + off);
        else ((u16*)Cp)[off] = f2bf(vv[ni]);
      }
    }
}

// ---------------- flash attention (load-balanced: 2 q-tiles per block) ----------------
// Block (i, bh), i in 0..7, processes qt = i then qt = 15-i: uniform 34 K-tile units.
// grid: (8, 32), block 256 (4 waves x 32 q-rows)
__global__ __launch_bounds__(256) void attn_kernel(const u16* __restrict__ qkv,
                                                   const u16* __restrict__ vt,
                                                   u16* __restrict__ o) {
  __shared__ __align__(16) u16 Ks[64 * 64];
  __shared__ __align__(16) u16 Vt[64 * 64];
  __shared__ u16 Ps[4][32 * 64];
  const u16* q = qkv;
  const u16* k = qkv + D_MODEL;
  const int tid = threadIdx.x, lane = tid & 63, wid = tid >> 6;
  const int qg = lane >> 4, l15 = lane & 15;
  const int bh = blockIdx.y;
  const int b = bh >> 4, h = bh & 15;
  const int tok0 = b * TSEQ;
  const int hoff = h * HDIM;
  const u16* vtb = vt + (size_t)bh * 64 * TSEQ;

  for (int half = 0; half < 2; half++) {
    const int qt = half == 0 ? (int)blockIdx.x : 15 - (int)blockIdx.x;
    const int qrow0 = qt * 128 + wid * 32;

    short8 aq[2][2];
#pragma unroll
    for (int mi = 0; mi < 2; mi++)
#pragma unroll
      for (int ks = 0; ks < 2; ks++) {
        int r = qrow0 + mi * 16 + l15;
        int d = ks * 32 + qg * 8;
        aq[mi][ks] = *(const short8*)(q + (size_t)(tok0 + r) * QKV_STRIDE + hoff + d);
      }
    f32x4 oacc[2][4] = {};
    float mrow[2][4], lrow[2][4];
#pragma unroll
    for (int mi = 0; mi < 2; mi++)
#pragma unroll
      for (int j = 0; j < 4; j++) { mrow[mi][j] = -1e30f; lrow[mi][j] = 0.f; }

    const int nkt = (qt + 1) * 2;
    for (int kt = 0; kt < nkt; kt++) {
      const int kv0 = kt * 64;
#pragma unroll
      for (int it = 0; it < 2; it++) {
        int idx = it * 256 + tid;
        int row = idx >> 3, ch = idx & 7;
        int sc = (ch ^ (row & 7)) << 3;
        gload_lds16(k + (size_t)(tok0 + kv0 + row) * QKV_STRIDE + hoff + sc, Ks + idx * 8);
        gload_lds16(vtb + (size_t)row * TSEQ + kv0 + sc, Vt + idx * 8);
      }
      __syncthreads();
      f32x4 sc[2][4] = {};
#pragma unroll
      for (int ks = 0; ks < 2; ks++) {
        short8 bk[4];
        int kcol = ks * 32 + qg * 8;
#pragma unroll
        for (int ni = 0; ni < 4; ni++) {
          int r = ni * 16 + l15;
          bk[ni] = *(const short8*)&Ks[r * 64 + (kcol ^ ((r & 7) << 3))];
        }
#pragma unroll
        for (int mi = 0; mi < 2; mi++)
#pragma unroll
          for (int ni = 0; ni < 4; ni++)
            sc[mi][ni] = __builtin_amdgcn_mfma_f32_16x16x32_bf16(aq[mi][ks], bk[ni], sc[mi][ni], 0, 0, 0);
      }
      float pm[2][4];
#pragma unroll
      for (int mi = 0; mi < 2; mi++)
#pragma unroll
        for (int j = 0; j < 4; j++) pm[mi][j] = -1e30f;
#pragma unroll
      for (int mi = 0; mi < 2; mi++)
#pragma unroll
        for (int ni = 0; ni < 4; ni++)
#pragma unroll
          for (int j = 0; j < 4; j++) {
            int rq = qrow0 + mi * 16 + qg * 4 + j;
            int ck = kv0 + ni * 16 + l15;
            float s = sc[mi][ni][j] * 0.125f;
            if (ck > rq) s = -1e30f;
            sc[mi][ni][j] = s;
            pm[mi][j] = fmaxf(pm[mi][j], s);
          }
#pragma unroll
      for (int mi = 0; mi < 2; mi++)
#pragma unroll
        for (int j = 0; j < 4; j++) {
          float t = pm[mi][j];
          t = fmaxf(t, __shfl_xor(t, 1, 64));
          t = fmaxf(t, __shfl_xor(t, 2, 64));
          t = fmaxf(t, __shfl_xor(t, 4, 64));
          t = fmaxf(t, __shfl_xor(t, 8, 64));
          pm[mi][j] = t;
        }
#pragma unroll
      for (int mi = 0; mi < 2; mi++)
#pragma unroll
        for (int j = 0; j < 4; j++) {
          float mn = fmaxf(mrow[mi][j], pm[mi][j]);
          float fac = expf(mrow[mi][j] - mn);
          lrow[mi][j] *= fac;
#pragma unroll
          for (int df = 0; df < 4; df++) oacc[mi][df][j] *= fac;
          mrow[mi][j] = mn;
        }
      float psum[2][4] = {};
#pragma unroll
      for (int mi = 0; mi < 2; mi++)
#pragma unroll
        for (int ni = 0; ni < 4; ni++)
#pragma unroll
          for (int j = 0; j < 4; j++) {
            float p = expf(sc[mi][ni][j] - mrow[mi][j]);
            psum[mi][j] += p;
            int r32 = mi * 16 + qg * 4 + j;
            int cc = ni * 16 + l15;
            Ps[wid][r32 * 64 + (cc ^ ((r32 & 7) << 3))] = f2bf(p);
          }
#pragma unroll
      for (int mi = 0; mi < 2; mi++)
#pragma unroll
        for (int j = 0; j < 4; j++) {
          float t = psum[mi][j];
          t += __shfl_xor(t, 1, 64);
          t += __shfl_xor(t, 2, 64);
          t += __shfl_xor(t, 4, 64);
          t += __shfl_xor(t, 8, 64);
          lrow[mi][j] += t;
        }
#pragma unroll
      for (int kf = 0; kf < 2; kf++) {
        short8 pa[2], bv[4];
        int kcol = kf * 32 + qg * 8;
#pragma unroll
        for (int mi = 0; mi < 2; mi++) {
          int r = mi * 16 + l15;
          pa[mi] = *(const short8*)&Ps[wid][r * 64 + (kcol ^ ((r & 7) << 3))];
        }
#pragma unroll
        for (int df = 0; df < 4; df++) {
          int r = df * 16 + l15;
          bv[df] = *(const short8*)&Vt[r * 64 + (kcol ^ ((r & 7) << 3))];
        }
#pragma unroll
        for (int mi = 0; mi < 2; mi++)
#pragma unroll
          for (int df = 0; df < 4; df++)
            oacc[mi][df] = __builtin_amdgcn_mfma_f32_16x16x32_bf16(pa[mi], bv[df], oacc[mi][df], 0, 0, 0);
      }
      __syncthreads();
    }
#pragma unroll
    for (int mi = 0; mi < 2; mi++)
#pragma unroll
      for (int df = 0; df < 4; df++)
#pragma unroll
        for (int j = 0; j < 4; j++) {
          int r = qrow0 + mi * 16 + qg * 4 + j;
          int d = df * 16 + l15;
          float val = oacc[mi][df][j] / lrow[mi][j];
          o[(size_t)(tok0 + r) * D_MODEL + hoff + d] = f2bf(val);
        }
  }
}

// ---------------- loss ----------------

__global__ void nll_finalize_kernel(const float* __restrict__ partM, const float* __restrict__ partS,
                                    const float* __restrict__ logits, const int* __restrict__ targets,
                                    float* __restrict__ nll) {
  int tok = blockIdx.x;
  int lane = threadIdx.x;    // 64
  const int NTL = V_SIZE >> 6;  // 500
  float m = -1e30f, s = 0.f;
  for (int i = lane; i < NTL; i += 64) {
    float m2 = partM[(size_t)tok * NTL + i];
    float s2 = partS[(size_t)tok * NTL + i];
    float nm = fmaxf(m, m2);
    s = s * expf(m - nm) + s2 * expf(m2 - nm);
    m = nm;
  }
#pragma unroll
  for (int mask = 1; mask < 64; mask <<= 1) {
    float m2 = __shfl_xor(m, mask, 64);
    float s2 = __shfl_xor(s, mask, 64);
    float nm = fmaxf(m, m2);
    s = s * expf(m - nm) + s2 * expf(m2 - nm);
    m = nm;
  }
  if (lane == 0)
    nll[tok] = m + logf(s) - logits[(size_t)tok * V_SIZE + targets[tok]];
}

__global__ void loss_reduce_kernel(const float* __restrict__ nll, float* __restrict__ out) {
  float s = 0.f;
  for (int i = threadIdx.x; i < BT; i += 256) s += nll[i];
#pragma unroll
  for (int mask = 1; mask < 64; mask <<= 1) s += __shfl_xor(s, mask, 64);
  __shared__ float sm[4];
  if ((threadIdx.x & 63) == 0) sm[threadIdx.x >> 6] = s;
  __syncthreads();
  if (threadIdx.x == 0) out[0] = (sm[0] + sm[1] + sm[2] + sm[3]) / (float)BT;
}

// ---------------- host launcher ----------------

extern "C" void kernel_launch(void* const* d_in, const int* in_sizes, int n_in,
                              void* d_out, int out_size, void* d_ws, size_t ws_size,
                              hipStream_t stream) {
  const int* idx = (const int*)d_in[0];
  const int* targets = (const int*)d_in[1];
  const float* embed = (const float*)d_in[2];
  const float* wq = (const float*)d_in[3];
  const float* wk = (const float*)d_in[4];
  const float* wv = (const float*)d_in[5];
  const float* wo = (const float*)d_in[6];
  const float* w_gate = (const float*)d_in[7];
  const float* w_up = (const float*)d_in[8];
  const float* w_down = (const float*)d_in[9];
  const float* attn_norm = (const float*)d_in[10];
  const float* mlp_norm = (const float*)d_in[11];
  const float* final_norm = (const float*)d_in[12];
  const float* lm_head = (const float*)d_in[13];
  float* out = (float*)d_out;

  char* ws = (char*)d_ws;
  size_t off = 0;
  auto alloc = [&](size_t bytes) {
    void* p = ws + off;
    off += (bytes + 255) & ~(size_t)255;
    return p;
  };
  const size_t DD = (size_t)D_MODEL * D_MODEL;
  float* rope_cos = (float*)alloc((size_t)TSEQ * 32 * 4);
  float* rope_sin = (float*)alloc((size_t)TSEQ * 32 * 4);
  float* X = (float*)alloc((size_t)BT * D_MODEL * 4);
  u16* Xb = (u16*)alloc((size_t)BT * D_MODEL * 2);
  u16* XbF = (u16*)alloc((size_t)BT * D_MODEL * 2);
  float* Rinv = (float*)alloc((size_t)BT * 4);
  float* SsqP = (float*)alloc((size_t)BT * 16 * 4);
  u16* QKVb = (u16*)alloc((size_t)BT * QKV_STRIDE * 2);
  u16* Vtb = (u16*)alloc((size_t)32 * 64 * TSEQ * 2);
  u16* Ob = (u16*)alloc((size_t)BT * D_MODEL * 2);
  u16* Gb = (u16*)alloc((size_t)BT * HFF * 2);
  u16* WQKVT = (u16*)alloc((size_t)NLAYER * QKV_STRIDE * D_MODEL * 2);
  u16* WOT = (u16*)alloc((size_t)NLAYER * DD * 2);
  u16* WGU = (u16*)alloc((size_t)NLAYER * GU_STRIDE * D_MODEL * 2);
  u16* WDT = (u16*)alloc((size_t)NLAYER * D_MODEL * HFF * 2);
  u16* LMH = (u16*)alloc((size_t)V_SIZE * D_MODEL * 2);
  float* NLLb = (float*)alloc((size_t)BT * 4);
  float* PartM = (float*)alloc((size_t)BT * (V_SIZE >> 6) * 4);
  float* PartS = (float*)alloc((size_t)BT * (V_SIZE >> 6) * 4);

  rope_table_kernel<<<256, 256, 0, stream>>>(rope_cos, rope_sin);
  convert_bf16_kernel<<<4096, 256, 0, stream>>>(lm_head, LMH, final_norm, (long)V_SIZE * D_MODEL / 8);
  embed_gather_kernel<<<BT, 256, 0, stream>>>(idx, embed, X, Xb, Rinv);

  const long QKVW = (long)QKV_STRIDE * D_MODEL;
  const long GUW = (long)GU_STRIDE * D_MODEL;
  const long DW = (long)D_MODEL * HFF;
  // attn_norm folded into QKV weights; mlp_norm into gate/up weights
  transpose_bf16_kernel<<<dim3(32, 32, NLAYER), 256, 0, stream>>>(wq, WQKVT, D_MODEL, D_MODEL, DD, QKVW, 0, attn_norm, D_MODEL);
  transpose_bf16_kernel<<<dim3(32, 32, NLAYER), 256, 0, stream>>>(wk, WQKVT + DD, D_MODEL, D_MODEL, DD, QKVW, 0, attn_norm, D_MODEL);
  transpose_bf16_kernel<<<dim3(32, 32, NLAYER), 256, 0, stream>>>(wv, WQKVT + 2 * DD, D_MODEL, D_MODEL, DD, QKVW, 0, attn_norm, D_MODEL);
  transpose_bf16_kernel<<<dim3(32, 32, NLAYER), 256, 0, stream>>>(wo, WOT, D_MODEL, D_MODEL, DD, DD, 0, nullptr, 0);
  transpose_bf16_kernel<<<dim3(128, 32, NLAYER), 256, 0, stream>>>(w_gate, WGU, D_MODEL, HFF, DW, GUW, 1, mlp_norm, D_MODEL);
  transpose_bf16_kernel<<<dim3(128, 32, NLAYER), 256, 0, stream>>>(w_up, WGU, D_MODEL, HFF, DW, GUW, 2, mlp_norm, D_MODEL);
  transpose_bf16_kernel<<<dim3(32, 128, NLAYER), 256, 0, stream>>>(w_down, WDT, HFF, D_MODEL, DW, DW, 0, nullptr, 0);

  for (int l = 0; l < NLAYER; l++) {
    gemm128_kernel<4><<<(QKV_STRIDE / 128) * (BT / 128), 256, 0, stream>>>(
        Xb, WQKVT + (size_t)l * QKVW, QKVb, nullptr, nullptr, nullptr, rope_cos, rope_sin,
        nullptr, nullptr, Rinv, BT, QKV_STRIDE, D_MODEL, QKV_STRIDE / 128);
    vtrans_kernel<<<dim3(32, 32), 256, 0, stream>>>(QKVb, Vtb);
    attn_kernel<<<dim3(8, 32), 256, 0, stream>>>(QKVb, Vtb, Ob);
    gemm128_kernel<2><<<(D_MODEL / 128) * (BT / 128), 256, 0, stream>>>(
        Ob, WOT + (size_t)l * DD, X, X, nullptr, nullptr, nullptr, nullptr,
        Xb, SsqP, nullptr, BT, D_MODEL, D_MODEL, D_MODEL / 128);
    rinv_kernel<<<BT / 256, 256, 0, stream>>>(SsqP, Rinv);

    gemm128_kernel<5><<<(GU_STRIDE / 128) * (BT / 128), 256, 0, stream>>>(
        Xb, WGU + (size_t)l * GUW, Gb, nullptr, nullptr, nullptr, nullptr, nullptr,
        nullptr, nullptr, Rinv, BT, GU_STRIDE, D_MODEL, 32);
    gemm128_kernel<2><<<(D_MODEL / 128) * (BT / 128), 256, 0, stream>>>(
        Gb, WDT + (size_t)l * DW, X, X, nullptr, nullptr, nullptr, nullptr,
        Xb, SsqP, nullptr, BT, D_MODEL, HFF, D_MODEL / 128);
    rinv_kernel<<<BT / 256, 256, 0, stream>>>(SsqP, Rinv);
  }

  scale_xb_kernel<<<BT * D_MODEL / (256 * 8), 256, 0, stream>>>(Xb, Rinv, XbF);
  gemm128_kernel<0><<<(V_SIZE / 128) * (BT / 128), 256, 0, stream>>>(
      XbF, LMH, out, nullptr, PartM, PartS, nullptr, nullptr,
      nullptr, nullptr, nullptr, BT, V_SIZE, D_MODEL, 50);
  nll_finalize_kernel<<<BT, 64, 0, stream>>>(PartM, PartS, out, targets, NLLb);
  loss_reduce_kernel<<<1, 256, 0, stream>>>(NLLb, out + (size_t)BT * V_SIZE);
}

// Round 15
// 1736.984 us; speedup vs baseline: 1.9536x; 1.1543x over previous
//
#include <hip/hip_runtime.h>

typedef __attribute__((ext_vector_type(8))) short short8;
typedef __attribute__((ext_vector_type(4))) float f32x4;
typedef __attribute__((ext_vector_type(8))) unsigned short u16x8;
typedef unsigned short u16;

#define V_SIZE 32000
#define D_MODEL 1024
#define HFF 4096
#define NHEAD 16
#define HDIM 64
#define NLAYER 4
#define BT 4096   // B*T tokens
#define TSEQ 2048
#define QKV_STRIDE 3072
#define GU_STRIDE 8192

__device__ __forceinline__ u16 f2bf(float f) {
  union { float f; unsigned u; } v; v.f = f;
  unsigned r = v.u + 0x7fffu + ((v.u >> 16) & 1u);
  return (u16)(r >> 16);
}
__device__ __forceinline__ float bf2f(u16 h) {
  union { unsigned u; float f; } v; v.u = ((unsigned)h) << 16;
  return v.f;
}

__device__ __forceinline__ void gload_lds16(const void* g, void* l) {
  __builtin_amdgcn_global_load_lds((__attribute__((address_space(1))) void*)g,
                                   (__attribute__((address_space(3))) void*)l, 16, 0, 0);
}

// ---------------- elementwise / small kernels ----------------

__global__ void rope_table_kernel(float* __restrict__ cosb, float* __restrict__ sinb) {
  int i = blockIdx.x * 256 + threadIdx.x;       // 2048*32 = 65536 items
  int t = i >> 5, fi = i & 31;
  float freq = exp2f(-(2.0f * (float)fi / 64.0f) * log2f(10000.0f));
  float ang = (float)t * freq;
  cosb[i] = cosf(ang);
  sinb[i] = sinf(ang);
}

// lm_head fp32 -> bf16, scaled by final_norm[k] (k = flat index & 1023)
__global__ void convert_bf16_kernel(const float* __restrict__ src, u16* __restrict__ dst,
                                    const float* __restrict__ fn, long n8) {
  long i = (long)blockIdx.x * 256 + threadIdx.x;
  long stride = (long)gridDim.x * 256;
  for (; i < n8; i += stride) {
    const float4* s = (const float4*)(src + i * 8);
    float4 a = s[0], b = s[1];
    int k0 = (int)((i * 8) & (D_MODEL - 1));
    u16x8 r;
    r[0] = f2bf(a.x * fn[k0 + 0]); r[1] = f2bf(a.y * fn[k0 + 1]);
    r[2] = f2bf(a.z * fn[k0 + 2]); r[3] = f2bf(a.w * fn[k0 + 3]);
    r[4] = f2bf(b.x * fn[k0 + 4]); r[5] = f2bf(b.y * fn[k0 + 5]);
    r[6] = f2bf(b.z * fn[k0 + 6]); r[7] = f2bf(b.w * fn[k0 + 7]);
    *(u16x8*)(dst + i * 8) = r;
  }
}

// src [R][C] fp32 -> dst bf16, scaled by nw[src row] if nw != null (norm fold).
// rowMode: 0 -> dst row = c; 1 -> ((c>>6)<<7)|(c&63) (gate); 2 -> +64 (up)
__global__ __launch_bounds__(256) void transpose_bf16_kernel(const float* __restrict__ src0,
                                                             u16* __restrict__ dst0, int R, int C,
                                                             long srcStride, long dstStride,
                                                             int rowMode,
                                                             const float* __restrict__ nw0,
                                                             int nwStride) {
  __shared__ float tile[32][33];
  const float* src = src0 + (size_t)blockIdx.z * srcStride;
  u16* dst = dst0 + (size_t)blockIdx.z * dstStride;
  const float* nw = nw0 ? nw0 + (size_t)blockIdx.z * nwStride : nullptr;
  int tx = threadIdx.x & 31, ty = threadIdx.x >> 5;  // 32 x 8
  int bx = blockIdx.x, by = blockIdx.y;
#pragma unroll
  for (int i = 0; i < 32; i += 8) {
    int r = by * 32 + ty + i, c = bx * 32 + tx;
    tile[ty + i][tx] = src[(size_t)r * C + c];
  }
  __syncthreads();
#pragma unroll
  for (int i = 0; i < 32; i += 8) {
    int c = bx * 32 + ty + i;   // source col
    int r = by * 32 + tx;       // source row (k index) -> dst col
    float val = tile[tx][ty + i];
    if (nw) val *= nw[r];
    int drow = c;
    if (rowMode == 1) drow = ((c >> 6) << 7) | (c & 63);
    else if (rowMode == 2) drow = ((c >> 6) << 7) | 64 | (c & 63);
    dst[(size_t)drow * R + r] = f2bf(val);
  }
}

// embed gather: writes X fp32, Xb bf16, and rinv[t]. 1 block = 1 token.
__global__ __launch_bounds__(256) void embed_gather_kernel(const int* __restrict__ idx,
                                                           const float* __restrict__ embed,
                                                           float* __restrict__ x,
                                                           u16* __restrict__ xb,
                                                           float* __restrict__ rinv) {
  int t = blockIdx.x;
  int id = idx[t];
  float4 v = ((const float4*)embed)[(size_t)id * 256 + threadIdx.x];
  ((float4*)x)[(size_t)t * 256 + threadIdx.x] = v;
  u16* hp = xb + (size_t)t * D_MODEL + threadIdx.x * 4;
  hp[0] = f2bf(v.x); hp[1] = f2bf(v.y); hp[2] = f2bf(v.z); hp[3] = f2bf(v.w);
  float ss = v.x * v.x + v.y * v.y + v.z * v.z + v.w * v.w;
#pragma unroll
  for (int m = 32; m > 0; m >>= 1) ss += __shfl_xor(ss, m, 64);
  __shared__ float wsum[4];
  if ((threadIdx.x & 63) == 0) wsum[threadIdx.x >> 6] = ss;
  __syncthreads();
  if (threadIdx.x == 0) {
    float tot = wsum[0] + wsum[1] + wsum[2] + wsum[3];
    rinv[t] = rsqrtf(tot * (1.0f / (float)D_MODEL) + 1e-6f);
  }
}

// reduce 16 ssq partials per row -> rinv
__global__ void rinv_kernel(const float* __restrict__ ssqPart, float* __restrict__ rinv) {
  int r = blockIdx.x * 256 + threadIdx.x;   // BT rows
  float s = 0.f;
#pragma unroll
  for (int i = 0; i < 16; i++) s += ssqPart[(size_t)r * 16 + i];
  rinv[r] = rsqrtf(s * (1.0f / (float)D_MODEL) + 1e-6f);
}

// XbF = Xb * rinv[row] (bf16, vectorized)
__global__ void scale_xb_kernel(const u16* __restrict__ xb, const float* __restrict__ rinv,
                                u16* __restrict__ xbf) {
  long i = (long)blockIdx.x * 256 + threadIdx.x;   // item = 8 elems
  int row = (int)(i >> 7);
  float ri = rinv[row];
  short8 v = *(const short8*)(xb + i * 8);
  u16x8 r;
#pragma unroll
  for (int j = 0; j < 8; j++) r[j] = f2bf(bf2f((u16)v[j]) * ri);
  *(u16x8*)(xbf + i * 8) = r;
}

// V (in QKV buffer) -> Vt [bh][64 d][TSEQ t] bf16, tile-transposed via LDS.
__global__ __launch_bounds__(256) void vtrans_kernel(const u16* __restrict__ qkv,
                                                     u16* __restrict__ vt) {
  __shared__ u16 lds[64 * 64];
  const int tid = threadIdx.x;
  const int bh = blockIdx.y, tt = blockIdx.x;
  const int b = bh >> 4, h = bh & 15;
  const int tok0 = b * TSEQ + tt * 64;
  const int hoff = 2 * D_MODEL + h * HDIM;
#pragma unroll
  for (int it = 0; it < 2; it++) {
    int idx = it * 256 + tid;
    int row = idx >> 3, c = (idx & 7) * 8;
    short8 v = *(const short8*)(qkv + (size_t)(tok0 + row) * QKV_STRIDE + hoff + c);
    *(short8*)&lds[row * 64 + (c ^ ((row & 7) << 3))] = v;
  }
  __syncthreads();
#pragma unroll
  for (int it = 0; it < 2; it++) {
    int idx = it * 256 + tid;
    int d = idx >> 3, t0 = (idx & 7) * 8;
    u16x8 pk;
#pragma unroll
    for (int j = 0; j < 8; j++) {
      int t = t0 + j;
      pk[j] = lds[t * 64 + (((d & ~7) ^ ((t & 7) << 3)) | (d & 7))];
    }
    *(u16x8*)(vt + ((size_t)bh * 64 + d) * TSEQ + tt * 64 + t0) = pk;
  }
}

// ---------------- GEMM 128x128 (m97 structure, both-sides swizzle, 4 blocks/CU) ----
// EPI: 0 = lm-head (A pre-normed): fp32 nontemporal store + LSE partials
//      4 = QKV: vv *= rinv, fused RoPE on cols < 2048, bf16 store
//      5 = GU fused silu-mul: g,u *= rinv before silu; LDS exchange; N/2 store
template <int EPI>
__global__ __launch_bounds__(256, 4) void gemm128_kernel(const u16* __restrict__ A,
                                                         const u16* __restrict__ B, void* Cp,
                                                         float* __restrict__ partM,
                                                         float* __restrict__ partS,
                                                         const float* __restrict__ cosb,
                                                         const float* __restrict__ sinb,
                                                         const float* __restrict__ rinv,
                                                         int M, int N, int K, int chunkBn) {
  __shared__ __align__(16) u16 smem_ab[2][128 * 64];   // 32 KiB total
  u16* As = smem_ab[0];
  u16* Bs = smem_ab[1];
  const int tid = threadIdx.x;
  const int lane = tid & 63, wid = tid >> 6;
  const int wr = wid >> 1, wc = wid & 1;
  const int q = lane >> 4, l15 = lane & 15;
  const int nbm = M >> 7;
  const int nbmx = nbm >> 3;               // bm rows per XCD
  const int cs = nbm * chunkBn;            // blocks per chunk
  const int chunk = (int)blockIdx.x / cs;
  const int r0 = (int)blockIdx.x - chunk * cs;
  const int s2 = r0 >> 3;
  const int bm = (r0 & 7) * nbmx + (s2 % nbmx);
  const int bn = chunk * chunkBn + (s2 / nbmx);
  const size_t abase = (size_t)bm * 128 * K;
  const size_t bbase = (size_t)bn * 128 * K;
  f32x4 acc[4][4] = {};
  for (int k0 = 0; k0 < K; k0 += 64) {
#pragma unroll
    for (int i = 0; i < 4; i++) {
      int idx8 = i * 256 + tid;
      int row = idx8 >> 3, ch = idx8 & 7;
      int sc = (ch ^ (row & 7)) << 3;
      gload_lds16(A + abase + (size_t)row * K + k0 + sc, As + idx8 * 8);
      gload_lds16(B + bbase + (size_t)row * K + k0 + sc, Bs + idx8 * 8);
    }
    __syncthreads();
#pragma unroll
    for (int ks = 0; ks < 2; ks++) {
      short8 af[4], bfr[4];
      int chunkc = ks * 4 + q;
#pragma unroll
      for (int mi = 0; mi < 4; mi++) {
        int row = wr * 64 + mi * 16 + l15;
        af[mi] = *(const short8*)&As[row * 64 + ((chunkc ^ (row & 7)) << 3)];
      }
#pragma unroll
      for (int ni = 0; ni < 4; ni++) {
        int row = wc * 64 + ni * 16 + l15;
        bfr[ni] = *(const short8*)&Bs[row * 64 + ((chunkc ^ (row & 7)) << 3)];
      }
#pragma unroll
      for (int mi = 0; mi < 4; mi++)
#pragma unroll
        for (int ni = 0; ni < 4; ni++)
          acc[mi][ni] = __builtin_amdgcn_mfma_f32_16x16x32_bf16(af[mi], bfr[ni], acc[mi][ni], 0, 0, 0);
    }
    __syncthreads();
  }

  // ---- EPI 5: fused silu-mul via cross-wave LDS exchange (rinv applied pre-silu) ----
  if (EPI == 5) {
    float* upf = (float*)&smem_ab[0][0];   // 128x64 floats = 32 KiB
    if (wc == 1) {
#pragma unroll
      for (int mi = 0; mi < 4; mi++)
#pragma unroll
        for (int ni = 0; ni < 4; ni++)
#pragma unroll
          for (int j = 0; j < 4; j++) {
            int r = wr * 64 + mi * 16 + q * 4 + j;
            int cswz = (ni ^ ((r >> 2) & 3)) * 16 + l15;
            upf[r * 64 + cswz] = acc[mi][ni][j];
          }
    }
    __syncthreads();
    if (wc == 0) {
#pragma unroll
      for (int mi = 0; mi < 4; mi++)
#pragma unroll
        for (int j = 0; j < 4; j++) {
          int rloc = wr * 64 + mi * 16 + q * 4 + j;
          int rr = bm * 128 + rloc;
          float ri = rinv[rr];
#pragma unroll
          for (int ni = 0; ni < 4; ni++) {
            int cswz = (ni ^ ((rloc >> 2) & 3)) * 16 + l15;
            float g = acc[mi][ni][j] * ri;
            float u = upf[rloc * 64 + cswz] * ri;
            float rsl = g / (1.0f + expf(-g)) * u;
            ((u16*)Cp)[(size_t)rr * (N >> 1) + bn * 64 + ni * 16 + l15] = f2bf(rsl);
          }
        }
    }
    return;
  }

  // ---- EPI 0 / 4 ----
#pragma unroll
  for (int mi = 0; mi < 4; mi++)
#pragma unroll
    for (int j = 0; j < 4; j++) {
      int rr = bm * 128 + wr * 64 + mi * 16 + q * 4 + j;
      float vv[4];
      if (EPI == 4) {
        float ri = rinv[rr];
#pragma unroll
        for (int ni = 0; ni < 4; ni++) vv[ni] = acc[mi][ni][j] * ri;
      } else {
#pragma unroll
        for (int ni = 0; ni < 4; ni++) vv[ni] = acc[mi][ni][j];
      }
      if (EPI == 0) {
        float mx = fmaxf(fmaxf(vv[0], vv[1]), fmaxf(vv[2], vv[3]));
        mx = fmaxf(mx, __shfl_xor(mx, 1, 64));
        mx = fmaxf(mx, __shfl_xor(mx, 2, 64));
        mx = fmaxf(mx, __shfl_xor(mx, 4, 64));
        mx = fmaxf(mx, __shfl_xor(mx, 8, 64));
        float sm = 0.f;
#pragma unroll
        for (int ni = 0; ni < 4; ni++) sm += expf(vv[ni] - mx);
        sm += __shfl_xor(sm, 1, 64);
        sm += __shfl_xor(sm, 2, 64);
        sm += __shfl_xor(sm, 4, 64);
        sm += __shfl_xor(sm, 8, 64);
        if (l15 == 0) {
          int nt = (N >> 6);
          partM[(size_t)rr * nt + (bn << 1) + wc] = mx;
          partS[(size_t)rr * nt + (bn << 1) + wc] = sm;
        }
      }
      if (EPI == 4) {
        if (((bn << 1) + wc) < 32) {   // Q or K cols: wave-uniform
          int t = rr & (TSEQ - 1);
#pragma unroll
          for (int ni = 0; ni < 2; ni++) {
            int fi = ni * 16 + l15;
            float c = cosb[t * 32 + fi], s = sinb[t * 32 + fi];
            float x1 = vv[ni], x2 = vv[ni + 2];
            vv[ni] = x1 * c - x2 * s;
            vv[ni + 2] = x2 * c + x1 * s;
          }
        }
      }
#pragma unroll
      for (int ni = 0; ni < 4; ni++) {
        int cn = bn * 128 + wc * 64 + ni * 16 + l15;
        size_t off = (size_t)rr * N + cn;
        if (EPI == 0) __builtin_nontemporal_store(vv[ni], (float*)Cp + off);
        else ((u16*)Cp)[off] = f2bf(vv[ni]);
      }
    }
}

// ---------------- GEMM 64x128 for N=1024 projections (o-proj / down-proj) ----------
// 512 blocks = 2 blocks/CU = 8 waves/CU (vs 1 block/CU at 128x128). LDS 24 KiB.
// EPI2 fixed: residual add + Xb bf16 + ssq partials.
__global__ __launch_bounds__(256, 4) void gemm64_kernel(const u16* __restrict__ A,
                                                        const u16* __restrict__ B, float* __restrict__ Cp,
                                                        const float* __restrict__ resid,
                                                        u16* __restrict__ xbout,
                                                        float* __restrict__ ssqPart,
                                                        int M, int N, int K) {
  __shared__ __align__(16) u16 As[64 * 64];    // 8 KiB
  __shared__ __align__(16) u16 Bs[128 * 64];   // 16 KiB
  const int tid = threadIdx.x;
  const int lane = tid & 63, wid = tid >> 6;
  const int wr = wid >> 1, wc = wid & 1;
  const int q = lane >> 4, l15 = lane & 15;
  const int nbm = M >> 6;                  // 64
  const int nbmx = nbm >> 3;               // 8 bm rows per XCD
  const int s2 = (int)blockIdx.x >> 3;
  const int bm = ((int)blockIdx.x & 7) * nbmx + (s2 % nbmx);
  const int bn = s2 / nbmx;
  const size_t abase = (size_t)bm * 64 * K;
  const size_t bbase = (size_t)bn * 128 * K;
  f32x4 acc[2][4] = {};
  for (int k0 = 0; k0 < K; k0 += 64) {
#pragma unroll
    for (int i = 0; i < 2; i++) {
      int idx8 = i * 256 + tid;            // 512 chunks for A (64 rows)
      int row = idx8 >> 3, ch = idx8 & 7;
      int sc = (ch ^ (row & 7)) << 3;
      gload_lds16(A + abase + (size_t)row * K + k0 + sc, As + idx8 * 8);
    }
#pragma unroll
    for (int i = 0; i < 4; i++) {
      int idx8 = i * 256 + tid;            // 1024 chunks for B (128 rows)
      int row = idx8 >> 3, ch = idx8 & 7;
      int sc = (ch ^ (row & 7)) << 3;
      gload_lds16(B + bbase + (size_t)row * K + k0 + sc, Bs + idx8 * 8);
    }
    __syncthreads();
#pragma unroll
    for (int ks = 0; ks < 2; ks++) {
      short8 af[2], bfr[4];
      int chunkc = ks * 4 + q;
#pragma unroll
      for (int mi = 0; mi < 2; mi++) {
        int row = wr * 32 + mi * 16 + l15;
        af[mi] = *(const short8*)&As[row * 64 + ((chunkc ^ (row & 7)) << 3)];
      }
#pragma unroll
      for (int ni = 0; ni < 4; ni++) {
        int row = wc * 64 + ni * 16 + l15;
        bfr[ni] = *(const short8*)&Bs[row * 64 + ((chunkc ^ (row & 7)) << 3)];
      }
#pragma unroll
      for (int mi = 0; mi < 2; mi++)
#pragma unroll
        for (int ni = 0; ni < 4; ni++)
          acc[mi][ni] = __builtin_amdgcn_mfma_f32_16x16x32_bf16(af[mi], bfr[ni], acc[mi][ni], 0, 0, 0);
    }
    __syncthreads();
  }
  // EPI2: residual add + Xb + ssq partials
#pragma unroll
  for (int mi = 0; mi < 2; mi++)
#pragma unroll
    for (int j = 0; j < 4; j++) {
      int rr = bm * 64 + wr * 32 + mi * 16 + q * 4 + j;
      float ssq = 0.f;
#pragma unroll
      for (int ni = 0; ni < 4; ni++) {
        int cn = bn * 128 + wc * 64 + ni * 16 + l15;
        size_t off = (size_t)rr * N + cn;
        float nx = resid[off] + acc[mi][ni][j];
        Cp[off] = nx;
        xbout[off] = f2bf(nx);
        ssq += nx * nx;
      }
      ssq += __shfl_xor(ssq, 1, 64);
      ssq += __shfl_xor(ssq, 2, 64);
      ssq += __shfl_xor(ssq, 4, 64);
      ssq += __shfl_xor(ssq, 8, 64);
      if (l15 == 0) ssqPart[(size_t)rr * 16 + (bn << 1) + wc] = ssq;
    }
}

// ---------------- flash attention (64-row q-tiles, uniform load, 2 blocks/CU) -------
// grid (16, 32): block i handles qt64 = i then 31-i -> (i+1)+(32-i) = 33 K-tile units.
// 4 waves x 16 q-rows. LDS: Ks 8K + Vt 8K + Ps 8K = 24 KiB.
__global__ __launch_bounds__(256) void attn_kernel(const u16* __restrict__ qkv,
                                                   const u16* __restrict__ vt,
                                                   u16* __restrict__ o) {
  __shared__ __align__(16) u16 Ks[64 * 64];
  __shared__ __align__(16) u16 Vt[64 * 64];
  __shared__ u16 Ps[4][16 * 64];
  const u16* q = qkv;
  const u16* k = qkv + D_MODEL;
  const int tid = threadIdx.x, lane = tid & 63, wid = tid >> 6;
  const int qg = lane >> 4, l15 = lane & 15;
  const int bh = blockIdx.y;
  const int b = bh >> 4, h = bh & 15;
  const int tok0 = b * TSEQ;
  const int hoff = h * HDIM;
  const u16* vtb = vt + (size_t)bh * 64 * TSEQ;

  for (int half = 0; half < 2; half++) {
    const int qt = half == 0 ? (int)blockIdx.x : 31 - (int)blockIdx.x;
    const int qrow0 = qt * 64 + wid * 16;

    short8 aq[2];
#pragma unroll
    for (int ks = 0; ks < 2; ks++) {
      int r = qrow0 + l15;
      int d = ks * 32 + qg * 8;
      aq[ks] = *(const short8*)(q + (size_t)(tok0 + r) * QKV_STRIDE + hoff + d);
    }
    f32x4 oacc[4] = {};
    float mrow[4], lrow[4];
#pragma unroll
    for (int j = 0; j < 4; j++) { mrow[j] = -1e30f; lrow[j] = 0.f; }

    const int nkt = qt + 1;
    for (int kt = 0; kt < nkt; kt++) {
      const int kv0 = kt * 64;
#pragma unroll
      for (int it = 0; it < 2; it++) {
        int idx = it * 256 + tid;
        int row = idx >> 3, ch = idx & 7;
        int sc = (ch ^ (row & 7)) << 3;
        gload_lds16(k + (size_t)(tok0 + kv0 + row) * QKV_STRIDE + hoff + sc, Ks + idx * 8);
        gload_lds16(vtb + (size_t)row * TSEQ + kv0 + sc, Vt + idx * 8);
      }
      __syncthreads();
      f32x4 sc[4] = {};
#pragma unroll
      for (int ks = 0; ks < 2; ks++) {
        short8 bk[4];
        int kcol = ks * 32 + qg * 8;
#pragma unroll
        for (int ni = 0; ni < 4; ni++) {
          int r = ni * 16 + l15;
          bk[ni] = *(const short8*)&Ks[r * 64 + (kcol ^ ((r & 7) << 3))];
        }
#pragma unroll
        for (int ni = 0; ni < 4; ni++)
          sc[ni] = __builtin_amdgcn_mfma_f32_16x16x32_bf16(aq[ks], bk[ni], sc[ni], 0, 0, 0);
      }
      float pm[4];
#pragma unroll
      for (int j = 0; j < 4; j++) pm[j] = -1e30f;
#pragma unroll
      for (int ni = 0; ni < 4; ni++)
#pragma unroll
        for (int j = 0; j < 4; j++) {
          int rq = qrow0 + qg * 4 + j;
          int ck = kv0 + ni * 16 + l15;
          float s = sc[ni][j] * 0.125f;
          if (ck > rq) s = -1e30f;
          sc[ni][j] = s;
          pm[j] = fmaxf(pm[j], s);
        }
#pragma unroll
      for (int j = 0; j < 4; j++) {
        float t = pm[j];
        t = fmaxf(t, __shfl_xor(t, 1, 64));
        t = fmaxf(t, __shfl_xor(t, 2, 64));
        t = fmaxf(t, __shfl_xor(t, 4, 64));
        t = fmaxf(t, __shfl_xor(t, 8, 64));
        pm[j] = t;
      }
#pragma unroll
      for (int j = 0; j < 4; j++) {
        float mn = fmaxf(mrow[j], pm[j]);
        float fac = expf(mrow[j] - mn);
        lrow[j] *= fac;
#pragma unroll
        for (int df = 0; df < 4; df++) oacc[df][j] *= fac;
        mrow[j] = mn;
      }
      float psum[4] = {};
#pragma unroll
      for (int ni = 0; ni < 4; ni++)
#pragma unroll
        for (int j = 0; j < 4; j++) {
          float p = expf(sc[ni][j] - mrow[j]);
          psum[j] += p;
          int r16 = qg * 4 + j;
          int cc = ni * 16 + l15;
          Ps[wid][r16 * 64 + (cc ^ ((r16 & 7) << 3))] = f2bf(p);
        }
#pragma unroll
      for (int j = 0; j < 4; j++) {
        float t = psum[j];
        t += __shfl_xor(t, 1, 64);
        t += __shfl_xor(t, 2, 64);
        t += __shfl_xor(t, 4, 64);
        t += __shfl_xor(t, 8, 64);
        lrow[j] += t;
      }
#pragma unroll
      for (int kf = 0; kf < 2; kf++) {
        short8 pa, bv[4];
        int kcol = kf * 32 + qg * 8;
        {
          int r = l15;
          pa = *(const short8*)&Ps[wid][r * 64 + (kcol ^ ((r & 7) << 3))];
        }
#pragma unroll
        for (int df = 0; df < 4; df++) {
          int r = df * 16 + l15;
          bv[df] = *(const short8*)&Vt[r * 64 + (kcol ^ ((r & 7) << 3))];
        }
#pragma unroll
        for (int df = 0; df < 4; df++)
          oacc[df] = __builtin_amdgcn_mfma_f32_16x16x32_bf16(pa, bv[df], oacc[df], 0, 0, 0);
      }
      __syncthreads();
    }
#pragma unroll
    for (int df = 0; df < 4; df++)
#pragma unroll
      for (int j = 0; j < 4; j++) {
        int r = qrow0 + qg * 4 + j;
        int d = df * 16 + l15;
        float val = oacc[df][j] / lrow[j];
        o[(size_t)(tok0 + r) * D_MODEL + hoff + d] = f2bf(val);
      }
  }
}

// ---------------- loss ----------------

__global__ void nll_finalize_kernel(const float* __restrict__ partM, const float* __restrict__ partS,
                                    const float* __restrict__ logits, const int* __restrict__ targets,
                                    float* __restrict__ nll) {
  int tok = blockIdx.x;
  int lane = threadIdx.x;    // 64
  const int NTL = V_SIZE >> 6;  // 500
  float m = -1e30f, s = 0.f;
  for (int i = lane; i < NTL; i += 64) {
    float m2 = partM[(size_t)tok * NTL + i];
    float s2 = partS[(size_t)tok * NTL + i];
    float nm = fmaxf(m, m2);
    s = s * expf(m - nm) + s2 * expf(m2 - nm);
    m = nm;
  }
#pragma unroll
  for (int mask = 1; mask < 64; mask <<= 1) {
    float m2 = __shfl_xor(m, mask, 64);
    float s2 = __shfl_xor(s, mask, 64);
    float nm = fmaxf(m, m2);
    s = s * expf(m - nm) + s2 * expf(m2 - nm);
    m = nm;
  }
  if (lane == 0)
    nll[tok] = m + logf(s) - logits[(size_t)tok * V_SIZE + targets[tok]];
}

__global__ void loss_reduce_kernel(const float* __restrict__ nll, float* __restrict__ out) {
  float s = 0.f;
  for (int i = threadIdx.x; i < BT; i += 256) s += nll[i];
#pragma unroll
  for (int mask = 1; mask < 64; mask <<= 1) s += __shfl_xor(s, mask, 64);
  __shared__ float sm[4];
  if ((threadIdx.x & 63) == 0) sm[threadIdx.x >> 6] = s;
  __syncthreads();
  if (threadIdx.x == 0) out[0] = (sm[0] + sm[1] + sm[2] + sm[3]) / (float)BT;
}

// ---------------- host launcher ----------------

extern "C" void kernel_launch(void* const* d_in, const int* in_sizes, int n_in,
                              void* d_out, int out_size, void* d_ws, size_t ws_size,
                              hipStream_t stream) {
  const int* idx = (const int*)d_in[0];
  const int* targets = (const int*)d_in[1];
  const float* embed = (const float*)d_in[2];
  const float* wq = (const float*)d_in[3];
  const float* wk = (const float*)d_in[4];
  const float* wv = (const float*)d_in[5];
  const float* wo = (const float*)d_in[6];
  const float* w_gate = (const float*)d_in[7];
  const float* w_up = (const float*)d_in[8];
  const float* w_down = (const float*)d_in[9];
  const float* attn_norm = (const float*)d_in[10];
  const float* mlp_norm = (const float*)d_in[11];
  const float* final_norm = (const float*)d_in[12];
  const float* lm_head = (const float*)d_in[13];
  float* out = (float*)d_out;

  char* ws = (char*)d_ws;
  size_t off = 0;
  auto alloc = [&](size_t bytes) {
    void* p = ws + off;
    off += (bytes + 255) & ~(size_t)255;
    return p;
  };
  const size_t DD = (size_t)D_MODEL * D_MODEL;
  float* rope_cos = (float*)alloc((size_t)TSEQ * 32 * 4);
  float* rope_sin = (float*)alloc((size_t)TSEQ * 32 * 4);
  float* X = (float*)alloc((size_t)BT * D_MODEL * 4);
  u16* Xb = (u16*)alloc((size_t)BT * D_MODEL * 2);
  u16* XbF = (u16*)alloc((size_t)BT * D_MODEL * 2);
  float* Rinv = (float*)alloc((size_t)BT * 4);
  float* SsqP = (float*)alloc((size_t)BT * 16 * 4);
  u16* QKVb = (u16*)alloc((size_t)BT * QKV_STRIDE * 2);
  u16* Vtb = (u16*)alloc((size_t)32 * 64 * TSEQ * 2);
  u16* Ob = (u16*)alloc((size_t)BT * D_MODEL * 2);
  u16* Gb = (u16*)alloc((size_t)BT * HFF * 2);
  u16* WQKVT = (u16*)alloc((size_t)NLAYER * QKV_STRIDE * D_MODEL * 2);
  u16* WOT = (u16*)alloc((size_t)NLAYER * DD * 2);
  u16* WGU = (u16*)alloc((size_t)NLAYER * GU_STRIDE * D_MODEL * 2);
  u16* WDT = (u16*)alloc((size_t)NLAYER * D_MODEL * HFF * 2);
  u16* LMH = (u16*)alloc((size_t)V_SIZE * D_MODEL * 2);
  float* NLLb = (float*)alloc((size_t)BT * 4);
  float* PartM = (float*)alloc((size_t)BT * (V_SIZE >> 6) * 4);
  float* PartS = (float*)alloc((size_t)BT * (V_SIZE >> 6) * 4);

  rope_table_kernel<<<256, 256, 0, stream>>>(rope_cos, rope_sin);
  convert_bf16_kernel<<<4096, 256, 0, stream>>>(lm_head, LMH, final_norm, (long)V_SIZE * D_MODEL / 8);
  embed_gather_kernel<<<BT, 256, 0, stream>>>(idx, embed, X, Xb, Rinv);

  const long QKVW = (long)QKV_STRIDE * D_MODEL;
  const long GUW = (long)GU_STRIDE * D_MODEL;
  const long DW = (long)D_MODEL * HFF;
  transpose_bf16_kernel<<<dim3(32, 32, NLAYER), 256, 0, stream>>>(wq, WQKVT, D_MODEL, D_MODEL, DD, QKVW, 0, attn_norm, D_MODEL);
  transpose_bf16_kernel<<<dim3(32, 32, NLAYER), 256, 0, stream>>>(wk, WQKVT + DD, D_MODEL, D_MODEL, DD, QKVW, 0, attn_norm, D_MODEL);
  transpose_bf16_kernel<<<dim3(32, 32, NLAYER), 256, 0, stream>>>(wv, WQKVT + 2 * DD, D_MODEL, D_MODEL, DD, QKVW, 0, attn_norm, D_MODEL);
  transpose_bf16_kernel<<<dim3(32, 32, NLAYER), 256, 0, stream>>>(wo, WOT, D_MODEL, D_MODEL, DD, DD, 0, nullptr, 0);
  transpose_bf16_kernel<<<dim3(128, 32, NLAYER), 256, 0, stream>>>(w_gate, WGU, D_MODEL, HFF, DW, GUW, 1, mlp_norm, D_MODEL);
  transpose_bf16_kernel<<<dim3(128, 32, NLAYER), 256, 0, stream>>>(w_up, WGU, D_MODEL, HFF, DW, GUW, 2, mlp_norm, D_MODEL);
  transpose_bf16_kernel<<<dim3(32, 128, NLAYER), 256, 0, stream>>>(w_down, WDT, HFF, D_MODEL, DW, DW, 0, nullptr, 0);

  for (int l = 0; l < NLAYER; l++) {
    gemm128_kernel<4><<<(QKV_STRIDE / 128) * (BT / 128), 256, 0, stream>>>(
        Xb, WQKVT + (size_t)l * QKVW, QKVb, nullptr, nullptr, rope_cos, rope_sin,
        Rinv, BT, QKV_STRIDE, D_MODEL, QKV_STRIDE / 128);
    vtrans_kernel<<<dim3(32, 32), 256, 0, stream>>>(QKVb, Vtb);
    attn_kernel<<<dim3(16, 32), 256, 0, stream>>>(QKVb, Vtb, Ob);
    gemm64_kernel<<<(BT / 64) * (D_MODEL / 128), 256, 0, stream>>>(
        Ob, WOT + (size_t)l * DD, X, X, Xb, SsqP, BT, D_MODEL, D_MODEL);
    rinv_kernel<<<BT / 256, 256, 0, stream>>>(SsqP, Rinv);

    gemm128_kernel<5><<<(GU_STRIDE / 128) * (BT / 128), 256, 0, stream>>>(
        Xb, WGU + (size_t)l * GUW, Gb, nullptr, nullptr, nullptr, nullptr,
        Rinv, BT, GU_STRIDE, D_MODEL, 32);
    gemm64_kernel<<<(BT / 64) * (D_MODEL / 128), 256, 0, stream>>>(
        Gb, WDT + (size_t)l * DW, X, X, Xb, SsqP, BT, D_MODEL, HFF);
    rinv_kernel<<<BT / 256, 256, 0, stream>>>(SsqP, Rinv);
  }

  scale_xb_kernel<<<BT * D_MODEL / (256 * 8), 256, 0, stream>>>(Xb, Rinv, XbF);
  gemm128_kernel<0><<<(V_SIZE / 128) * (BT / 128), 256, 0, stream>>>(
      XbF, LMH, out, PartM, PartS, nullptr, nullptr,
      nullptr, BT, V_SIZE, D_MODEL, 50);
  nll_finalize_kernel<<<BT, 64, 0, stream>>>(PartM, PartS, out, targets, NLLb);
  loss_reduce_kernel<<<1, 256, 0, stream>>>(NLLb, out + (size_t)BT * V_SIZE);
}

// Round 16
// 1648.594 us; speedup vs baseline: 2.0584x; 1.0536x over previous
//
#include <hip/hip_runtime.h>

typedef __attribute__((ext_vector_type(8))) short short8;
typedef __attribute__((ext_vector_type(4))) float f32x4;
typedef __attribute__((ext_vector_type(8))) unsigned short u16x8;
typedef unsigned short u16;

#define V_SIZE 32000
#define D_MODEL 1024
#define HFF 4096
#define NHEAD 16
#define HDIM 64
#define NLAYER 4
#define BT 4096   // B*T tokens
#define TSEQ 2048
#define QKV_STRIDE 3072
#define GU_STRIDE 8192
#define QSCALE 0.18033688011112043f   // 0.125 * log2(e), folded into Q at EPI4

__device__ __forceinline__ u16 f2bf(float f) {
  union { float f; unsigned u; } v; v.f = f;
  unsigned r = v.u + 0x7fffu + ((v.u >> 16) & 1u);
  return (u16)(r >> 16);
}
__device__ __forceinline__ float bf2f(u16 h) {
  union { unsigned u; float f; } v; v.u = ((unsigned)h) << 16;
  return v.f;
}

__device__ __forceinline__ void gload_lds16(const void* g, void* l) {
  __builtin_amdgcn_global_load_lds((__attribute__((address_space(1))) void*)g,
                                   (__attribute__((address_space(3))) void*)l, 16, 0, 0);
}

// ---------------- elementwise / small kernels ----------------

__global__ void rope_table_kernel(float* __restrict__ cosb, float* __restrict__ sinb) {
  int i = blockIdx.x * 256 + threadIdx.x;       // 2048*32 = 65536 items
  int t = i >> 5, fi = i & 31;
  float freq = exp2f(-(2.0f * (float)fi / 64.0f) * log2f(10000.0f));
  float ang = (float)t * freq;
  cosb[i] = cosf(ang);
  sinb[i] = sinf(ang);
}

// lm_head fp32 -> bf16, scaled by final_norm[k]
__global__ void convert_bf16_kernel(const float* __restrict__ src, u16* __restrict__ dst,
                                    const float* __restrict__ fn, long n8) {
  long i = (long)blockIdx.x * 256 + threadIdx.x;
  long stride = (long)gridDim.x * 256;
  for (; i < n8; i += stride) {
    const float4* s = (const float4*)(src + i * 8);
    float4 a = s[0], b = s[1];
    int k0 = (int)((i * 8) & (D_MODEL - 1));
    u16x8 r;
    r[0] = f2bf(a.x * fn[k0 + 0]); r[1] = f2bf(a.y * fn[k0 + 1]);
    r[2] = f2bf(a.z * fn[k0 + 2]); r[3] = f2bf(a.w * fn[k0 + 3]);
    r[4] = f2bf(b.x * fn[k0 + 4]); r[5] = f2bf(b.y * fn[k0 + 5]);
    r[6] = f2bf(b.z * fn[k0 + 6]); r[7] = f2bf(b.w * fn[k0 + 7]);
    *(u16x8*)(dst + i * 8) = r;
  }
}

// src [R][C] fp32 -> dst bf16, scaled by nw[src row] if nw != null (norm fold).
// rowMode: 0 -> dst row = c; 1 -> ((c>>6)<<7)|(c&63) (gate); 2 -> +64 (up)
__global__ __launch_bounds__(256) void transpose_bf16_kernel(const float* __restrict__ src0,
                                                             u16* __restrict__ dst0, int R, int C,
                                                             long srcStride, long dstStride,
                                                             int rowMode,
                                                             const float* __restrict__ nw0,
                                                             int nwStride) {
  __shared__ float tile[32][33];
  const float* src = src0 + (size_t)blockIdx.z * srcStride;
  u16* dst = dst0 + (size_t)blockIdx.z * dstStride;
  const float* nw = nw0 ? nw0 + (size_t)blockIdx.z * nwStride : nullptr;
  int tx = threadIdx.x & 31, ty = threadIdx.x >> 5;  // 32 x 8
  int bx = blockIdx.x, by = blockIdx.y;
#pragma unroll
  for (int i = 0; i < 32; i += 8) {
    int r = by * 32 + ty + i, c = bx * 32 + tx;
    tile[ty + i][tx] = src[(size_t)r * C + c];
  }
  __syncthreads();
#pragma unroll
  for (int i = 0; i < 32; i += 8) {
    int c = bx * 32 + ty + i;   // source col
    int r = by * 32 + tx;       // source row (k index) -> dst col
    float val = tile[tx][ty + i];
    if (nw) val *= nw[r];
    int drow = c;
    if (rowMode == 1) drow = ((c >> 6) << 7) | (c & 63);
    else if (rowMode == 2) drow = ((c >> 6) << 7) | 64 | (c & 63);
    dst[(size_t)drow * R + r] = f2bf(val);
  }
}

// embed gather: writes Xb bf16 (residual stream) and rinv[t]. 1 block = 1 token.
__global__ __launch_bounds__(256) void embed_gather_kernel(const int* __restrict__ idx,
                                                           const float* __restrict__ embed,
                                                           u16* __restrict__ xb,
                                                           float* __restrict__ rinv) {
  int t = blockIdx.x;
  int id = idx[t];
  float4 v = ((const float4*)embed)[(size_t)id * 256 + threadIdx.x];
  u16* hp = xb + (size_t)t * D_MODEL + threadIdx.x * 4;
  hp[0] = f2bf(v.x); hp[1] = f2bf(v.y); hp[2] = f2bf(v.z); hp[3] = f2bf(v.w);
  float ss = v.x * v.x + v.y * v.y + v.z * v.z + v.w * v.w;
#pragma unroll
  for (int m = 32; m > 0; m >>= 1) ss += __shfl_xor(ss, m, 64);
  __shared__ float wsum[4];
  if ((threadIdx.x & 63) == 0) wsum[threadIdx.x >> 6] = ss;
  __syncthreads();
  if (threadIdx.x == 0) {
    float tot = wsum[0] + wsum[1] + wsum[2] + wsum[3];
    rinv[t] = rsqrtf(tot * (1.0f / (float)D_MODEL) + 1e-6f);
  }
}

// reduce 16 ssq partials per row -> rinv
__global__ void rinv_kernel(const float* __restrict__ ssqPart, float* __restrict__ rinv) {
  int r = blockIdx.x * 256 + threadIdx.x;   // BT rows
  float s = 0.f;
#pragma unroll
  for (int i = 0; i < 16; i++) s += ssqPart[(size_t)r * 16 + i];
  rinv[r] = rsqrtf(s * (1.0f / (float)D_MODEL) + 1e-6f);
}

// XbF = Xb * rinv[row] (bf16, vectorized)
__global__ void scale_xb_kernel(const u16* __restrict__ xb, const float* __restrict__ rinv,
                                u16* __restrict__ xbf) {
  long i = (long)blockIdx.x * 256 + threadIdx.x;   // item = 8 elems
  int row = (int)(i >> 7);
  float ri = rinv[row];
  short8 v = *(const short8*)(xb + i * 8);
  u16x8 r;
#pragma unroll
  for (int j = 0; j < 8; j++) r[j] = f2bf(bf2f((u16)v[j]) * ri);
  *(u16x8*)(xbf + i * 8) = r;
}

// V (in QKV buffer) -> Vt [bh][64 d][TSEQ t] bf16, tile-transposed via LDS.
__global__ __launch_bounds__(256) void vtrans_kernel(const u16* __restrict__ qkv,
                                                     u16* __restrict__ vt) {
  __shared__ u16 lds[64 * 64];
  const int tid = threadIdx.x;
  const int bh = blockIdx.y, tt = blockIdx.x;
  const int b = bh >> 4, h = bh & 15;
  const int tok0 = b * TSEQ + tt * 64;
  const int hoff = 2 * D_MODEL + h * HDIM;
#pragma unroll
  for (int it = 0; it < 2; it++) {
    int idx = it * 256 + tid;
    int row = idx >> 3, c = (idx & 7) * 8;
    short8 v = *(const short8*)(qkv + (size_t)(tok0 + row) * QKV_STRIDE + hoff + c);
    *(short8*)&lds[row * 64 + (c ^ ((row & 7) << 3))] = v;
  }
  __syncthreads();
#pragma unroll
  for (int it = 0; it < 2; it++) {
    int idx = it * 256 + tid;
    int d = idx >> 3, t0 = (idx & 7) * 8;
    u16x8 pk;
#pragma unroll
    for (int j = 0; j < 8; j++) {
      int t = t0 + j;
      pk[j] = lds[t * 64 + (((d & ~7) ^ ((t & 7) << 3)) | (d & 7))];
    }
    *(u16x8*)(vt + ((size_t)bh * 64 + d) * TSEQ + tt * 64 + t0) = pk;
  }
}

// ---------------- GEMM 128x128 (m97 structure, both-sides swizzle, 4 blocks/CU) ----
// EPI: 0 = lm-head (A pre-normed): fp32 nontemporal store + LSE partials
//      4 = QKV: vv *= rinv (Q cols additionally *= QSCALE), fused RoPE, bf16 store
//      5 = GU fused silu-mul: g,u *= rinv before silu; LDS exchange; N/2 store
template <int EPI>
__global__ __launch_bounds__(256, 4) void gemm128_kernel(const u16* __restrict__ A,
                                                         const u16* __restrict__ B, void* Cp,
                                                         float* __restrict__ partM,
                                                         float* __restrict__ partS,
                                                         const float* __restrict__ cosb,
                                                         const float* __restrict__ sinb,
                                                         const float* __restrict__ rinv,
                                                         int M, int N, int K, int chunkBn) {
  __shared__ __align__(16) u16 smem_ab[2][128 * 64];   // 32 KiB total
  u16* As = smem_ab[0];
  u16* Bs = smem_ab[1];
  const int tid = threadIdx.x;
  const int lane = tid & 63, wid = tid >> 6;
  const int wr = wid >> 1, wc = wid & 1;
  const int q = lane >> 4, l15 = lane & 15;
  const int nbm = M >> 7;
  const int nbmx = nbm >> 3;               // bm rows per XCD
  const int cs = nbm * chunkBn;            // blocks per chunk
  const int chunk = (int)blockIdx.x / cs;
  const int r0 = (int)blockIdx.x - chunk * cs;
  const int s2 = r0 >> 3;
  const int bm = (r0 & 7) * nbmx + (s2 % nbmx);
  const int bn = chunk * chunkBn + (s2 / nbmx);
  const size_t abase = (size_t)bm * 128 * K;
  const size_t bbase = (size_t)bn * 128 * K;
  f32x4 acc[4][4] = {};
  for (int k0 = 0; k0 < K; k0 += 64) {
#pragma unroll
    for (int i = 0; i < 4; i++) {
      int idx8 = i * 256 + tid;
      int row = idx8 >> 3, ch = idx8 & 7;
      int sc = (ch ^ (row & 7)) << 3;
      gload_lds16(A + abase + (size_t)row * K + k0 + sc, As + idx8 * 8);
      gload_lds16(B + bbase + (size_t)row * K + k0 + sc, Bs + idx8 * 8);
    }
    __syncthreads();
#pragma unroll
    for (int ks = 0; ks < 2; ks++) {
      short8 af[4], bfr[4];
      int chunkc = ks * 4 + q;
#pragma unroll
      for (int mi = 0; mi < 4; mi++) {
        int row = wr * 64 + mi * 16 + l15;
        af[mi] = *(const short8*)&As[row * 64 + ((chunkc ^ (row & 7)) << 3)];
      }
#pragma unroll
      for (int ni = 0; ni < 4; ni++) {
        int row = wc * 64 + ni * 16 + l15;
        bfr[ni] = *(const short8*)&Bs[row * 64 + ((chunkc ^ (row & 7)) << 3)];
      }
#pragma unroll
      for (int mi = 0; mi < 4; mi++)
#pragma unroll
        for (int ni = 0; ni < 4; ni++)
          acc[mi][ni] = __builtin_amdgcn_mfma_f32_16x16x32_bf16(af[mi], bfr[ni], acc[mi][ni], 0, 0, 0);
    }
    __syncthreads();
  }

  // ---- EPI 5: fused silu-mul via cross-wave LDS exchange (rinv applied pre-silu) ----
  if (EPI == 5) {
    float* upf = (float*)&smem_ab[0][0];   // 128x64 floats = 32 KiB
    if (wc == 1) {
#pragma unroll
      for (int mi = 0; mi < 4; mi++)
#pragma unroll
        for (int ni = 0; ni < 4; ni++)
#pragma unroll
          for (int j = 0; j < 4; j++) {
            int r = wr * 64 + mi * 16 + q * 4 + j;
            int cswz = (ni ^ ((r >> 2) & 3)) * 16 + l15;
            upf[r * 64 + cswz] = acc[mi][ni][j];
          }
    }
    __syncthreads();
    if (wc == 0) {
#pragma unroll
      for (int mi = 0; mi < 4; mi++)
#pragma unroll
        for (int j = 0; j < 4; j++) {
          int rloc = wr * 64 + mi * 16 + q * 4 + j;
          int rr = bm * 128 + rloc;
          float ri = rinv[rr];
#pragma unroll
          for (int ni = 0; ni < 4; ni++) {
            int cswz = (ni ^ ((rloc >> 2) & 3)) * 16 + l15;
            float g = acc[mi][ni][j] * ri;
            float u = upf[rloc * 64 + cswz] * ri;
            float rsl = g / (1.0f + expf(-g)) * u;
            ((u16*)Cp)[(size_t)rr * (N >> 1) + bn * 64 + ni * 16 + l15] = f2bf(rsl);
          }
        }
    }
    return;
  }

  // ---- EPI 0 / 4 ----
#pragma unroll
  for (int mi = 0; mi < 4; mi++)
#pragma unroll
    for (int j = 0; j < 4; j++) {
      int rr = bm * 128 + wr * 64 + mi * 16 + q * 4 + j;
      float vv[4];
      if (EPI == 4) {
        float ri = rinv[rr];
        if (((bn << 1) + wc) < 16) ri *= QSCALE;   // Q cols: fold softmax scale + log2e
#pragma unroll
        for (int ni = 0; ni < 4; ni++) vv[ni] = acc[mi][ni][j] * ri;
      } else {
#pragma unroll
        for (int ni = 0; ni < 4; ni++) vv[ni] = acc[mi][ni][j];
      }
      if (EPI == 0) {
        float mx = fmaxf(fmaxf(vv[0], vv[1]), fmaxf(vv[2], vv[3]));
        mx = fmaxf(mx, __shfl_xor(mx, 1, 64));
        mx = fmaxf(mx, __shfl_xor(mx, 2, 64));
        mx = fmaxf(mx, __shfl_xor(mx, 4, 64));
        mx = fmaxf(mx, __shfl_xor(mx, 8, 64));
        float sm = 0.f;
#pragma unroll
        for (int ni = 0; ni < 4; ni++) sm += expf(vv[ni] - mx);
        sm += __shfl_xor(sm, 1, 64);
        sm += __shfl_xor(sm, 2, 64);
        sm += __shfl_xor(sm, 4, 64);
        sm += __shfl_xor(sm, 8, 64);
        if (l15 == 0) {
          int nt = (N >> 6);
          partM[(size_t)rr * nt + (bn << 1) + wc] = mx;
          partS[(size_t)rr * nt + (bn << 1) + wc] = sm;
        }
      }
      if (EPI == 4) {
        if (((bn << 1) + wc) < 32) {   // Q or K cols: wave-uniform RoPE
          int t = rr & (TSEQ - 1);
#pragma unroll
          for (int ni = 0; ni < 2; ni++) {
            int fi = ni * 16 + l15;
            float c = cosb[t * 32 + fi], s = sinb[t * 32 + fi];
            float x1 = vv[ni], x2 = vv[ni + 2];
            vv[ni] = x1 * c - x2 * s;
            vv[ni + 2] = x2 * c + x1 * s;
          }
        }
      }
#pragma unroll
      for (int ni = 0; ni < 4; ni++) {
        int cn = bn * 128 + wc * 64 + ni * 16 + l15;
        size_t off = (size_t)rr * N + cn;
        if (EPI == 0) __builtin_nontemporal_store(vv[ni], (float*)Cp + off);
        else ((u16*)Cp)[off] = f2bf(vv[ni]);
      }
    }
}

// ---------------- GEMM 64x128 for N=1024 projections (o-proj / down-proj) ----------
// 512 blocks = 2 blocks/CU = 8 waves/CU. LDS 24 KiB.
// EPI: bf16 residual add (resid == xbout, in-place per-element) + ssq partials.
__global__ __launch_bounds__(256, 4) void gemm64_kernel(const u16* __restrict__ A,
                                                        const u16* __restrict__ B,
                                                        const u16* __restrict__ resid,
                                                        u16* __restrict__ xbout,
                                                        float* __restrict__ ssqPart,
                                                        int M, int N, int K) {
  __shared__ __align__(16) u16 As[64 * 64];    // 8 KiB
  __shared__ __align__(16) u16 Bs[128 * 64];   // 16 KiB
  const int tid = threadIdx.x;
  const int lane = tid & 63, wid = tid >> 6;
  const int wr = wid >> 1, wc = wid & 1;
  const int q = lane >> 4, l15 = lane & 15;
  const int nbm = M >> 6;                  // 64
  const int nbmx = nbm >> 3;               // 8 bm rows per XCD
  const int s2 = (int)blockIdx.x >> 3;
  const int bm = ((int)blockIdx.x & 7) * nbmx + (s2 % nbmx);
  const int bn = s2 / nbmx;
  const size_t abase = (size_t)bm * 64 * K;
  const size_t bbase = (size_t)bn * 128 * K;
  f32x4 acc[2][4] = {};
  for (int k0 = 0; k0 < K; k0 += 64) {
#pragma unroll
    for (int i = 0; i < 2; i++) {
      int idx8 = i * 256 + tid;
      int row = idx8 >> 3, ch = idx8 & 7;
      int sc = (ch ^ (row & 7)) << 3;
      gload_lds16(A + abase + (size_t)row * K + k0 + sc, As + idx8 * 8);
    }
#pragma unroll
    for (int i = 0; i < 4; i++) {
      int idx8 = i * 256 + tid;
      int row = idx8 >> 3, ch = idx8 & 7;
      int sc = (ch ^ (row & 7)) << 3;
      gload_lds16(B + bbase + (size_t)row * K + k0 + sc, Bs + idx8 * 8);
    }
    __syncthreads();
#pragma unroll
    for (int ks = 0; ks < 2; ks++) {
      short8 af[2], bfr[4];
      int chunkc = ks * 4 + q;
#pragma unroll
      for (int mi = 0; mi < 2; mi++) {
        int row = wr * 32 + mi * 16 + l15;
        af[mi] = *(const short8*)&As[row * 64 + ((chunkc ^ (row & 7)) << 3)];
      }
#pragma unroll
      for (int ni = 0; ni < 4; ni++) {
        int row = wc * 64 + ni * 16 + l15;
        bfr[ni] = *(const short8*)&Bs[row * 64 + ((chunkc ^ (row & 7)) << 3)];
      }
#pragma unroll
      for (int mi = 0; mi < 2; mi++)
#pragma unroll
        for (int ni = 0; ni < 4; ni++)
          acc[mi][ni] = __builtin_amdgcn_mfma_f32_16x16x32_bf16(af[mi], bfr[ni], acc[mi][ni], 0, 0, 0);
    }
    __syncthreads();
  }
  // epilogue: bf16 residual add + ssq partials
#pragma unroll
  for (int mi = 0; mi < 2; mi++)
#pragma unroll
    for (int j = 0; j < 4; j++) {
      int rr = bm * 64 + wr * 32 + mi * 16 + q * 4 + j;
      float ssq = 0.f;
#pragma unroll
      for (int ni = 0; ni < 4; ni++) {
        int cn = bn * 128 + wc * 64 + ni * 16 + l15;
        size_t off = (size_t)rr * N + cn;
        float nx = bf2f(resid[off]) + acc[mi][ni][j];
        xbout[off] = f2bf(nx);
        ssq += nx * nx;
      }
      ssq += __shfl_xor(ssq, 1, 64);
      ssq += __shfl_xor(ssq, 2, 64);
      ssq += __shfl_xor(ssq, 4, 64);
      ssq += __shfl_xor(ssq, 8, 64);
      if (l15 == 0) ssqPart[(size_t)rr * 16 + (bn << 1) + wc] = ssq;
    }
}

// ---------------- flash attention (64-row q-tiles, exp2 domain, diag-only mask) ----
// Scores arrive pre-scaled by 0.125*log2e (folded into Q); softmax uses exp2f.
// grid (16, 32): block i handles qt = i then 31-i -> uniform 33 K-tile units.
__global__ __launch_bounds__(256) void attn_kernel(const u16* __restrict__ qkv,
                                                   const u16* __restrict__ vt,
                                                   u16* __restrict__ o) {
  __shared__ __align__(16) u16 Ks[64 * 64];
  __shared__ __align__(16) u16 Vt[64 * 64];
  __shared__ u16 Ps[4][16 * 64];
  const u16* q = qkv;
  const u16* k = qkv + D_MODEL;
  const int tid = threadIdx.x, lane = tid & 63, wid = tid >> 6;
  const int qg = lane >> 4, l15 = lane & 15;
  const int bh = blockIdx.y;
  const int b = bh >> 4, h = bh & 15;
  const int tok0 = b * TSEQ;
  const int hoff = h * HDIM;
  const u16* vtb = vt + (size_t)bh * 64 * TSEQ;

  for (int half = 0; half < 2; half++) {
    const int qt = half == 0 ? (int)blockIdx.x : 31 - (int)blockIdx.x;
    const int qrow0 = qt * 64 + wid * 16;

    short8 aq[2];
#pragma unroll
    for (int ks = 0; ks < 2; ks++) {
      int r = qrow0 + l15;
      int d = ks * 32 + qg * 8;
      aq[ks] = *(const short8*)(q + (size_t)(tok0 + r) * QKV_STRIDE + hoff + d);
    }
    f32x4 oacc[4] = {};
    float mrow[4], lrow[4];
#pragma unroll
    for (int j = 0; j < 4; j++) { mrow[j] = -1e30f; lrow[j] = 0.f; }

    const int nkt = qt + 1;
    for (int kt = 0; kt < nkt; kt++) {
      const int kv0 = kt * 64;
#pragma unroll
      for (int it = 0; it < 2; it++) {
        int idx = it * 256 + tid;
        int row = idx >> 3, ch = idx & 7;
        int sc = (ch ^ (row & 7)) << 3;
        gload_lds16(k + (size_t)(tok0 + kv0 + row) * QKV_STRIDE + hoff + sc, Ks + idx * 8);
        gload_lds16(vtb + (size_t)row * TSEQ + kv0 + sc, Vt + idx * 8);
      }
      __syncthreads();
      f32x4 sc[4] = {};
#pragma unroll
      for (int ks = 0; ks < 2; ks++) {
        short8 bk[4];
        int kcol = ks * 32 + qg * 8;
#pragma unroll
        for (int ni = 0; ni < 4; ni++) {
          int r = ni * 16 + l15;
          bk[ni] = *(const short8*)&Ks[r * 64 + (kcol ^ ((r & 7) << 3))];
        }
#pragma unroll
        for (int ni = 0; ni < 4; ni++)
          sc[ni] = __builtin_amdgcn_mfma_f32_16x16x32_bf16(aq[ks], bk[ni], sc[ni], 0, 0, 0);
      }
      float pm[4];
#pragma unroll
      for (int j = 0; j < 4; j++) pm[j] = -1e30f;
      if (kt == qt) {
        // diagonal tile: causal mask needed
#pragma unroll
        for (int ni = 0; ni < 4; ni++)
#pragma unroll
          for (int j = 0; j < 4; j++) {
            int rq = qrow0 + qg * 4 + j;
            int ck = kv0 + ni * 16 + l15;
            float s = sc[ni][j];
            if (ck > rq) s = -1e30f;
            sc[ni][j] = s;
            pm[j] = fmaxf(pm[j], s);
          }
      } else {
        // strictly-below-diagonal tile: all positions valid
#pragma unroll
        for (int ni = 0; ni < 4; ni++)
#pragma unroll
          for (int j = 0; j < 4; j++) pm[j] = fmaxf(pm[j], sc[ni][j]);
      }
#pragma unroll
      for (int j = 0; j < 4; j++) {
        float t = pm[j];
        t = fmaxf(t, __shfl_xor(t, 1, 64));
        t = fmaxf(t, __shfl_xor(t, 2, 64));
        t = fmaxf(t, __shfl_xor(t, 4, 64));
        t = fmaxf(t, __shfl_xor(t, 8, 64));
        pm[j] = t;
      }
#pragma unroll
      for (int j = 0; j < 4; j++) {
        float mn = fmaxf(mrow[j], pm[j]);
        float fac = exp2f(mrow[j] - mn);
        lrow[j] *= fac;
#pragma unroll
        for (int df = 0; df < 4; df++) oacc[df][j] *= fac;
        mrow[j] = mn;
      }
      float psum[4] = {};
#pragma unroll
      for (int ni = 0; ni < 4; ni++)
#pragma unroll
        for (int j = 0; j < 4; j++) {
          float p = exp2f(sc[ni][j] - mrow[j]);
          psum[j] += p;
          int r16 = qg * 4 + j;
          int cc = ni * 16 + l15;
          Ps[wid][r16 * 64 + (cc ^ ((r16 & 7) << 3))] = f2bf(p);
        }
#pragma unroll
      for (int j = 0; j < 4; j++) {
        float t = psum[j];
        t += __shfl_xor(t, 1, 64);
        t += __shfl_xor(t, 2, 64);
        t += __shfl_xor(t, 4, 64);
        t += __shfl_xor(t, 8, 64);
        lrow[j] += t;
      }
#pragma unroll
      for (int kf = 0; kf < 2; kf++) {
        short8 pa, bv[4];
        int kcol = kf * 32 + qg * 8;
        {
          int r = l15;
          pa = *(const short8*)&Ps[wid][r * 64 + (kcol ^ ((r & 7) << 3))];
        }
#pragma unroll
        for (int df = 0; df < 4; df++) {
          int r = df * 16 + l15;
          bv[df] = *(const short8*)&Vt[r * 64 + (kcol ^ ((r & 7) << 3))];
        }
#pragma unroll
        for (int df = 0; df < 4; df++)
          oacc[df] = __builtin_amdgcn_mfma_f32_16x16x32_bf16(pa, bv[df], oacc[df], 0, 0, 0);
      }
      __syncthreads();
    }
#pragma unroll
    for (int df = 0; df < 4; df++)
#pragma unroll
      for (int j = 0; j < 4; j++) {
        int r = qrow0 + qg * 4 + j;
        int d = df * 16 + l15;
        float val = oacc[df][j] / lrow[j];
        o[(size_t)(tok0 + r) * D_MODEL + hoff + d] = f2bf(val);
      }
  }
}

// ---------------- loss ----------------

__global__ void nll_finalize_kernel(const float* __restrict__ partM, const float* __restrict__ partS,
                                    const float* __restrict__ logits, const int* __restrict__ targets,
                                    float* __restrict__ nll) {
  int tok = blockIdx.x;
  int lane = threadIdx.x;    // 64
  const int NTL = V_SIZE >> 6;  // 500
  float m = -1e30f, s = 0.f;
  for (int i = lane; i < NTL; i += 64) {
    float m2 = partM[(size_t)tok * NTL + i];
    float s2 = partS[(size_t)tok * NTL + i];
    float nm = fmaxf(m, m2);
    s = s * expf(m - nm) + s2 * expf(m2 - nm);
    m = nm;
  }
#pragma unroll
  for (int mask = 1; mask < 64; mask <<= 1) {
    float m2 = __shfl_xor(m, mask, 64);
    float s2 = __shfl_xor(s, mask, 64);
    float nm = fmaxf(m, m2);
    s = s * expf(m - nm) + s2 * expf(m2 - nm);
    m = nm;
  }
  if (lane == 0)
    nll[tok] = m + logf(s) - logits[(size_t)tok * V_SIZE + targets[tok]];
}

__global__ void loss_reduce_kernel(const float* __restrict__ nll, float* __restrict__ out) {
  float s = 0.f;
  for (int i = threadIdx.x; i < BT; i += 256) s += nll[i];
#pragma unroll
  for (int mask = 1; mask < 64; mask <<= 1) s += __shfl_xor(s, mask, 64);
  __shared__ float sm[4];
  if ((threadIdx.x & 63) == 0) sm[threadIdx.x >> 6] = s;
  __syncthreads();
  if (threadIdx.x == 0) out[0] = (sm[0] + sm[1] + sm[2] + sm[3]) / (float)BT;
}

// ---------------- host launcher ----------------

extern "C" void kernel_launch(void* const* d_in, const int* in_sizes, int n_in,
                              void* d_out, int out_size, void* d_ws, size_t ws_size,
                              hipStream_t stream) {
  const int* idx = (const int*)d_in[0];
  const int* targets = (const int*)d_in[1];
  const float* embed = (const float*)d_in[2];
  const float* wq = (const float*)d_in[3];
  const float* wk = (const float*)d_in[4];
  const float* wv = (const float*)d_in[5];
  const float* wo = (const float*)d_in[6];
  const float* w_gate = (const float*)d_in[7];
  const float* w_up = (const float*)d_in[8];
  const float* w_down = (const float*)d_in[9];
  const float* attn_norm = (const float*)d_in[10];
  const float* mlp_norm = (const float*)d_in[11];
  const float* final_norm = (const float*)d_in[12];
  const float* lm_head = (const float*)d_in[13];
  float* out = (float*)d_out;

  char* ws = (char*)d_ws;
  size_t off = 0;
  auto alloc = [&](size_t bytes) {
    void* p = ws + off;
    off += (bytes + 255) & ~(size_t)255;
    return p;
  };
  const size_t DD = (size_t)D_MODEL * D_MODEL;
  float* rope_cos = (float*)alloc((size_t)TSEQ * 32 * 4);
  float* rope_sin = (float*)alloc((size_t)TSEQ * 32 * 4);
  u16* Xb = (u16*)alloc((size_t)BT * D_MODEL * 2);
  u16* XbF = (u16*)alloc((size_t)BT * D_MODEL * 2);
  float* Rinv = (float*)alloc((size_t)BT * 4);
  float* SsqP = (float*)alloc((size_t)BT * 16 * 4);
  u16* QKVb = (u16*)alloc((size_t)BT * QKV_STRIDE * 2);
  u16* Vtb = (u16*)alloc((size_t)32 * 64 * TSEQ * 2);
  u16* Ob = (u16*)alloc((size_t)BT * D_MODEL * 2);
  u16* Gb = (u16*)alloc((size_t)BT * HFF * 2);
  u16* WQKVT = (u16*)alloc((size_t)NLAYER * QKV_STRIDE * D_MODEL * 2);
  u16* WOT = (u16*)alloc((size_t)NLAYER * DD * 2);
  u16* WGU = (u16*)alloc((size_t)NLAYER * GU_STRIDE * D_MODEL * 2);
  u16* WDT = (u16*)alloc((size_t)NLAYER * D_MODEL * HFF * 2);
  u16* LMH = (u16*)alloc((size_t)V_SIZE * D_MODEL * 2);
  float* NLLb = (float*)alloc((size_t)BT * 4);
  float* PartM = (float*)alloc((size_t)BT * (V_SIZE >> 6) * 4);
  float* PartS = (float*)alloc((size_t)BT * (V_SIZE >> 6) * 4);

  rope_table_kernel<<<256, 256, 0, stream>>>(rope_cos, rope_sin);
  convert_bf16_kernel<<<4096, 256, 0, stream>>>(lm_head, LMH, final_norm, (long)V_SIZE * D_MODEL / 8);
  embed_gather_kernel<<<BT, 256, 0, stream>>>(idx, embed, Xb, Rinv);

  const long QKVW = (long)QKV_STRIDE * D_MODEL;
  const long GUW = (long)GU_STRIDE * D_MODEL;
  const long DW = (long)D_MODEL * HFF;
  transpose_bf16_kernel<<<dim3(32, 32, NLAYER), 256, 0, stream>>>(wq, WQKVT, D_MODEL, D_MODEL, DD, QKVW, 0, attn_norm, D_MODEL);
  transpose_bf16_kernel<<<dim3(32, 32, NLAYER), 256, 0, stream>>>(wk, WQKVT + DD, D_MODEL, D_MODEL, DD, QKVW, 0, attn_norm, D_MODEL);
  transpose_bf16_kernel<<<dim3(32, 32, NLAYER), 256, 0, stream>>>(wv, WQKVT + 2 * DD, D_MODEL, D_MODEL, DD, QKVW, 0, attn_norm, D_MODEL);
  transpose_bf16_kernel<<<dim3(32, 32, NLAYER), 256, 0, stream>>>(wo, WOT, D_MODEL, D_MODEL, DD, DD, 0, nullptr, 0);
  transpose_bf16_kernel<<<dim3(128, 32, NLAYER), 256, 0, stream>>>(w_gate, WGU, D_MODEL, HFF, DW, GUW, 1, mlp_norm, D_MODEL);
  transpose_bf16_kernel<<<dim3(128, 32, NLAYER), 256, 0, stream>>>(w_up, WGU, D_MODEL, HFF, DW, GUW, 2, mlp_norm, D_MODEL);
  transpose_bf16_kernel<<<dim3(32, 128, NLAYER), 256, 0, stream>>>(w_down, WDT, HFF, D_MODEL, DW, DW, 0, nullptr, 0);

  for (int l = 0; l < NLAYER; l++) {
    gemm128_kernel<4><<<(QKV_STRIDE / 128) * (BT / 128), 256, 0, stream>>>(
        Xb, WQKVT + (size_t)l * QKVW, QKVb, nullptr, nullptr, rope_cos, rope_sin,
        Rinv, BT, QKV_STRIDE, D_MODEL, QKV_STRIDE / 128);
    vtrans_kernel<<<dim3(32, 32), 256, 0, stream>>>(QKVb, Vtb);
    attn_kernel<<<dim3(16, 32), 256, 0, stream>>>(QKVb, Vtb, Ob);
    gemm64_kernel<<<(BT / 64) * (D_MODEL / 128), 256, 0, stream>>>(
        Ob, WOT + (size_t)l * DD, Xb, Xb, SsqP, BT, D_MODEL, D_MODEL);
    rinv_kernel<<<BT / 256, 256, 0, stream>>>(SsqP, Rinv);

    gemm128_kernel<5><<<(GU_STRIDE / 128) * (BT / 128), 256, 0, stream>>>(
        Xb, WGU + (size_t)l * GUW, Gb, nullptr, nullptr, nullptr, nullptr,
        Rinv, BT, GU_STRIDE, D_MODEL, 32);
    gemm64_kernel<<<(BT / 64) * (D_MODEL / 128), 256, 0, stream>>>(
        Gb, WDT + (size_t)l * DW, Xb, Xb, SsqP, BT, D_MODEL, HFF);
    rinv_kernel<<<BT / 256, 256, 0, stream>>>(SsqP, Rinv);
  }

  scale_xb_kernel<<<BT * D_MODEL / (256 * 8), 256, 0, stream>>>(Xb, Rinv, XbF);
  gemm128_kernel<0><<<(V_SIZE / 128) * (BT / 128), 256, 0, stream>>>(
      XbF, LMH, out, PartM, PartS, nullptr, nullptr,
      nullptr, BT, V_SIZE, D_MODEL, 50);
  nll_finalize_kernel<<<BT, 64, 0, stream>>>(PartM, PartS, out, targets, NLLb);
  loss_reduce_kernel<<<1, 256, 0, stream>>>(NLLb, out + (size_t)BT * V_SIZE);
}

// Round 17
// 1612.926 us; speedup vs baseline: 2.1039x; 1.0221x over previous
//
#include <hip/hip_runtime.h>

typedef __attribute__((ext_vector_type(8))) short short8;
typedef __attribute__((ext_vector_type(4))) float f32x4;
typedef __attribute__((ext_vector_type(8))) unsigned short u16x8;
typedef unsigned short u16;

#define V_SIZE 32000
#define D_MODEL 1024
#define HFF 4096
#define NHEAD 16
#define HDIM 64
#define NLAYER 4
#define BT 4096   // B*T tokens
#define TSEQ 2048
#define QKV_STRIDE 3072
#define GU_STRIDE 8192
#define QSCALE 0.18033688011112043f   // 0.125 * log2(e), folded into Q at EPI4

__device__ __forceinline__ u16 f2bf(float f) {
  union { float f; unsigned u; } v; v.f = f;
  unsigned r = v.u + 0x7fffu + ((v.u >> 16) & 1u);
  return (u16)(r >> 16);
}
__device__ __forceinline__ float bf2f(u16 h) {
  union { unsigned u; float f; } v; v.u = ((unsigned)h) << 16;
  return v.f;
}

__device__ __forceinline__ void gload_lds16(const void* g, void* l) {
  __builtin_amdgcn_global_load_lds((__attribute__((address_space(1))) void*)g,
                                   (__attribute__((address_space(3))) void*)l, 16, 0, 0);
}

// ---------------- elementwise / small kernels ----------------

__global__ void rope_table_kernel(float* __restrict__ cosb, float* __restrict__ sinb) {
  int i = blockIdx.x * 256 + threadIdx.x;       // 2048*32 = 65536 items
  int t = i >> 5, fi = i & 31;
  float freq = exp2f(-(2.0f * (float)fi / 64.0f) * log2f(10000.0f));
  float ang = (float)t * freq;
  cosb[i] = cosf(ang);
  sinb[i] = sinf(ang);
}

// lm_head fp32 -> bf16, scaled by final_norm[k]
__global__ void convert_bf16_kernel(const float* __restrict__ src, u16* __restrict__ dst,
                                    const float* __restrict__ fn, long n8) {
  long i = (long)blockIdx.x * 256 + threadIdx.x;
  long stride = (long)gridDim.x * 256;
  for (; i < n8; i += stride) {
    const float4* s = (const float4*)(src + i * 8);
    float4 a = s[0], b = s[1];
    int k0 = (int)((i * 8) & (D_MODEL - 1));
    u16x8 r;
    r[0] = f2bf(a.x * fn[k0 + 0]); r[1] = f2bf(a.y * fn[k0 + 1]);
    r[2] = f2bf(a.z * fn[k0 + 2]); r[3] = f2bf(a.w * fn[k0 + 3]);
    r[4] = f2bf(b.x * fn[k0 + 4]); r[5] = f2bf(b.y * fn[k0 + 5]);
    r[6] = f2bf(b.z * fn[k0 + 6]); r[7] = f2bf(b.w * fn[k0 + 7]);
    *(u16x8*)(dst + i * 8) = r;
  }
}

// src [R][C] fp32 -> dst bf16, scaled by nw[src row] if nw != null (norm fold).
// rowMode: 0 -> dst row = c
//          1 -> ((c>>4)<<5)|(c&15)        (gate cols, 16-col interleave)
//          2 -> ((c>>4)<<5)|16|(c&15)     (up cols, partner rows)
__global__ __launch_bounds__(256) void transpose_bf16_kernel(const float* __restrict__ src0,
                                                             u16* __restrict__ dst0, int R, int C,
                                                             long srcStride, long dstStride,
                                                             int rowMode,
                                                             const float* __restrict__ nw0,
                                                             int nwStride) {
  __shared__ float tile[32][33];
  const float* src = src0 + (size_t)blockIdx.z * srcStride;
  u16* dst = dst0 + (size_t)blockIdx.z * dstStride;
  const float* nw = nw0 ? nw0 + (size_t)blockIdx.z * nwStride : nullptr;
  int tx = threadIdx.x & 31, ty = threadIdx.x >> 5;  // 32 x 8
  int bx = blockIdx.x, by = blockIdx.y;
#pragma unroll
  for (int i = 0; i < 32; i += 8) {
    int r = by * 32 + ty + i, c = bx * 32 + tx;
    tile[ty + i][tx] = src[(size_t)r * C + c];
  }
  __syncthreads();
#pragma unroll
  for (int i = 0; i < 32; i += 8) {
    int c = bx * 32 + ty + i;   // source col
    int r = by * 32 + tx;       // source row (k index) -> dst col
    float val = tile[tx][ty + i];
    if (nw) val *= nw[r];
    int drow = c;
    if (rowMode == 1) drow = ((c >> 4) << 5) | (c & 15);
    else if (rowMode == 2) drow = ((c >> 4) << 5) | 16 | (c & 15);
    dst[(size_t)drow * R + r] = f2bf(val);
  }
}

// embed gather: writes Xb bf16 (residual stream) and rinv[t]. 1 block = 1 token.
__global__ __launch_bounds__(256) void embed_gather_kernel(const int* __restrict__ idx,
                                                           const float* __restrict__ embed,
                                                           u16* __restrict__ xb,
                                                           float* __restrict__ rinv) {
  int t = blockIdx.x;
  int id = idx[t];
  float4 v = ((const float4*)embed)[(size_t)id * 256 + threadIdx.x];
  u16* hp = xb + (size_t)t * D_MODEL + threadIdx.x * 4;
  hp[0] = f2bf(v.x); hp[1] = f2bf(v.y); hp[2] = f2bf(v.z); hp[3] = f2bf(v.w);
  float ss = v.x * v.x + v.y * v.y + v.z * v.z + v.w * v.w;
#pragma unroll
  for (int m = 32; m > 0; m >>= 1) ss += __shfl_xor(ss, m, 64);
  __shared__ float wsum[4];
  if ((threadIdx.x & 63) == 0) wsum[threadIdx.x >> 6] = ss;
  __syncthreads();
  if (threadIdx.x == 0) {
    float tot = wsum[0] + wsum[1] + wsum[2] + wsum[3];
    rinv[t] = rsqrtf(tot * (1.0f / (float)D_MODEL) + 1e-6f);
  }
}

// reduce 16 ssq partials per row -> rinv
__global__ void rinv_kernel(const float* __restrict__ ssqPart, float* __restrict__ rinv) {
  int r = blockIdx.x * 256 + threadIdx.x;   // BT rows
  float s = 0.f;
#pragma unroll
  for (int i = 0; i < 16; i++) s += ssqPart[(size_t)r * 16 + i];
  rinv[r] = rsqrtf(s * (1.0f / (float)D_MODEL) + 1e-6f);
}

// XbF = Xb * rinv[row] (bf16, vectorized)
__global__ void scale_xb_kernel(const u16* __restrict__ xb, const float* __restrict__ rinv,
                                u16* __restrict__ xbf) {
  long i = (long)blockIdx.x * 256 + threadIdx.x;   // item = 8 elems
  int row = (int)(i >> 7);
  float ri = rinv[row];
  short8 v = *(const short8*)(xb + i * 8);
  u16x8 r;
#pragma unroll
  for (int j = 0; j < 8; j++) r[j] = f2bf(bf2f((u16)v[j]) * ri);
  *(u16x8*)(xbf + i * 8) = r;
}

// V (in QKV buffer) -> Vt [bh][64 d][TSEQ t] bf16, tile-transposed via LDS.
__global__ __launch_bounds__(256) void vtrans_kernel(const u16* __restrict__ qkv,
                                                     u16* __restrict__ vt) {
  __shared__ u16 lds[64 * 64];
  const int tid = threadIdx.x;
  const int bh = blockIdx.y, tt = blockIdx.x;
  const int b = bh >> 4, h = bh & 15;
  const int tok0 = b * TSEQ + tt * 64;
  const int hoff = 2 * D_MODEL + h * HDIM;
#pragma unroll
  for (int it = 0; it < 2; it++) {
    int idx = it * 256 + tid;
    int row = idx >> 3, c = (idx & 7) * 8;
    short8 v = *(const short8*)(qkv + (size_t)(tok0 + row) * QKV_STRIDE + hoff + c);
    *(short8*)&lds[row * 64 + (c ^ ((row & 7) << 3))] = v;
  }
  __syncthreads();
#pragma unroll
  for (int it = 0; it < 2; it++) {
    int idx = it * 256 + tid;
    int d = idx >> 3, t0 = (idx & 7) * 8;
    u16x8 pk;
#pragma unroll
    for (int j = 0; j < 8; j++) {
      int t = t0 + j;
      pk[j] = lds[t * 64 + (((d & ~7) ^ ((t & 7) << 3)) | (d & 7))];
    }
    *(u16x8*)(vt + ((size_t)bh * 64 + d) * TSEQ + tt * 64 + t0) = pk;
  }
}

// ---------------- GEMM 128x128 (m97 structure, both-sides swizzle, 4 blocks/CU) ----
// EPI: 0 = lm-head (A pre-normed): fp32 nontemporal store + LSE partials
//      4 = QKV: vv *= rinv (Q cols additionally *= QSCALE), fused RoPE, bf16 store
//      5 = GU fused silu-mul, PAIRWISE (B rows 16-col-interleaved gate/up: lane holds
//          the (g,u) pair in acc[ni]/acc[ni+1] -> no LDS exchange); N/2-wide store
template <int EPI>
__global__ __launch_bounds__(256, 4) void gemm128_kernel(const u16* __restrict__ A,
                                                         const u16* __restrict__ B, void* Cp,
                                                         float* __restrict__ partM,
                                                         float* __restrict__ partS,
                                                         const float* __restrict__ cosb,
                                                         const float* __restrict__ sinb,
                                                         const float* __restrict__ rinv,
                                                         int M, int N, int K, int chunkBn) {
  __shared__ __align__(16) u16 As[128 * 64];
  __shared__ __align__(16) u16 Bs[128 * 64];
  const int tid = threadIdx.x;
  const int lane = tid & 63, wid = tid >> 6;
  const int wr = wid >> 1, wc = wid & 1;
  const int q = lane >> 4, l15 = lane & 15;
  const int nbm = M >> 7;
  const int nbmx = nbm >> 3;               // bm rows per XCD
  const int cs = nbm * chunkBn;            // blocks per chunk
  const int chunk = (int)blockIdx.x / cs;
  const int r0 = (int)blockIdx.x - chunk * cs;
  const int s2 = r0 >> 3;
  const int bm = (r0 & 7) * nbmx + (s2 % nbmx);
  const int bn = chunk * chunkBn + (s2 / nbmx);
  const size_t abase = (size_t)bm * 128 * K;
  const size_t bbase = (size_t)bn * 128 * K;
  f32x4 acc[4][4] = {};
  for (int k0 = 0; k0 < K; k0 += 64) {
#pragma unroll
    for (int i = 0; i < 4; i++) {
      int idx8 = i * 256 + tid;
      int row = idx8 >> 3, ch = idx8 & 7;
      int sc = (ch ^ (row & 7)) << 3;
      gload_lds16(A + abase + (size_t)row * K + k0 + sc, As + idx8 * 8);
      gload_lds16(B + bbase + (size_t)row * K + k0 + sc, Bs + idx8 * 8);
    }
    __syncthreads();
#pragma unroll
    for (int ks = 0; ks < 2; ks++) {
      short8 af[4], bfr[4];
      int chunkc = ks * 4 + q;
#pragma unroll
      for (int mi = 0; mi < 4; mi++) {
        int row = wr * 64 + mi * 16 + l15;
        af[mi] = *(const short8*)&As[row * 64 + ((chunkc ^ (row & 7)) << 3)];
      }
#pragma unroll
      for (int ni = 0; ni < 4; ni++) {
        int row = wc * 64 + ni * 16 + l15;
        bfr[ni] = *(const short8*)&Bs[row * 64 + ((chunkc ^ (row & 7)) << 3)];
      }
#pragma unroll
      for (int mi = 0; mi < 4; mi++)
#pragma unroll
        for (int ni = 0; ni < 4; ni++)
          acc[mi][ni] = __builtin_amdgcn_mfma_f32_16x16x32_bf16(af[mi], bfr[ni], acc[mi][ni], 0, 0, 0);
    }
    __syncthreads();
  }

  // ---- EPI 5: pairwise silu-mul (g at ni even, u at ni odd, same lane) ----
  if (EPI == 5) {
#pragma unroll
    for (int mi = 0; mi < 4; mi++)
#pragma unroll
      for (int j = 0; j < 4; j++) {
        int rr = bm * 128 + wr * 64 + mi * 16 + q * 4 + j;
        float ri = rinv[rr];
#pragma unroll
        for (int pr = 0; pr < 2; pr++) {
          float g = acc[mi][pr * 2][j] * ri;
          float u = acc[mi][pr * 2 + 1][j] * ri;
          float rsl = g / (1.0f + expf(-g)) * u;
          int cn = (bn * 4 + wc * 2 + pr) * 16 + l15;
          ((u16*)Cp)[(size_t)rr * (N >> 1) + cn] = f2bf(rsl);
        }
      }
    return;
  }

  // ---- EPI 0 / 4 ----
#pragma unroll
  for (int mi = 0; mi < 4; mi++)
#pragma unroll
    for (int j = 0; j < 4; j++) {
      int rr = bm * 128 + wr * 64 + mi * 16 + q * 4 + j;
      float vv[4];
      if (EPI == 4) {
        float ri = rinv[rr];
        if (((bn << 1) + wc) < 16) ri *= QSCALE;   // Q cols: fold softmax scale + log2e
#pragma unroll
        for (int ni = 0; ni < 4; ni++) vv[ni] = acc[mi][ni][j] * ri;
      } else {
#pragma unroll
        for (int ni = 0; ni < 4; ni++) vv[ni] = acc[mi][ni][j];
      }
      if (EPI == 0) {
        float mx = fmaxf(fmaxf(vv[0], vv[1]), fmaxf(vv[2], vv[3]));
        mx = fmaxf(mx, __shfl_xor(mx, 1, 64));
        mx = fmaxf(mx, __shfl_xor(mx, 2, 64));
        mx = fmaxf(mx, __shfl_xor(mx, 4, 64));
        mx = fmaxf(mx, __shfl_xor(mx, 8, 64));
        float sm = 0.f;
#pragma unroll
        for (int ni = 0; ni < 4; ni++) sm += expf(vv[ni] - mx);
        sm += __shfl_xor(sm, 1, 64);
        sm += __shfl_xor(sm, 2, 64);
        sm += __shfl_xor(sm, 4, 64);
        sm += __shfl_xor(sm, 8, 64);
        if (l15 == 0) {
          int nt = (N >> 6);
          partM[(size_t)rr * nt + (bn << 1) + wc] = mx;
          partS[(size_t)rr * nt + (bn << 1) + wc] = sm;
        }
      }
      if (EPI == 4) {
        if (((bn << 1) + wc) < 32) {   // Q or K cols: wave-uniform RoPE
          int t = rr & (TSEQ - 1);
#pragma unroll
          for (int ni = 0; ni < 2; ni++) {
            int fi = ni * 16 + l15;
            float c = cosb[t * 32 + fi], s = sinb[t * 32 + fi];
            float x1 = vv[ni], x2 = vv[ni + 2];
            vv[ni] = x1 * c - x2 * s;
            vv[ni + 2] = x2 * c + x1 * s;
          }
        }
      }
#pragma unroll
      for (int ni = 0; ni < 4; ni++) {
        int cn = bn * 128 + wc * 64 + ni * 16 + l15;
        size_t off = (size_t)rr * N + cn;
        if (EPI == 0) __builtin_nontemporal_store(vv[ni], (float*)Cp + off);
        else ((u16*)Cp)[off] = f2bf(vv[ni]);
      }
    }
}

// ---------------- GEMM 64x128 for N=1024 projections (o-proj / down-proj) ----------
// Double-buffered LDS (48 KiB; grid 512 = 2 blocks/CU, grid-limited): stage(kt+1)
// issued BEFORE compute(kt); single counted-cover vmcnt(0)+raw-barrier per K-tile.
// EPI: bf16 residual add (resid == xbout, in-place per-element) + ssq partials.
__global__ __launch_bounds__(256, 2) void gemm64_kernel(const u16* __restrict__ A,
                                                        const u16* __restrict__ B,
                                                        const u16* __restrict__ resid,
                                                        u16* __restrict__ xbout,
                                                        float* __restrict__ ssqPart,
                                                        int M, int N, int K) {
  __shared__ __align__(16) u16 As[2][64 * 64];    // 16 KiB
  __shared__ __align__(16) u16 Bs[2][128 * 64];   // 32 KiB
  const int tid = threadIdx.x;
  const int lane = tid & 63, wid = tid >> 6;
  const int wr = wid >> 1, wc = wid & 1;
  const int q = lane >> 4, l15 = lane & 15;
  const int nbm = M >> 6;                  // 64
  const int nbmx = nbm >> 3;               // 8 bm rows per XCD
  const int s2 = (int)blockIdx.x >> 3;
  const int bm = ((int)blockIdx.x & 7) * nbmx + (s2 % nbmx);
  const int bn = s2 / nbmx;
  const size_t abase = (size_t)bm * 64 * K;
  const size_t bbase = (size_t)bn * 128 * K;

  auto stage = [&](int t, int b) {
    const int k0 = t << 6;
#pragma unroll
    for (int i = 0; i < 2; i++) {
      int idx8 = i * 256 + tid;
      int row = idx8 >> 3, ch = idx8 & 7;
      int sc = (ch ^ (row & 7)) << 3;
      gload_lds16(A + abase + (size_t)row * K + k0 + sc, &As[b][idx8 * 8]);
    }
#pragma unroll
    for (int i = 0; i < 4; i++) {
      int idx8 = i * 256 + tid;
      int row = idx8 >> 3, ch = idx8 & 7;
      int sc = (ch ^ (row & 7)) << 3;
      gload_lds16(B + bbase + (size_t)row * K + k0 + sc, &Bs[b][idx8 * 8]);
    }
  };

  f32x4 acc[2][4] = {};
  const int NT = K >> 6;
  stage(0, 0);
  asm volatile("s_waitcnt vmcnt(0)" ::: "memory");
  __builtin_amdgcn_s_barrier();
  asm volatile("" ::: "memory");
  int buf = 0;
  for (int kt = 0; kt < NT; kt++) {
    if (kt + 1 < NT) stage(kt + 1, buf ^ 1);
    const u16* lA = &As[buf][0];
    const u16* lB = &Bs[buf][0];
#pragma unroll
    for (int ks = 0; ks < 2; ks++) {
      short8 af[2], bfr[4];
      int chunkc = ks * 4 + q;
#pragma unroll
      for (int mi = 0; mi < 2; mi++) {
        int row = wr * 32 + mi * 16 + l15;
        af[mi] = *(const short8*)&lA[row * 64 + ((chunkc ^ (row & 7)) << 3)];
      }
#pragma unroll
      for (int ni = 0; ni < 4; ni++) {
        int row = wc * 64 + ni * 16 + l15;
        bfr[ni] = *(const short8*)&lB[row * 64 + ((chunkc ^ (row & 7)) << 3)];
      }
#pragma unroll
      for (int mi = 0; mi < 2; mi++)
#pragma unroll
        for (int ni = 0; ni < 4; ni++)
          acc[mi][ni] = __builtin_amdgcn_mfma_f32_16x16x32_bf16(af[mi], bfr[ni], acc[mi][ni], 0, 0, 0);
    }
    asm volatile("s_waitcnt vmcnt(0)" ::: "memory");
    __builtin_amdgcn_s_barrier();
    asm volatile("" ::: "memory");
    buf ^= 1;
  }
  // epilogue: bf16 residual add + ssq partials
#pragma unroll
  for (int mi = 0; mi < 2; mi++)
#pragma unroll
    for (int j = 0; j < 4; j++) {
      int rr = bm * 64 + wr * 32 + mi * 16 + q * 4 + j;
      float ssq = 0.f;
#pragma unroll
      for (int ni = 0; ni < 4; ni++) {
        int cn = bn * 128 + wc * 64 + ni * 16 + l15;
        size_t off = (size_t)rr * N + cn;
        float nx = bf2f(resid[off]) + acc[mi][ni][j];
        xbout[off] = f2bf(nx);
        ssq += nx * nx;
      }
      ssq += __shfl_xor(ssq, 1, 64);
      ssq += __shfl_xor(ssq, 2, 64);
      ssq += __shfl_xor(ssq, 4, 64);
      ssq += __shfl_xor(ssq, 8, 64);
      if (l15 == 0) ssqPart[(size_t)rr * 16 + (bn << 1) + wc] = ssq;
    }
}

// ---------------- flash attention (dbuf K/V prefetch, exp2 domain, diag-only mask) --
// Scores pre-scaled by 0.125*log2e (folded into Q); softmax in exp2.
// K/V double-buffered (LDS 40 KiB; grid 512 = 2 blocks/CU): stage(kt+1) issued
// before compute(kt); vmcnt(0)+raw barrier per tile, covered by QK+softmax+PV.
// grid (16, 32): block i handles qt = i then 31-i -> uniform 33 K-tile units.
__global__ __launch_bounds__(256, 2) void attn_kernel(const u16* __restrict__ qkv,
                                                      const u16* __restrict__ vt,
                                                      u16* __restrict__ o) {
  __shared__ __align__(16) u16 Ks[2][64 * 64];
  __shared__ __align__(16) u16 Vt[2][64 * 64];
  __shared__ u16 Ps[4][16 * 64];
  const u16* q = qkv;
  const u16* k = qkv + D_MODEL;
  const int tid = threadIdx.x, lane = tid & 63, wid = tid >> 6;
  const int qg = lane >> 4, l15 = lane & 15;
  const int bh = blockIdx.y;
  const int b = bh >> 4, h = bh & 15;
  const int tok0 = b * TSEQ;
  const int hoff = h * HDIM;
  const u16* vtb = vt + (size_t)bh * 64 * TSEQ;

  auto stage = [&](int kv0, int bf) {
#pragma unroll
    for (int it = 0; it < 2; it++) {
      int idx = it * 256 + tid;
      int row = idx >> 3, ch = idx & 7;
      int sc = (ch ^ (row & 7)) << 3;
      gload_lds16(k + (size_t)(tok0 + kv0 + row) * QKV_STRIDE + hoff + sc, &Ks[bf][idx * 8]);
      gload_lds16(vtb + (size_t)row * TSEQ + kv0 + sc, &Vt[bf][idx * 8]);
    }
  };

  for (int half = 0; half < 2; half++) {
    const int qt = half == 0 ? (int)blockIdx.x : 31 - (int)blockIdx.x;
    const int qrow0 = qt * 64 + wid * 16;

    short8 aq[2];
#pragma unroll
    for (int ks = 0; ks < 2; ks++) {
      int r = qrow0 + l15;
      int d = ks * 32 + qg * 8;
      aq[ks] = *(const short8*)(q + (size_t)(tok0 + r) * QKV_STRIDE + hoff + d);
    }
    f32x4 oacc[4] = {};
    float mrow[4], lrow[4];
#pragma unroll
    for (int j = 0; j < 4; j++) { mrow[j] = -1e30f; lrow[j] = 0.f; }

    const int nkt = qt + 1;
    stage(0, 0);
    asm volatile("s_waitcnt vmcnt(0)" ::: "memory");
    __builtin_amdgcn_s_barrier();
    asm volatile("" ::: "memory");
    int buf = 0;
    for (int kt = 0; kt < nkt; kt++) {
      const int kv0 = kt * 64;
      if (kt + 1 < nkt) stage(kv0 + 64, buf ^ 1);
      const u16* KsB = &Ks[buf][0];
      const u16* VtB = &Vt[buf][0];
      f32x4 sc[4] = {};
#pragma unroll
      for (int ks = 0; ks < 2; ks++) {
        short8 bk[4];
        int kcol = ks * 32 + qg * 8;
#pragma unroll
        for (int ni = 0; ni < 4; ni++) {
          int r = ni * 16 + l15;
          bk[ni] = *(const short8*)&KsB[r * 64 + (kcol ^ ((r & 7) << 3))];
        }
#pragma unroll
        for (int ni = 0; ni < 4; ni++)
          sc[ni] = __builtin_amdgcn_mfma_f32_16x16x32_bf16(aq[ks], bk[ni], sc[ni], 0, 0, 0);
      }
      float pm[4];
#pragma unroll
      for (int j = 0; j < 4; j++) pm[j] = -1e30f;
      if (kt == qt) {
#pragma unroll
        for (int ni = 0; ni < 4; ni++)
#pragma unroll
          for (int j = 0; j < 4; j++) {
            int rq = qrow0 + qg * 4 + j;
            int ck = kv0 + ni * 16 + l15;
            float s = sc[ni][j];
            if (ck > rq) s = -1e30f;
            sc[ni][j] = s;
            pm[j] = fmaxf(pm[j], s);
          }
      } else {
#pragma unroll
        for (int ni = 0; ni < 4; ni++)
#pragma unroll
          for (int j = 0; j < 4; j++) pm[j] = fmaxf(pm[j], sc[ni][j]);
      }
#pragma unroll
      for (int j = 0; j < 4; j++) {
        float t = pm[j];
        t = fmaxf(t, __shfl_xor(t, 1, 64));
        t = fmaxf(t, __shfl_xor(t, 2, 64));
        t = fmaxf(t, __shfl_xor(t, 4, 64));
        t = fmaxf(t, __shfl_xor(t, 8, 64));
        pm[j] = t;
      }
#pragma unroll
      for (int j = 0; j < 4; j++) {
        float mn = fmaxf(mrow[j], pm[j]);
        float fac = exp2f(mrow[j] - mn);
        lrow[j] *= fac;
#pragma unroll
        for (int df = 0; df < 4; df++) oacc[df][j] *= fac;
        mrow[j] = mn;
      }
      float psum[4] = {};
#pragma unroll
      for (int ni = 0; ni < 4; ni++)
#pragma unroll
        for (int j = 0; j < 4; j++) {
          float p = exp2f(sc[ni][j] - mrow[j]);
          psum[j] += p;
          int r16 = qg * 4 + j;
          int cc = ni * 16 + l15;
          Ps[wid][r16 * 64 + (cc ^ ((r16 & 7) << 3))] = f2bf(p);
        }
#pragma unroll
      for (int j = 0; j < 4; j++) {
        float t = psum[j];
        t += __shfl_xor(t, 1, 64);
        t += __shfl_xor(t, 2, 64);
        t += __shfl_xor(t, 4, 64);
        t += __shfl_xor(t, 8, 64);
        lrow[j] += t;
      }
#pragma unroll
      for (int kf = 0; kf < 2; kf++) {
        short8 pa, bv[4];
        int kcol = kf * 32 + qg * 8;
        {
          int r = l15;
          pa = *(const short8*)&Ps[wid][r * 64 + (kcol ^ ((r & 7) << 3))];
        }
#pragma unroll
        for (int df = 0; df < 4; df++) {
          int r = df * 16 + l15;
          bv[df] = *(const short8*)&VtB[r * 64 + (kcol ^ ((r & 7) << 3))];
        }
#pragma unroll
        for (int df = 0; df < 4; df++)
          oacc[df] = __builtin_amdgcn_mfma_f32_16x16x32_bf16(pa, bv[df], oacc[df], 0, 0, 0);
      }
      asm volatile("s_waitcnt vmcnt(0)" ::: "memory");
      __builtin_amdgcn_s_barrier();
      asm volatile("" ::: "memory");
      buf ^= 1;
    }
#pragma unroll
    for (int df = 0; df < 4; df++)
#pragma unroll
      for (int j = 0; j < 4; j++) {
        int r = qrow0 + qg * 4 + j;
        int d = df * 16 + l15;
        float val = oacc[df][j] / lrow[j];
        o[(size_t)(tok0 + r) * D_MODEL + hoff + d] = f2bf(val);
      }
  }
}

// ---------------- loss ----------------

__global__ void nll_finalize_kernel(const float* __restrict__ partM, const float* __restrict__ partS,
                                    const float* __restrict__ logits, const int* __restrict__ targets,
                                    float* __restrict__ nll) {
  int tok = blockIdx.x;
  int lane = threadIdx.x;    // 64
  const int NTL = V_SIZE >> 6;  // 500
  float m = -1e30f, s = 0.f;
  for (int i = lane; i < NTL; i += 64) {
    float m2 = partM[(size_t)tok * NTL + i];
    float s2 = partS[(size_t)tok * NTL + i];
    float nm = fmaxf(m, m2);
    s = s * expf(m - nm) + s2 * expf(m2 - nm);
    m = nm;
  }
#pragma unroll
  for (int mask = 1; mask < 64; mask <<= 1) {
    float m2 = __shfl_xor(m, mask, 64);
    float s2 = __shfl_xor(s, mask, 64);
    float nm = fmaxf(m, m2);
    s = s * expf(m - nm) + s2 * expf(m2 - nm);
    m = nm;
  }
  if (lane == 0)
    nll[tok] = m + logf(s) - logits[(size_t)tok * V_SIZE + targets[tok]];
}

__global__ void loss_reduce_kernel(const float* __restrict__ nll, float* __restrict__ out) {
  float s = 0.f;
  for (int i = threadIdx.x; i < BT; i += 256) s += nll[i];
#pragma unroll
  for (int mask = 1; mask < 64; mask <<= 1) s += __shfl_xor(s, mask, 64);
  __shared__ float sm[4];
  if ((threadIdx.x & 63) == 0) sm[threadIdx.x >> 6] = s;
  __syncthreads();
  if (threadIdx.x == 0) out[0] = (sm[0] + sm[1] + sm[2] + sm[3]) / (float)BT;
}

// ---------------- host launcher ----------------

extern "C" void kernel_launch(void* const* d_in, const int* in_sizes, int n_in,
                              void* d_out, int out_size, void* d_ws, size_t ws_size,
                              hipStream_t stream) {
  const int* idx = (const int*)d_in[0];
  const int* targets = (const int*)d_in[1];
  const float* embed = (const float*)d_in[2];
  const float* wq = (const float*)d_in[3];
  const float* wk = (const float*)d_in[4];
  const float* wv = (const float*)d_in[5];
  const float* wo = (const float*)d_in[6];
  const float* w_gate = (const float*)d_in[7];
  const float* w_up = (const float*)d_in[8];
  const float* w_down = (const float*)d_in[9];
  const float* attn_norm = (const float*)d_in[10];
  const float* mlp_norm = (const float*)d_in[11];
  const float* final_norm = (const float*)d_in[12];
  const float* lm_head = (const float*)d_in[13];
  float* out = (float*)d_out;

  char* ws = (char*)d_ws;
  size_t off = 0;
  auto alloc = [&](size_t bytes) {
    void* p = ws + off;
    off += (bytes + 255) & ~(size_t)255;
    return p;
  };
  const size_t DD = (size_t)D_MODEL * D_MODEL;
  float* rope_cos = (float*)alloc((size_t)TSEQ * 32 * 4);
  float* rope_sin = (float*)alloc((size_t)TSEQ * 32 * 4);
  u16* Xb = (u16*)alloc((size_t)BT * D_MODEL * 2);
  u16* XbF = (u16*)alloc((size_t)BT * D_MODEL * 2);
  float* Rinv = (float*)alloc((size_t)BT * 4);
  float* SsqP = (float*)alloc((size_t)BT * 16 * 4);
  u16* QKVb = (u16*)alloc((size_t)BT * QKV_STRIDE * 2);
  u16* Vtb = (u16*)alloc((size_t)32 * 64 * TSEQ * 2);
  u16* Ob = (u16*)alloc((size_t)BT * D_MODEL * 2);
  u16* Gb = (u16*)alloc((size_t)BT * HFF * 2);
  u16* WQKVT = (u16*)alloc((size_t)NLAYER * QKV_STRIDE * D_MODEL * 2);
  u16* WOT = (u16*)alloc((size_t)NLAYER * DD * 2);
  u16* WGU = (u16*)alloc((size_t)NLAYER * GU_STRIDE * D_MODEL * 2);
  u16* WDT = (u16*)alloc((size_t)NLAYER * D_MODEL * HFF * 2);
  u16* LMH = (u16*)alloc((size_t)V_SIZE * D_MODEL * 2);
  float* NLLb = (float*)alloc((size_t)BT * 4);
  float* PartM = (float*)alloc((size_t)BT * (V_SIZE >> 6) * 4);
  float* PartS = (float*)alloc((size_t)BT * (V_SIZE >> 6) * 4);

  rope_table_kernel<<<256, 256, 0, stream>>>(rope_cos, rope_sin);
  convert_bf16_kernel<<<4096, 256, 0, stream>>>(lm_head, LMH, final_norm, (long)V_SIZE * D_MODEL / 8);
  embed_gather_kernel<<<BT, 256, 0, stream>>>(idx, embed, Xb, Rinv);

  const long QKVW = (long)QKV_STRIDE * D_MODEL;
  const long GUW = (long)GU_STRIDE * D_MODEL;
  const long DW = (long)D_MODEL * HFF;
  transpose_bf16_kernel<<<dim3(32, 32, NLAYER), 256, 0, stream>>>(wq, WQKVT, D_MODEL, D_MODEL, DD, QKVW, 0, attn_norm, D_MODEL);
  transpose_bf16_kernel<<<dim3(32, 32, NLAYER), 256, 0, stream>>>(wk, WQKVT + DD, D_MODEL, D_MODEL, DD, QKVW, 0, attn_norm, D_MODEL);
  transpose_bf16_kernel<<<dim3(32, 32, NLAYER), 256, 0, stream>>>(wv, WQKVT + 2 * DD, D_MODEL, D_MODEL, DD, QKVW, 0, attn_norm, D_MODEL);
  transpose_bf16_kernel<<<dim3(32, 32, NLAYER), 256, 0, stream>>>(wo, WOT, D_MODEL, D_MODEL, DD, DD, 0, nullptr, 0);
  transpose_bf16_kernel<<<dim3(128, 32, NLAYER), 256, 0, stream>>>(w_gate, WGU, D_MODEL, HFF, DW, GUW, 1, mlp_norm, D_MODEL);
  transpose_bf16_kernel<<<dim3(128, 32, NLAYER), 256, 0, stream>>>(w_up, WGU, D_MODEL, HFF, DW, GUW, 2, mlp_norm, D_MODEL);
  transpose_bf16_kernel<<<dim3(32, 128, NLAYER), 256, 0, stream>>>(w_down, WDT, HFF, D_MODEL, DW, DW, 0, nullptr, 0);

  for (int l = 0; l < NLAYER; l++) {
    gemm128_kernel<4><<<(QKV_STRIDE / 128) * (BT / 128), 256, 0, stream>>>(
        Xb, WQKVT + (size_t)l * QKVW, QKVb, nullptr, nullptr, rope_cos, rope_sin,
        Rinv, BT, QKV_STRIDE, D_MODEL, QKV_STRIDE / 128);
    vtrans_kernel<<<dim3(32, 32), 256, 0, stream>>>(QKVb, Vtb);
    attn_kernel<<<dim3(16, 32), 256, 0, stream>>>(QKVb, Vtb, Ob);
    gemm64_kernel<<<(BT / 64) * (D_MODEL / 128), 256, 0, stream>>>(
        Ob, WOT + (size_t)l * DD, Xb, Xb, SsqP, BT, D_MODEL, D_MODEL);
    rinv_kernel<<<BT / 256, 256, 0, stream>>>(SsqP, Rinv);

    gemm128_kernel<5><<<(GU_STRIDE / 128) * (BT / 128), 256, 0, stream>>>(
        Xb, WGU + (size_t)l * GUW, Gb, nullptr, nullptr, nullptr, nullptr,
        Rinv, BT, GU_STRIDE, D_MODEL, 32);
    gemm64_kernel<<<(BT / 64) * (D_MODEL / 128), 256, 0, stream>>>(
        Gb, WDT + (size_t)l * DW, Xb, Xb, SsqP, BT, D_MODEL, HFF);
    rinv_kernel<<<BT / 256, 256, 0, stream>>>(SsqP, Rinv);
  }

  scale_xb_kernel<<<BT * D_MODEL / (256 * 8), 256, 0, stream>>>(Xb, Rinv, XbF);
  gemm128_kernel<0><<<(V_SIZE / 128) * (BT / 128), 256, 0, stream>>>(
      XbF, LMH, out, PartM, PartS, nullptr, nullptr,
      nullptr, BT, V_SIZE, D_MODEL, 50);
  nll_finalize_kernel<<<BT, 64, 0, stream>>>(PartM, PartS, out, targets, NLLb);
  loss_reduce_kernel<<<1, 256, 0, stream>>>(NLLb, out + (size_t)BT * V_SIZE);
}

// Round 18
// 1585.066 us; speedup vs baseline: 2.1409x; 1.0176x over previous
//
#include <hip/hip_runtime.h>

typedef __attribute__((ext_vector_type(8))) short short8;
typedef __attribute__((ext_vector_type(4))) float f32x4;
typedef __attribute__((ext_vector_type(8))) unsigned short u16x8;
typedef unsigned short u16;

#define V_SIZE 32000
#define D_MODEL 1024
#define HFF 4096
#define NHEAD 16
#define HDIM 64
#define NLAYER 4
#define BT 4096   // B*T tokens
#define TSEQ 2048
#define QKV_STRIDE 3072
#define GU_STRIDE 8192
#define QSCALE 0.18033688011112043f   // 0.125 * log2(e), folded into Q at EPI4

__device__ __forceinline__ u16 f2bf(float f) {
  union { float f; unsigned u; } v; v.f = f;
  unsigned r = v.u + 0x7fffu + ((v.u >> 16) & 1u);
  return (u16)(r >> 16);
}
__device__ __forceinline__ float bf2f(u16 h) {
  union { unsigned u; float f; } v; v.u = ((unsigned)h) << 16;
  return v.f;
}

__device__ __forceinline__ void gload_lds16(const void* g, void* l) {
  __builtin_amdgcn_global_load_lds((__attribute__((address_space(1))) void*)g,
                                   (__attribute__((address_space(3))) void*)l, 16, 0, 0);
}

// ---------------- elementwise / small kernels ----------------

__global__ void rope_table_kernel(float* __restrict__ cosb, float* __restrict__ sinb) {
  int i = blockIdx.x * 256 + threadIdx.x;       // 2048*32 = 65536 items
  int t = i >> 5, fi = i & 31;
  float freq = exp2f(-(2.0f * (float)fi / 64.0f) * log2f(10000.0f));
  float ang = (float)t * freq;
  cosb[i] = cosf(ang);
  sinb[i] = sinf(ang);
}

// lm_head fp32 -> bf16, scaled by final_norm[k]
__global__ void convert_bf16_kernel(const float* __restrict__ src, u16* __restrict__ dst,
                                    const float* __restrict__ fn, long n8) {
  long i = (long)blockIdx.x * 256 + threadIdx.x;
  long stride = (long)gridDim.x * 256;
  for (; i < n8; i += stride) {
    const float4* s = (const float4*)(src + i * 8);
    float4 a = s[0], b = s[1];
    int k0 = (int)((i * 8) & (D_MODEL - 1));
    u16x8 r;
    r[0] = f2bf(a.x * fn[k0 + 0]); r[1] = f2bf(a.y * fn[k0 + 1]);
    r[2] = f2bf(a.z * fn[k0 + 2]); r[3] = f2bf(a.w * fn[k0 + 3]);
    r[4] = f2bf(b.x * fn[k0 + 4]); r[5] = f2bf(b.y * fn[k0 + 5]);
    r[6] = f2bf(b.z * fn[k0 + 6]); r[7] = f2bf(b.w * fn[k0 + 7]);
    *(u16x8*)(dst + i * 8) = r;
  }
}

// src [R][C] fp32 -> dst bf16, scaled by nw[src row] if nw != null (norm fold).
// rowMode: 0 -> dst row = c
//          1 -> ((c>>4)<<5)|(c&15)        (gate cols, 16-col interleave)
//          2 -> ((c>>4)<<5)|16|(c&15)     (up cols, partner rows)
__global__ __launch_bounds__(256) void transpose_bf16_kernel(const float* __restrict__ src0,
                                                             u16* __restrict__ dst0, int R, int C,
                                                             long srcStride, long dstStride,
                                                             int rowMode,
                                                             const float* __restrict__ nw0,
                                                             int nwStride) {
  __shared__ float tile[32][33];
  const float* src = src0 + (size_t)blockIdx.z * srcStride;
  u16* dst = dst0 + (size_t)blockIdx.z * dstStride;
  const float* nw = nw0 ? nw0 + (size_t)blockIdx.z * nwStride : nullptr;
  int tx = threadIdx.x & 31, ty = threadIdx.x >> 5;  // 32 x 8
  int bx = blockIdx.x, by = blockIdx.y;
#pragma unroll
  for (int i = 0; i < 32; i += 8) {
    int r = by * 32 + ty + i, c = bx * 32 + tx;
    tile[ty + i][tx] = src[(size_t)r * C + c];
  }
  __syncthreads();
#pragma unroll
  for (int i = 0; i < 32; i += 8) {
    int c = bx * 32 + ty + i;   // source col
    int r = by * 32 + tx;       // source row (k index) -> dst col
    float val = tile[tx][ty + i];
    if (nw) val *= nw[r];
    int drow = c;
    if (rowMode == 1) drow = ((c >> 4) << 5) | (c & 15);
    else if (rowMode == 2) drow = ((c >> 4) << 5) | 16 | (c & 15);
    dst[(size_t)drow * R + r] = f2bf(val);
  }
}

// embed gather: writes Xb bf16 (residual stream) and rinv[t]. 1 block = 1 token.
__global__ __launch_bounds__(256) void embed_gather_kernel(const int* __restrict__ idx,
                                                           const float* __restrict__ embed,
                                                           u16* __restrict__ xb,
                                                           float* __restrict__ rinv) {
  int t = blockIdx.x;
  int id = idx[t];
  float4 v = ((const float4*)embed)[(size_t)id * 256 + threadIdx.x];
  u16* hp = xb + (size_t)t * D_MODEL + threadIdx.x * 4;
  hp[0] = f2bf(v.x); hp[1] = f2bf(v.y); hp[2] = f2bf(v.z); hp[3] = f2bf(v.w);
  float ss = v.x * v.x + v.y * v.y + v.z * v.z + v.w * v.w;
#pragma unroll
  for (int m = 32; m > 0; m >>= 1) ss += __shfl_xor(ss, m, 64);
  __shared__ float wsum[4];
  if ((threadIdx.x & 63) == 0) wsum[threadIdx.x >> 6] = ss;
  __syncthreads();
  if (threadIdx.x == 0) {
    float tot = wsum[0] + wsum[1] + wsum[2] + wsum[3];
    rinv[t] = rsqrtf(tot * (1.0f / (float)D_MODEL) + 1e-6f);
  }
}

// reduce 16 ssq partials per row -> rinv
__global__ void rinv_kernel(const float* __restrict__ ssqPart, float* __restrict__ rinv) {
  int r = blockIdx.x * 256 + threadIdx.x;   // BT rows
  float s = 0.f;
#pragma unroll
  for (int i = 0; i < 16; i++) s += ssqPart[(size_t)r * 16 + i];
  rinv[r] = rsqrtf(s * (1.0f / (float)D_MODEL) + 1e-6f);
}

// XbF = Xb * rinv[row] (bf16, vectorized)
__global__ void scale_xb_kernel(const u16* __restrict__ xb, const float* __restrict__ rinv,
                                u16* __restrict__ xbf) {
  long i = (long)blockIdx.x * 256 + threadIdx.x;   // item = 8 elems
  int row = (int)(i >> 7);
  float ri = rinv[row];
  short8 v = *(const short8*)(xb + i * 8);
  u16x8 r;
#pragma unroll
  for (int j = 0; j < 8; j++) r[j] = f2bf(bf2f((u16)v[j]) * ri);
  *(u16x8*)(xbf + i * 8) = r;
}

// V (in QKV buffer) -> Vt [bh][64 d][TSEQ t] bf16, tile-transposed via LDS.
__global__ __launch_bounds__(256) void vtrans_kernel(const u16* __restrict__ qkv,
                                                     u16* __restrict__ vt) {
  __shared__ u16 lds[64 * 64];
  const int tid = threadIdx.x;
  const int bh = blockIdx.y, tt = blockIdx.x;
  const int b = bh >> 4, h = bh & 15;
  const int tok0 = b * TSEQ + tt * 64;
  const int hoff = 2 * D_MODEL + h * HDIM;
#pragma unroll
  for (int it = 0; it < 2; it++) {
    int idx = it * 256 + tid;
    int row = idx >> 3, c = (idx & 7) * 8;
    short8 v = *(const short8*)(qkv + (size_t)(tok0 + row) * QKV_STRIDE + hoff + c);
    *(short8*)&lds[row * 64 + (c ^ ((row & 7) << 3))] = v;
  }
  __syncthreads();
#pragma unroll
  for (int it = 0; it < 2; it++) {
    int idx = it * 256 + tid;
    int d = idx >> 3, t0 = (idx & 7) * 8;
    u16x8 pk;
#pragma unroll
    for (int j = 0; j < 8; j++) {
      int t = t0 + j;
      pk[j] = lds[t * 64 + (((d & ~7) ^ ((t & 7) << 3)) | (d & 7))];
    }
    *(u16x8*)(vt + ((size_t)bh * 64 + d) * TSEQ + tt * 64 + t0) = pk;
  }
}

// ---------------- GEMM 128x128 (m97 structure, both-sides swizzle, 4 blocks/CU) ----
// EPI: 0 = lm-head (A pre-normed): fp32 nontemporal store + LSE partials
//      4 = QKV: vv *= rinv (Q cols additionally *= QSCALE), fused RoPE, bf16 store
//      5 = GU fused silu-mul, PAIRWISE (B rows 16-col-interleaved gate/up: lane holds
//          the (g,u) pair in acc[ni]/acc[ni+1] -> no LDS exchange); N/2-wide store
template <int EPI>
__global__ __launch_bounds__(256, 4) void gemm128_kernel(const u16* __restrict__ A,
                                                         const u16* __restrict__ B, void* Cp,
                                                         float* __restrict__ partM,
                                                         float* __restrict__ partS,
                                                         const float* __restrict__ cosb,
                                                         const float* __restrict__ sinb,
                                                         const float* __restrict__ rinv,
                                                         int M, int N, int K, int chunkBn) {
  __shared__ __align__(16) u16 As[128 * 64];
  __shared__ __align__(16) u16 Bs[128 * 64];
  const int tid = threadIdx.x;
  const int lane = tid & 63, wid = tid >> 6;
  const int wr = wid >> 1, wc = wid & 1;
  const int q = lane >> 4, l15 = lane & 15;
  const int nbm = M >> 7;
  const int nbmx = nbm >> 3;               // bm rows per XCD
  const int cs = nbm * chunkBn;            // blocks per chunk
  const int chunk = (int)blockIdx.x / cs;
  const int r0 = (int)blockIdx.x - chunk * cs;
  const int s2 = r0 >> 3;
  const int bm = (r0 & 7) * nbmx + (s2 % nbmx);
  const int bn = chunk * chunkBn + (s2 / nbmx);
  const size_t abase = (size_t)bm * 128 * K;
  const size_t bbase = (size_t)bn * 128 * K;
  f32x4 acc[4][4] = {};
  for (int k0 = 0; k0 < K; k0 += 64) {
#pragma unroll
    for (int i = 0; i < 4; i++) {
      int idx8 = i * 256 + tid;
      int row = idx8 >> 3, ch = idx8 & 7;
      int sc = (ch ^ (row & 7)) << 3;
      gload_lds16(A + abase + (size_t)row * K + k0 + sc, As + idx8 * 8);
      gload_lds16(B + bbase + (size_t)row * K + k0 + sc, Bs + idx8 * 8);
    }
    __syncthreads();
#pragma unroll
    for (int ks = 0; ks < 2; ks++) {
      short8 af[4], bfr[4];
      int chunkc = ks * 4 + q;
#pragma unroll
      for (int mi = 0; mi < 4; mi++) {
        int row = wr * 64 + mi * 16 + l15;
        af[mi] = *(const short8*)&As[row * 64 + ((chunkc ^ (row & 7)) << 3)];
      }
#pragma unroll
      for (int ni = 0; ni < 4; ni++) {
        int row = wc * 64 + ni * 16 + l15;
        bfr[ni] = *(const short8*)&Bs[row * 64 + ((chunkc ^ (row & 7)) << 3)];
      }
#pragma unroll
      for (int mi = 0; mi < 4; mi++)
#pragma unroll
        for (int ni = 0; ni < 4; ni++)
          acc[mi][ni] = __builtin_amdgcn_mfma_f32_16x16x32_bf16(af[mi], bfr[ni], acc[mi][ni], 0, 0, 0);
    }
    __syncthreads();
  }

  // ---- EPI 5: pairwise silu-mul (g at ni even, u at ni odd, same lane) ----
  if (EPI == 5) {
#pragma unroll
    for (int mi = 0; mi < 4; mi++)
#pragma unroll
      for (int j = 0; j < 4; j++) {
        int rr = bm * 128 + wr * 64 + mi * 16 + q * 4 + j;
        float ri = rinv[rr];
#pragma unroll
        for (int pr = 0; pr < 2; pr++) {
          float g = acc[mi][pr * 2][j] * ri;
          float u = acc[mi][pr * 2 + 1][j] * ri;
          float rsl = g / (1.0f + __expf(-g)) * u;
          int cn = (bn * 4 + wc * 2 + pr) * 16 + l15;
          ((u16*)Cp)[(size_t)rr * (N >> 1) + cn] = f2bf(rsl);
        }
      }
    return;
  }

  // ---- EPI 0 / 4 ----
#pragma unroll
  for (int mi = 0; mi < 4; mi++)
#pragma unroll
    for (int j = 0; j < 4; j++) {
      int rr = bm * 128 + wr * 64 + mi * 16 + q * 4 + j;
      float vv[4];
      if (EPI == 4) {
        float ri = rinv[rr];
        if (((bn << 1) + wc) < 16) ri *= QSCALE;   // Q cols: fold softmax scale + log2e
#pragma unroll
        for (int ni = 0; ni < 4; ni++) vv[ni] = acc[mi][ni][j] * ri;
      } else {
#pragma unroll
        for (int ni = 0; ni < 4; ni++) vv[ni] = acc[mi][ni][j];
      }
      if (EPI == 0) {
        float mx = fmaxf(fmaxf(vv[0], vv[1]), fmaxf(vv[2], vv[3]));
        mx = fmaxf(mx, __shfl_xor(mx, 1, 64));
        mx = fmaxf(mx, __shfl_xor(mx, 2, 64));
        mx = fmaxf(mx, __shfl_xor(mx, 4, 64));
        mx = fmaxf(mx, __shfl_xor(mx, 8, 64));
        float sm = 0.f;
#pragma unroll
        for (int ni = 0; ni < 4; ni++) sm += __expf(vv[ni] - mx);
        sm += __shfl_xor(sm, 1, 64);
        sm += __shfl_xor(sm, 2, 64);
        sm += __shfl_xor(sm, 4, 64);
        sm += __shfl_xor(sm, 8, 64);
        if (l15 == 0) {
          int nt = (N >> 6);
          partM[(size_t)rr * nt + (bn << 1) + wc] = mx;
          partS[(size_t)rr * nt + (bn << 1) + wc] = sm;
        }
      }
      if (EPI == 4) {
        if (((bn << 1) + wc) < 32) {   // Q or K cols: wave-uniform RoPE
          int t = rr & (TSEQ - 1);
#pragma unroll
          for (int ni = 0; ni < 2; ni++) {
            int fi = ni * 16 + l15;
            float c = cosb[t * 32 + fi], s = sinb[t * 32 + fi];
            float x1 = vv[ni], x2 = vv[ni + 2];
            vv[ni] = x1 * c - x2 * s;
            vv[ni + 2] = x2 * c + x1 * s;
          }
        }
      }
#pragma unroll
      for (int ni = 0; ni < 4; ni++) {
        int cn = bn * 128 + wc * 64 + ni * 16 + l15;
        size_t off = (size_t)rr * N + cn;
        if (EPI == 0) __builtin_nontemporal_store(vv[ni], (float*)Cp + off);
        else ((u16*)Cp)[off] = f2bf(vv[ni]);
      }
    }
}

// ---------------- GEMM 64x128 for N=1024 projections (o-proj / down-proj) ----------
// Double-buffered LDS (48 KiB; grid 512 = 2 blocks/CU, grid-limited): stage(kt+1)
// issued BEFORE compute(kt); vmcnt(0)+raw-barrier per K-tile.
// EPI: bf16 residual add (resid == xbout, in-place per-element) + ssq partials.
__global__ __launch_bounds__(256, 2) void gemm64_kernel(const u16* __restrict__ A,
                                                        const u16* __restrict__ B,
                                                        const u16* __restrict__ resid,
                                                        u16* __restrict__ xbout,
                                                        float* __restrict__ ssqPart,
                                                        int M, int N, int K) {
  __shared__ __align__(16) u16 As[2][64 * 64];    // 16 KiB
  __shared__ __align__(16) u16 Bs[2][128 * 64];   // 32 KiB
  const int tid = threadIdx.x;
  const int lane = tid & 63, wid = tid >> 6;
  const int wr = wid >> 1, wc = wid & 1;
  const int q = lane >> 4, l15 = lane & 15;
  const int nbm = M >> 6;                  // 64
  const int nbmx = nbm >> 3;               // 8 bm rows per XCD
  const int s2 = (int)blockIdx.x >> 3;
  const int bm = ((int)blockIdx.x & 7) * nbmx + (s2 % nbmx);
  const int bn = s2 / nbmx;
  const size_t abase = (size_t)bm * 64 * K;
  const size_t bbase = (size_t)bn * 128 * K;

  auto stage = [&](int t, int b) {
    const int k0 = t << 6;
#pragma unroll
    for (int i = 0; i < 2; i++) {
      int idx8 = i * 256 + tid;
      int row = idx8 >> 3, ch = idx8 & 7;
      int sc = (ch ^ (row & 7)) << 3;
      gload_lds16(A + abase + (size_t)row * K + k0 + sc, &As[b][idx8 * 8]);
    }
#pragma unroll
    for (int i = 0; i < 4; i++) {
      int idx8 = i * 256 + tid;
      int row = idx8 >> 3, ch = idx8 & 7;
      int sc = (ch ^ (row & 7)) << 3;
      gload_lds16(B + bbase + (size_t)row * K + k0 + sc, &Bs[b][idx8 * 8]);
    }
  };

  f32x4 acc[2][4] = {};
  const int NT = K >> 6;
  stage(0, 0);
  asm volatile("s_waitcnt vmcnt(0)" ::: "memory");
  __builtin_amdgcn_s_barrier();
  asm volatile("" ::: "memory");
  int buf = 0;
  for (int kt = 0; kt < NT; kt++) {
    if (kt + 1 < NT) stage(kt + 1, buf ^ 1);
    const u16* lA = &As[buf][0];
    const u16* lB = &Bs[buf][0];
#pragma unroll
    for (int ks = 0; ks < 2; ks++) {
      short8 af[2], bfr[4];
      int chunkc = ks * 4 + q;
#pragma unroll
      for (int mi = 0; mi < 2; mi++) {
        int row = wr * 32 + mi * 16 + l15;
        af[mi] = *(const short8*)&lA[row * 64 + ((chunkc ^ (row & 7)) << 3)];
      }
#pragma unroll
      for (int ni = 0; ni < 4; ni++) {
        int row = wc * 64 + ni * 16 + l15;
        bfr[ni] = *(const short8*)&lB[row * 64 + ((chunkc ^ (row & 7)) << 3)];
      }
#pragma unroll
      for (int mi = 0; mi < 2; mi++)
#pragma unroll
        for (int ni = 0; ni < 4; ni++)
          acc[mi][ni] = __builtin_amdgcn_mfma_f32_16x16x32_bf16(af[mi], bfr[ni], acc[mi][ni], 0, 0, 0);
    }
    asm volatile("s_waitcnt vmcnt(0)" ::: "memory");
    __builtin_amdgcn_s_barrier();
    asm volatile("" ::: "memory");
    buf ^= 1;
  }
  // epilogue: bf16 residual add + ssq partials
#pragma unroll
  for (int mi = 0; mi < 2; mi++)
#pragma unroll
    for (int j = 0; j < 4; j++) {
      int rr = bm * 64 + wr * 32 + mi * 16 + q * 4 + j;
      float ssq = 0.f;
#pragma unroll
      for (int ni = 0; ni < 4; ni++) {
        int cn = bn * 128 + wc * 64 + ni * 16 + l15;
        size_t off = (size_t)rr * N + cn;
        float nx = bf2f(resid[off]) + acc[mi][ni][j];
        xbout[off] = f2bf(nx);
        ssq += nx * nx;
      }
      ssq += __shfl_xor(ssq, 1, 64);
      ssq += __shfl_xor(ssq, 2, 64);
      ssq += __shfl_xor(ssq, 4, 64);
      ssq += __shfl_xor(ssq, 8, 64);
      if (l15 == 0) ssqPart[(size_t)rr * 16 + (bn << 1) + wc] = ssq;
    }
}

// ---------------- flash attention (dbuf + cross-half prefetch, exp2 domain) --------
// Scores pre-scaled by 0.125*log2e (folded into Q); softmax in exp2; causal mask
// applied only on the diagonal K-tile. K/V double-buffered; the NEXT q-tile-half's
// tile-0 stage is issued during the current half's last tile, so its latency hides
// under the last PV + the O-write epilogue (no cold prologue for half 1).
// grid (16, 32): block i handles qt = i then 31-i -> uniform 33 K-tile units.
__global__ __launch_bounds__(256, 2) void attn_kernel(const u16* __restrict__ qkv,
                                                      const u16* __restrict__ vt,
                                                      u16* __restrict__ o) {
  __shared__ __align__(16) u16 Ks[2][64 * 64];
  __shared__ __align__(16) u16 Vt[2][64 * 64];
  __shared__ u16 Ps[4][16 * 64];
  const u16* q = qkv;
  const u16* k = qkv + D_MODEL;
  const int tid = threadIdx.x, lane = tid & 63, wid = tid >> 6;
  const int qg = lane >> 4, l15 = lane & 15;
  const int bh = blockIdx.y;
  const int b = bh >> 4, h = bh & 15;
  const int tok0 = b * TSEQ;
  const int hoff = h * HDIM;
  const u16* vtb = vt + (size_t)bh * 64 * TSEQ;

  auto stage = [&](int kv0, int bf) {
#pragma unroll
    for (int it = 0; it < 2; it++) {
      int idx = it * 256 + tid;
      int row = idx >> 3, ch = idx & 7;
      int sc = (ch ^ (row & 7)) << 3;
      gload_lds16(k + (size_t)(tok0 + kv0 + row) * QKV_STRIDE + hoff + sc, &Ks[bf][idx * 8]);
      gload_lds16(vtb + (size_t)row * TSEQ + kv0 + sc, &Vt[bf][idx * 8]);
    }
  };

  int buf = 0;
  for (int half = 0; half < 2; half++) {
    const int qt = half == 0 ? (int)blockIdx.x : 31 - (int)blockIdx.x;
    const int qrow0 = qt * 64 + wid * 16;

    short8 aq[2];
#pragma unroll
    for (int ks = 0; ks < 2; ks++) {
      int r = qrow0 + l15;
      int d = ks * 32 + qg * 8;
      aq[ks] = *(const short8*)(q + (size_t)(tok0 + r) * QKV_STRIDE + hoff + d);
    }
    f32x4 oacc[4] = {};
    float mrow[4], lrow[4];
#pragma unroll
    for (int j = 0; j < 4; j++) { mrow[j] = -1e30f; lrow[j] = 0.f; }

    const int nkt = qt + 1;
    if (half == 0) {   // cold prologue only once; half 1's tile 0 is prefetched
      stage(0, buf);
      asm volatile("s_waitcnt vmcnt(0)" ::: "memory");
      __builtin_amdgcn_s_barrier();
      asm volatile("" ::: "memory");
    }
    for (int kt = 0; kt < nkt; kt++) {
      const int kv0 = kt * 64;
      if (kt + 1 < nkt) stage(kv0 + 64, buf ^ 1);
      else if (half == 0) stage(0, buf ^ 1);   // cross-half prefetch of next tile-0
      const u16* KsB = &Ks[buf][0];
      const u16* VtB = &Vt[buf][0];
      f32x4 sc[4] = {};
#pragma unroll
      for (int ks = 0; ks < 2; ks++) {
        short8 bk[4];
        int kcol = ks * 32 + qg * 8;
#pragma unroll
        for (int ni = 0; ni < 4; ni++) {
          int r = ni * 16 + l15;
          bk[ni] = *(const short8*)&KsB[r * 64 + (kcol ^ ((r & 7) << 3))];
        }
#pragma unroll
        for (int ni = 0; ni < 4; ni++)
          sc[ni] = __builtin_amdgcn_mfma_f32_16x16x32_bf16(aq[ks], bk[ni], sc[ni], 0, 0, 0);
      }
      float pm[4];
#pragma unroll
      for (int j = 0; j < 4; j++) pm[j] = -1e30f;
      if (kt == qt) {
#pragma unroll
        for (int ni = 0; ni < 4; ni++)
#pragma unroll
          for (int j = 0; j < 4; j++) {
            int rq = qrow0 + qg * 4 + j;
            int ck = kv0 + ni * 16 + l15;
            float s = sc[ni][j];
            if (ck > rq) s = -1e30f;
            sc[ni][j] = s;
            pm[j] = fmaxf(pm[j], s);
          }
      } else {
#pragma unroll
        for (int ni = 0; ni < 4; ni++)
#pragma unroll
          for (int j = 0; j < 4; j++) pm[j] = fmaxf(pm[j], sc[ni][j]);
      }
#pragma unroll
      for (int j = 0; j < 4; j++) {
        float t = pm[j];
        t = fmaxf(t, __shfl_xor(t, 1, 64));
        t = fmaxf(t, __shfl_xor(t, 2, 64));
        t = fmaxf(t, __shfl_xor(t, 4, 64));
        t = fmaxf(t, __shfl_xor(t, 8, 64));
        pm[j] = t;
      }
#pragma unroll
      for (int j = 0; j < 4; j++) {
        float mn = fmaxf(mrow[j], pm[j]);
        float fac = exp2f(mrow[j] - mn);
        lrow[j] *= fac;
#pragma unroll
        for (int df = 0; df < 4; df++) oacc[df][j] *= fac;
        mrow[j] = mn;
      }
      float psum[4] = {};
#pragma unroll
      for (int ni = 0; ni < 4; ni++)
#pragma unroll
        for (int j = 0; j < 4; j++) {
          float p = exp2f(sc[ni][j] - mrow[j]);
          psum[j] += p;
          int r16 = qg * 4 + j;
          int cc = ni * 16 + l15;
          Ps[wid][r16 * 64 + (cc ^ ((r16 & 7) << 3))] = f2bf(p);
        }
#pragma unroll
      for (int j = 0; j < 4; j++) {
        float t = psum[j];
        t += __shfl_xor(t, 1, 64);
        t += __shfl_xor(t, 2, 64);
        t += __shfl_xor(t, 4, 64);
        t += __shfl_xor(t, 8, 64);
        lrow[j] += t;
      }
#pragma unroll
      for (int kf = 0; kf < 2; kf++) {
        short8 pa, bv[4];
        int kcol = kf * 32 + qg * 8;
        {
          int r = l15;
          pa = *(const short8*)&Ps[wid][r * 64 + (kcol ^ ((r & 7) << 3))];
        }
#pragma unroll
        for (int df = 0; df < 4; df++) {
          int r = df * 16 + l15;
          bv[df] = *(const short8*)&VtB[r * 64 + (kcol ^ ((r & 7) << 3))];
        }
#pragma unroll
        for (int df = 0; df < 4; df++)
          oacc[df] = __builtin_amdgcn_mfma_f32_16x16x32_bf16(pa, bv[df], oacc[df], 0, 0, 0);
      }
      asm volatile("s_waitcnt vmcnt(0)" ::: "memory");
      __builtin_amdgcn_s_barrier();
      asm volatile("" ::: "memory");
      buf ^= 1;
    }
#pragma unroll
    for (int df = 0; df < 4; df++)
#pragma unroll
      for (int j = 0; j < 4; j++) {
        int r = qrow0 + qg * 4 + j;
        int d = df * 16 + l15;
        float val = oacc[df][j] / lrow[j];
        o[(size_t)(tok0 + r) * D_MODEL + hoff + d] = f2bf(val);
      }
  }
}

// ---------------- loss ----------------

__global__ void nll_finalize_kernel(const float* __restrict__ partM, const float* __restrict__ partS,
                                    const float* __restrict__ logits, const int* __restrict__ targets,
                                    float* __restrict__ nll) {
  int tok = blockIdx.x;
  int lane = threadIdx.x;    // 64
  const int NTL = V_SIZE >> 6;  // 500
  float m = -1e30f, s = 0.f;
  for (int i = lane; i < NTL; i += 64) {
    float m2 = partM[(size_t)tok * NTL + i];
    float s2 = partS[(size_t)tok * NTL + i];
    float nm = fmaxf(m, m2);
    s = s * __expf(m - nm) + s2 * __expf(m2 - nm);
    m = nm;
  }
#pragma unroll
  for (int mask = 1; mask < 64; mask <<= 1) {
    float m2 = __shfl_xor(m, mask, 64);
    float s2 = __shfl_xor(s, mask, 64);
    float nm = fmaxf(m, m2);
    s = s * __expf(m - nm) + s2 * __expf(m2 - nm);
    m = nm;
  }
  if (lane == 0)
    nll[tok] = m + logf(s) - logits[(size_t)tok * V_SIZE + targets[tok]];
}

__global__ void loss_reduce_kernel(const float* __restrict__ nll, float* __restrict__ out) {
  float s = 0.f;
  for (int i = threadIdx.x; i < BT; i += 256) s += nll[i];
#pragma unroll
  for (int mask = 1; mask < 64; mask <<= 1) s += __shfl_xor(s, mask, 64);
  __shared__ float sm[4];
  if ((threadIdx.x & 63) == 0) sm[threadIdx.x >> 6] = s;
  __syncthreads();
  if (threadIdx.x == 0) out[0] = (sm[0] + sm[1] + sm[2] + sm[3]) / (float)BT;
}

// ---------------- host launcher ----------------

extern "C" void kernel_launch(void* const* d_in, const int* in_sizes, int n_in,
                              void* d_out, int out_size, void* d_ws, size_t ws_size,
                              hipStream_t stream) {
  const int* idx = (const int*)d_in[0];
  const int* targets = (const int*)d_in[1];
  const float* embed = (const float*)d_in[2];
  const float* wq = (const float*)d_in[3];
  const float* wk = (const float*)d_in[4];
  const float* wv = (const float*)d_in[5];
  const float* wo = (const float*)d_in[6];
  const float* w_gate = (const float*)d_in[7];
  const float* w_up = (const float*)d_in[8];
  const float* w_down = (const float*)d_in[9];
  const float* attn_norm = (const float*)d_in[10];
  const float* mlp_norm = (const float*)d_in[11];
  const float* final_norm = (const float*)d_in[12];
  const float* lm_head = (const float*)d_in[13];
  float* out = (float*)d_out;

  char* ws = (char*)d_ws;
  size_t off = 0;
  auto alloc = [&](size_t bytes) {
    void* p = ws + off;
    off += (bytes + 255) & ~(size_t)255;
    return p;
  };
  const size_t DD = (size_t)D_MODEL * D_MODEL;
  float* rope_cos = (float*)alloc((size_t)TSEQ * 32 * 4);
  float* rope_sin = (float*)alloc((size_t)TSEQ * 32 * 4);
  u16* Xb = (u16*)alloc((size_t)BT * D_MODEL * 2);
  u16* XbF = (u16*)alloc((size_t)BT * D_MODEL * 2);
  float* Rinv = (float*)alloc((size_t)BT * 4);
  float* SsqP = (float*)alloc((size_t)BT * 16 * 4);
  u16* QKVb = (u16*)alloc((size_t)BT * QKV_STRIDE * 2);
  u16* Vtb = (u16*)alloc((size_t)32 * 64 * TSEQ * 2);
  u16* Ob = (u16*)alloc((size_t)BT * D_MODEL * 2);
  u16* Gb = (u16*)alloc((size_t)BT * HFF * 2);
  u16* WQKVT = (u16*)alloc((size_t)NLAYER * QKV_STRIDE * D_MODEL * 2);
  u16* WOT = (u16*)alloc((size_t)NLAYER * DD * 2);
  u16* WGU = (u16*)alloc((size_t)NLAYER * GU_STRIDE * D_MODEL * 2);
  u16* WDT = (u16*)alloc((size_t)NLAYER * D_MODEL * HFF * 2);
  u16* LMH = (u16*)alloc((size_t)V_SIZE * D_MODEL * 2);
  float* NLLb = (float*)alloc((size_t)BT * 4);
  float* PartM = (float*)alloc((size_t)BT * (V_SIZE >> 6) * 4);
  float* PartS = (float*)alloc((size_t)BT * (V_SIZE >> 6) * 4);

  rope_table_kernel<<<256, 256, 0, stream>>>(rope_cos, rope_sin);
  convert_bf16_kernel<<<4096, 256, 0, stream>>>(lm_head, LMH, final_norm, (long)V_SIZE * D_MODEL / 8);
  embed_gather_kernel<<<BT, 256, 0, stream>>>(idx, embed, Xb, Rinv);

  const long QKVW = (long)QKV_STRIDE * D_MODEL;
  const long GUW = (long)GU_STRIDE * D_MODEL;
  const long DW = (long)D_MODEL * HFF;
  transpose_bf16_kernel<<<dim3(32, 32, NLAYER), 256, 0, stream>>>(wq, WQKVT, D_MODEL, D_MODEL, DD, QKVW, 0, attn_norm, D_MODEL);
  transpose_bf16_kernel<<<dim3(32, 32, NLAYER), 256, 0, stream>>>(wk, WQKVT + DD, D_MODEL, D_MODEL, DD, QKVW, 0, attn_norm, D_MODEL);
  transpose_bf16_kernel<<<dim3(32, 32, NLAYER), 256, 0, stream>>>(wv, WQKVT + 2 * DD, D_MODEL, D_MODEL, DD, QKVW, 0, attn_norm, D_MODEL);
  transpose_bf16_kernel<<<dim3(32, 32, NLAYER), 256, 0, stream>>>(wo, WOT, D_MODEL, D_MODEL, DD, DD, 0, nullptr, 0);
  transpose_bf16_kernel<<<dim3(128, 32, NLAYER), 256, 0, stream>>>(w_gate, WGU, D_MODEL, HFF, DW, GUW, 1, mlp_norm, D_MODEL);
  transpose_bf16_kernel<<<dim3(128, 32, NLAYER), 256, 0, stream>>>(w_up, WGU, D_MODEL, HFF, DW, GUW, 2, mlp_norm, D_MODEL);
  transpose_bf16_kernel<<<dim3(32, 128, NLAYER), 256, 0, stream>>>(w_down, WDT, HFF, D_MODEL, DW, DW, 0, nullptr, 0);

  for (int l = 0; l < NLAYER; l++) {
    gemm128_kernel<4><<<(QKV_STRIDE / 128) * (BT / 128), 256, 0, stream>>>(
        Xb, WQKVT + (size_t)l * QKVW, QKVb, nullptr, nullptr, rope_cos, rope_sin,
        Rinv, BT, QKV_STRIDE, D_MODEL, QKV_STRIDE / 128);
    vtrans_kernel<<<dim3(32, 32), 256, 0, stream>>>(QKVb, Vtb);
    attn_kernel<<<dim3(16, 32), 256, 0, stream>>>(QKVb, Vtb, Ob);
    gemm64_kernel<<<(BT / 64) * (D_MODEL / 128), 256, 0, stream>>>(
        Ob, WOT + (size_t)l * DD, Xb, Xb, SsqP, BT, D_MODEL, D_MODEL);
    rinv_kernel<<<BT / 256, 256, 0, stream>>>(SsqP, Rinv);

    gemm128_kernel<5><<<(GU_STRIDE / 128) * (BT / 128), 256, 0, stream>>>(
        Xb, WGU + (size_t)l * GUW, Gb, nullptr, nullptr, nullptr, nullptr,
        Rinv, BT, GU_STRIDE, D_MODEL, 32);
    gemm64_kernel<<<(BT / 64) * (D_MODEL / 128), 256, 0, stream>>>(
        Gb, WDT + (size_t)l * DW, Xb, Xb, SsqP, BT, D_MODEL, HFF);
    rinv_kernel<<<BT / 256, 256, 0, stream>>>(SsqP, Rinv);
  }

  scale_xb_kernel<<<BT * D_MODEL / (256 * 8), 256, 0, stream>>>(Xb, Rinv, XbF);
  gemm128_kernel<0><<<(V_SIZE / 128) * (BT / 128), 256, 0, stream>>>(
      XbF, LMH, out, PartM, PartS, nullptr, nullptr,
      nullptr, BT, V_SIZE, D_MODEL, 50);
  nll_finalize_kernel<<<BT, 64, 0, stream>>>(PartM, PartS, out, targets, NLLb);
  loss_reduce_kernel<<<1, 256, 0, stream>>>(NLLb, out + (size_t)BT * V_SIZE);
}